// Round 1
// baseline (767.902 us; speedup 1.0000x reference)
//
#include <hip/hip_runtime.h>

constexpr int CB   = 16;    // batch
constexpr int CN   = 512;   // nodes
constexpr int CD   = 256;   // dim
constexpr int CPH  = 8;     // pgat heads
constexpr int CDH  = 32;    // CD / CPH
constexpr int CNP1 = 513;   // nodes + c_node
constexpr int CFH  = 128;
constexpr int CNC  = 2;

__device__ __forceinline__ float tanh_fast(float x) {
  x = fminf(fmaxf(x, -15.f), 15.f);
  float e = __expf(2.f * x);
  return (e - 1.f) / (e + 1.f);
}

// ---------- generic fp32 GEMM: C[m,n] = sum_k A[m,k]*W[n,k] (+bias[n])
// 64x64 tile, 256 threads, 4x4 microtile. Ncols, K multiples of 64/16; M guarded.
__global__ __launch_bounds__(256) void gemm_nt(
    const float* __restrict__ A, const float* __restrict__ W,
    const float* __restrict__ bias, float* __restrict__ C,
    int M, int Ncols, int K)
{
  __shared__ float As[16][68];
  __shared__ float Ws[16][68];
  const int t  = threadIdx.x;
  const int mt = blockIdx.y * 64;
  const int nt = blockIdx.x * 64;
  const int lm = t >> 4;      // 0..15
  const int ln = t & 15;      // 0..15
  const int lrow = t >> 2;    // 0..63 staging row
  const int lkq  = (t & 3) * 4;

  float acc[4][4];
#pragma unroll
  for (int i = 0; i < 4; i++)
#pragma unroll
    for (int j = 0; j < 4; j++) acc[i][j] = 0.f;

  for (int k0 = 0; k0 < K; k0 += 16) {
    __syncthreads();
    float4 av = make_float4(0.f, 0.f, 0.f, 0.f);
    if (mt + lrow < M)
      av = *(const float4*)(A + (size_t)(mt + lrow) * K + k0 + lkq);
    As[lkq + 0][lrow] = av.x; As[lkq + 1][lrow] = av.y;
    As[lkq + 2][lrow] = av.z; As[lkq + 3][lrow] = av.w;
    float4 wv = *(const float4*)(W + (size_t)(nt + lrow) * K + k0 + lkq);
    Ws[lkq + 0][lrow] = wv.x; Ws[lkq + 1][lrow] = wv.y;
    Ws[lkq + 2][lrow] = wv.z; Ws[lkq + 3][lrow] = wv.w;
    __syncthreads();
#pragma unroll
    for (int kk = 0; kk < 16; kk++) {
      float4 a = *(const float4*)&As[kk][lm * 4];
      float4 w = *(const float4*)&Ws[kk][ln * 4];
      acc[0][0] += a.x * w.x; acc[0][1] += a.x * w.y; acc[0][2] += a.x * w.z; acc[0][3] += a.x * w.w;
      acc[1][0] += a.y * w.x; acc[1][1] += a.y * w.y; acc[1][2] += a.y * w.z; acc[1][3] += a.y * w.w;
      acc[2][0] += a.z * w.x; acc[2][1] += a.z * w.y; acc[2][2] += a.z * w.z; acc[2][3] += a.z * w.w;
      acc[3][0] += a.w * w.x; acc[3][1] += a.w * w.y; acc[3][2] += a.w * w.z; acc[3][3] += a.w * w.w;
    }
  }
  float4 bv = make_float4(0.f, 0.f, 0.f, 0.f);
  if (bias) bv = *(const float4*)(bias + nt + ln * 4);
#pragma unroll
  for (int i = 0; i < 4; i++) {
    int m = mt + lm * 4 + i;
    if (m < M) {
      float4 v = make_float4(acc[i][0] + bv.x, acc[i][1] + bv.y,
                             acc[i][2] + bv.z, acc[i][3] + bv.w);
      *(float4*)(C + (size_t)m * Ncols + nt + ln * 4) = v;
    }
  }
}

// ---------- P_GAT sq/sk: sqT/skT layout (B, PH, N) for coalesced reads later
__global__ __launch_bounds__(256) void pgat_sqsk(
    const float* __restrict__ qk, const float* __restrict__ attnw,
    float* __restrict__ sqT, float* __restrict__ skT)
{
  __shared__ float aw[CPH * 64];
  const int t = threadIdx.x;
  for (int i = t; i < CPH * 64; i += 256) aw[i] = attnw[i];
  __syncthreads();
  const int r = blockIdx.x * 32 + (t >> 3);   // global row in (B*N)
  const int h = t & 7;
  const float* p  = qk + (size_t)r * CD + h * CDH;
  const float* w1 = &aw[h * 64];
  const float* w2 = &aw[h * 64 + 32];
  float s1 = 0.f, s2 = 0.f;
#pragma unroll
  for (int j = 0; j < CDH; j += 4) {
    float4 v = *(const float4*)(p + j);
    s1 += v.x * w1[j] + v.y * w1[j + 1] + v.z * w1[j + 2] + v.w * w1[j + 3];
    s2 += v.x * w2[j] + v.y * w2[j + 1] + v.z * w2[j + 2] + v.w * w2[j + 3];
  }
  const int b = r >> 9, n = r & 511;
  sqT[((size_t)b * CPH + h) * CN + n] = s1;
  skT[((size_t)b * CPH + h) * CN + n] = s2;
}

// ---------- P_GAT attention + tanh + residual.
// grid (qt=8, h=8, b=16), 256 threads. Each thread: 2 q x 4 d outputs.
__global__ __launch_bounds__(256) void pgat_attn_kern(
    const float* __restrict__ qk, const float* __restrict__ sqT,
    const float* __restrict__ skT, const float* __restrict__ pmask,
    const float* __restrict__ fin, float* __restrict__ fout, int outStride)
{
  const int qt = blockIdx.x;
  const int h  = blockIdx.y;
  const int b  = blockIdx.z;
  const int t  = threadIdx.x;
  const int qg = t >> 3;   // 0..31 -> q pair
  const int dg = t & 7;    // 0..7  -> d quad

  __shared__ float skl[CN];
  __shared__ float pml[CN];
  __shared__ float sql[64];
  __shared__ float pmq[64];
  __shared__ float wbuf[64][64];
  __shared__ float chunk[64][40];

  for (int k = t; k < CN; k += 256) {
    skl[k] = skT[((size_t)b * CPH + h) * CN + k];
    pml[k] = pmask[b * CN + k];
  }
  if (t < 64) {
    sql[t] = sqT[((size_t)b * CPH + h) * CN + qt * 64 + t];
    pmq[t] = pmask[b * CN + qt * 64 + t];
  }

  float acc[2][4];
  float den[2];
#pragma unroll
  for (int i = 0; i < 2; i++) {
    den[i] = 0.f;
#pragma unroll
    for (int j = 0; j < 4; j++) acc[i][j] = 0.f;
  }

  for (int k0 = 0; k0 < CN; k0 += 64) {
    __syncthreads();
    // stage qk chunk (64 k x 32 d), coalesced 128B rows
#pragma unroll
    for (int j = 0; j < 2; j++) {
      int f4 = t + 256 * j;              // 0..511
      int kk = f4 >> 3, dq = f4 & 7;
      float4 v = *(const float4*)(qk + ((size_t)(b * CN + k0 + kk)) * CD + h * CDH + dq * 4);
      *(float4*)&chunk[kk][dq * 4] = v;
    }
    // compute softmax weights once per (q,k)
#pragma unroll
    for (int j = 0; j < 16; j++) {
      int id = t + 256 * j;              // 0..4095
      int kk = id >> 6, q = id & 63;
      float s = tanh_fast(sql[q] + skl[k0 + kk]);
      if (pmq[q] * pml[k0 + kk] == 0.f) s = -1e-8f;
      wbuf[kk][q] = __expf(s);
    }
    __syncthreads();
#pragma unroll 8
    for (int kk = 0; kk < 64; kk++) {
      float4 qv = *(const float4*)&chunk[kk][dg * 4];
#pragma unroll
      for (int i = 0; i < 2; i++) {
        float w = wbuf[kk][qg * 2 + i];
        acc[i][0] += w * qv.x; acc[i][1] += w * qv.y;
        acc[i][2] += w * qv.z; acc[i][3] += w * qv.w;
        den[i] += w;
      }
    }
  }
#pragma unroll
  for (int i = 0; i < 2; i++) {
    int q = qt * 64 + qg * 2 + i;
    float inv = 1.f / den[i];
    const float* ip = fin + ((size_t)b * CN + q) * CD + h * CDH + dg * 4;
    float*       op = fout + ((size_t)b * outStride + q) * CD + h * CDH + dg * 4;
    float4 r = *(const float4*)ip;
    float4 o;
    o.x = r.x + tanh_fast(acc[i][0] * inv);
    o.y = r.y + tanh_fast(acc[i][1] * inv);
    o.z = r.z + tanh_fast(acc[i][2] * inv);
    o.w = r.w + tanh_fast(acc[i][3] * inv);
    *(float4*)op = o;
  }
}

// ---------- append c_node row into comb
__global__ __launch_bounds__(256) void cnode_copy(
    const float* __restrict__ c, float* __restrict__ comb)
{
  int b = blockIdx.x, t = threadIdx.x;
  comb[((size_t)b * CNP1 + CN) * CD + t] = c[b * CD + t];
}

// ---------- UP_GAT (everything after the k-GEMM). grid (B), 256 threads.
__global__ __launch_bounds__(256) void up_kernel(
    const float* __restrict__ comb, const float* __restrict__ kmat,
    const float* __restrict__ cnode, const float* __restrict__ pmask,
    const float* __restrict__ qw, const float* __restrict__ qb,
    const float* __restrict__ ow, const float* __restrict__ ob,
    float* __restrict__ uout, int up)
{
  const int b = blockIdx.x;
  const int t = threadIdx.x;
  __shared__ float cl[CD];
  __shared__ float ql[CD];
  __shared__ float att[CNP1];
  __shared__ float red[256];
  __shared__ float hl[CD];

  cl[t] = cnode[b * CD + t];
  __syncthreads();
  // q projection (head dim t)
  {
    const float* wr = qw + (size_t)t * CD;
    float a = qb[t];
#pragma unroll 4
    for (int k = 0; k < CD; k += 4) {
      float4 w4 = *(const float4*)(wr + k);
      a += cl[k] * w4.x + cl[k + 1] * w4.y + cl[k + 2] * w4.z + cl[k + 3] * w4.w;
    }
    ql[t] = a;
  }
  __syncthreads();
  // sim over 513 keys
  for (int k = t; k < CNP1; k += 256) {
    const float* kr = kmat + ((size_t)b * CNP1 + k) * CD;
    float a = 0.f;
#pragma unroll 4
    for (int j = 0; j < CD; j += 4) {
      float4 v = *(const float4*)(kr + j);
      a += ql[j] * v.x + ql[j + 1] * v.y + ql[j + 2] * v.z + ql[j + 3] * v.w;
    }
    a *= 0.0625f;   // 1/sqrt(256)
    float m = (k < CN) ? pmask[b * CN + k] : 1.f;
    if (m == 0.f) a = 1e-8f;
    att[k] = a;
  }
  __syncthreads();
  // softmax (max-sub)
  float lm = -1e30f;
  for (int k = t; k < CNP1; k += 256) lm = fmaxf(lm, att[k]);
  red[t] = lm; __syncthreads();
  for (int s = 128; s > 0; s >>= 1) { if (t < s) red[t] = fmaxf(red[t], red[t + s]); __syncthreads(); }
  float mx = red[0];
  __syncthreads();
  float ls = 0.f;
  for (int k = t; k < CNP1; k += 256) { float e = __expf(att[k] - mx); att[k] = e; ls += e; }
  red[t] = ls; __syncthreads();
  for (int s = 128; s > 0; s >>= 1) { if (t < s) red[t] += red[t + s]; __syncthreads(); }
  float inv = 1.f / red[0];
  // head (d = t)
  {
    float a = 0.f;
    for (int k = 0; k < CNP1; k++) a += att[k] * comb[((size_t)b * CNP1 + k) * CD + t];
    hl[t] = a * inv;
  }
  __syncthreads();
  // out = head @ (sum of 4 ow blocks).T + ob  (since mh = concat([head]*4))
  {
    const float* r0 = ow + (size_t)t * 4 * CD;
    float a = ob[t];
#pragma unroll 2
    for (int dd = 0; dd < CD; dd += 4) {
      float4 w0 = *(const float4*)(r0 + dd);
      float4 w1 = *(const float4*)(r0 + CD + dd);
      float4 w2 = *(const float4*)(r0 + 2 * CD + dd);
      float4 w3 = *(const float4*)(r0 + 3 * CD + dd);
      a += hl[dd]     * (w0.x + w1.x + w2.x + w3.x)
         + hl[dd + 1] * (w0.y + w1.y + w2.y + w3.y)
         + hl[dd + 2] * (w0.z + w1.z + w2.z + w3.z)
         + hl[dd + 3] * (w0.w + w1.w + w2.w + w3.w);
    }
    uout[((size_t)b * 4 + up) * CD + t] = a;
  }
}

// ---------- U_GAT attention (4 nodes, 4 heads), in-place residual on u
__global__ __launch_bounds__(256) void ugat_attn_kern(
    const float* __restrict__ uqk, const float* __restrict__ attnw,
    float* __restrict__ u)
{
  const int b = blockIdx.x, t = threadIdx.x;
  __shared__ float uq[4][CD];
  __shared__ float sql[4][4], skl[4][4];
  for (int i = t; i < 4 * CD; i += 256) uq[i >> 8][i & 255] = uqk[(size_t)b * 4 * CD + i];
  __syncthreads();
  if (t < 32) {
    int node = t >> 3, h = (t >> 1) & 3, which = t & 1;
    const float* w = attnw + h * 128 + which * 64;
    float a = 0.f;
    for (int j = 0; j < 64; j++) a += uq[node][h * 64 + j] * w[j];
    if (which == 0) sql[node][h] = a; else skl[node][h] = a;
  }
  __syncthreads();
  const int h = t >> 6;
#pragma unroll
  for (int q = 0; q < 4; q++) {
    float e[4]; float ssum = 0.f;
#pragma unroll
    for (int k = 0; k < 4; k++) { e[k] = __expf(tanh_fast(sql[q][h] + skl[k][h])); ssum += e[k]; }
    float hid = 0.f;
#pragma unroll
    for (int k = 0; k < 4; k++) hid += e[k] * uq[k][t];
    hid = tanh_fast(hid / ssum);
    size_t idx = (size_t)b * 4 * CD + q * CD + t;
    u[idx] = u[idx] + hid;
  }
}

// ---------- MLP + per-trait classifier head. grid (B, 4), 128 threads.
__global__ __launch_bounds__(128) void mlp_kernel(
    const float* __restrict__ u,
    const float* __restrict__ w1, const float* __restrict__ b1,
    const float* __restrict__ w2, const float* __restrict__ b2,
    const float* __restrict__ f1w, const float* __restrict__ f1b,
    const float* __restrict__ f2w, const float* __restrict__ f2b,
    const float* __restrict__ f3w, const float* __restrict__ f3b,
    const float* __restrict__ f4w, const float* __restrict__ f4b,
    float* __restrict__ out)
{
  const int b = blockIdx.x, i = blockIdx.y, t = threadIdx.x;
  __shared__ float xl[CD];
  __shared__ float h1[CFH];
  __shared__ float h2[CFH];
  xl[t]       = u[((size_t)b * 4 + i) * CD + t];
  xl[t + 128] = u[((size_t)b * 4 + i) * CD + t + 128];
  __syncthreads();
  {
    const float* r = w1 + (size_t)t * CD;
    float a = b1[t];
#pragma unroll 4
    for (int k = 0; k < CD; k += 4) {
      float4 v = *(const float4*)(r + k);
      a += xl[k] * v.x + xl[k + 1] * v.y + xl[k + 2] * v.z + xl[k + 3] * v.w;
    }
    h1[t] = fmaxf(a, 0.f);
  }
  __syncthreads();
  {
    const float* r = w2 + (size_t)t * CFH;
    float a = b2[t];
#pragma unroll 4
    for (int k = 0; k < CFH; k += 4) {
      float4 v = *(const float4*)(r + k);
      a += h1[k] * v.x + h1[k + 1] * v.y + h1[k + 2] * v.z + h1[k + 3] * v.w;
    }
    h2[t] = fmaxf(a, 0.f);
  }
  __syncthreads();
  if (t < CNC) {
    const float* fw; const float* fb;
    switch (i) {
      case 0:  fw = f1w; fb = f1b; break;
      case 1:  fw = f2w; fb = f2b; break;
      case 2:  fw = f3w; fb = f3b; break;
      default: fw = f4w; fb = f4b; break;
    }
    const float* r = fw + (size_t)t * CFH;
    float a = fb[t];
    for (int k = 0; k < CFH; k++) a += h2[k] * r[k];
    out[(size_t)i * (CB * CNC) + b * CNC + t] = a;
  }
}

extern "C" void kernel_launch(void* const* d_in, const int* in_sizes, int n_in,
                              void* d_out, int out_size, void* d_ws, size_t ws_size,
                              hipStream_t stream) {
  (void)in_sizes; (void)n_in; (void)out_size; (void)ws_size;
  const float* pmask    = (const float*)d_in[0];
  const float* feature  = (const float*)d_in[1];
  const float* cnode    = (const float*)d_in[2];
  const float* pgat_W   = (const float*)d_in[3];
  const float* pgat_att = (const float*)d_in[4];
  const float* upw[4][6];
  for (int i = 0; i < 4; i++)
    for (int j = 0; j < 6; j++) upw[i][j] = (const float*)d_in[5 + i * 6 + j];
  const float* ugat_W   = (const float*)d_in[29];
  const float* ugat_att = (const float*)d_in[30];
  const float* mlp_w1 = (const float*)d_in[31];
  const float* mlp_b1 = (const float*)d_in[32];
  const float* mlp_w2 = (const float*)d_in[33];
  const float* mlp_b2 = (const float*)d_in[34];
  const float* fcf[8];
  for (int j = 0; j < 8; j++) fcf[j] = (const float*)d_in[35 + j];

  float* ws = (float*)d_ws;
  size_t o = 0;
  float* ws_qk   = ws + o; o += (size_t)CB * CN * CD;    // 2,097,152
  float* ws_feat = ws + o; o += (size_t)CB * CN * CD;    // 2,097,152
  float* ws_comb = ws + o; o += (size_t)CB * CNP1 * CD;  // 2,101,248
  float* ws_kmat = ws + o; o += (size_t)CB * CNP1 * CD;  // 2,101,248
  float* ws_sq   = ws + o; o += (size_t)CB * CPH * CN;   // 65,536
  float* ws_sk   = ws + o; o += (size_t)CB * CPH * CN;   // 65,536
  float* ws_u    = ws + o; o += (size_t)CB * 4 * CD;     // 16,384
  float* ws_uqk  = ws + o; o += (size_t)CB * 4 * CD;     // 16,384

  const dim3 gemmGridBig(CD / 64, (CB * CN) / 64);       // (4, 128)
  const dim3 gemmGridComb(CD / 64, (CB * CNP1 + 63) / 64); // (4, 129)
  const dim3 attnGrid(CN / 64, CPH, CB);                 // (8, 8, 16)

  // P_GAT layer 1
  gemm_nt<<<gemmGridBig, 256, 0, stream>>>(feature, pgat_W, nullptr, ws_qk, CB * CN, CD, CD);
  pgat_sqsk<<<dim3(CB * CN / 32), 256, 0, stream>>>(ws_qk, pgat_att, ws_sq, ws_sk);
  pgat_attn_kern<<<attnGrid, 256, 0, stream>>>(ws_qk, ws_sq, ws_sk, pmask, feature, ws_feat, CN);
  // P_GAT layer 2 (writes straight into comb rows, stride 513)
  gemm_nt<<<gemmGridBig, 256, 0, stream>>>(ws_feat, pgat_W, nullptr, ws_qk, CB * CN, CD, CD);
  pgat_sqsk<<<dim3(CB * CN / 32), 256, 0, stream>>>(ws_qk, pgat_att, ws_sq, ws_sk);
  pgat_attn_kern<<<attnGrid, 256, 0, stream>>>(ws_qk, ws_sq, ws_sk, pmask, ws_feat, ws_comb, CNP1);
  cnode_copy<<<dim3(CB), 256, 0, stream>>>(cnode, ws_comb);

  // UP_GAT x4 (single kmat buffer, sequential)
  for (int i = 0; i < 4; i++) {
    gemm_nt<<<gemmGridComb, 256, 0, stream>>>(ws_comb, upw[i][2], upw[i][3], ws_kmat, CB * CNP1, CD, CD);
    up_kernel<<<dim3(CB), 256, 0, stream>>>(ws_comb, ws_kmat, cnode, pmask,
                                            upw[i][0], upw[i][1], upw[i][4], upw[i][5], ws_u, i);
  }

  // U_GAT
  gemm_nt<<<dim3(CD / 64, 1), 256, 0, stream>>>(ws_u, ugat_W, nullptr, ws_uqk, CB * 4, CD, CD);
  ugat_attn_kern<<<dim3(CB), 256, 0, stream>>>(ws_uqk, ugat_att, ws_u);

  // MLP + heads
  mlp_kernel<<<dim3(CB, 4), 128, 0, stream>>>(ws_u, mlp_w1, mlp_b1, mlp_w2, mlp_b2,
                                              fcf[0], fcf[1], fcf[2], fcf[3],
                                              fcf[4], fcf[5], fcf[6], fcf[7],
                                              (float*)d_out);
}

// Round 2
// 562.290 us; speedup vs baseline: 1.3657x; 1.3657x over previous
//
#include <hip/hip_runtime.h>

constexpr int CB   = 16;    // batch
constexpr int CN   = 512;   // nodes
constexpr int CD   = 256;   // dim
constexpr int CPH  = 8;     // pgat heads
constexpr int CDH  = 32;    // CD / CPH
constexpr int CNP1 = 513;   // nodes + c_node
constexpr int CFH  = 128;
constexpr int CNC  = 2;

__device__ __forceinline__ float tanh_fast(float x) {
  x = fminf(fmaxf(x, -15.f), 15.f);
  float e = __expf(2.f * x);
  return (e - 1.f) / (e + 1.f);
}

// ---------- generic fp32 GEMM: C[m,n] = sum_k A[m,k]*W[n,k] (+bias[n])
__global__ __launch_bounds__(256) void gemm_nt(
    const float* __restrict__ A, const float* __restrict__ W,
    const float* __restrict__ bias, float* __restrict__ C,
    int M, int Ncols, int K)
{
  __shared__ float As[16][68];
  __shared__ float Ws[16][68];
  const int t  = threadIdx.x;
  const int mt = blockIdx.y * 64;
  const int nt = blockIdx.x * 64;
  const int lm = t >> 4;
  const int ln = t & 15;
  const int lrow = t >> 2;
  const int lkq  = (t & 3) * 4;

  float acc[4][4];
#pragma unroll
  for (int i = 0; i < 4; i++)
#pragma unroll
    for (int j = 0; j < 4; j++) acc[i][j] = 0.f;

  for (int k0 = 0; k0 < K; k0 += 16) {
    __syncthreads();
    float4 av = make_float4(0.f, 0.f, 0.f, 0.f);
    if (mt + lrow < M)
      av = *(const float4*)(A + (size_t)(mt + lrow) * K + k0 + lkq);
    As[lkq + 0][lrow] = av.x; As[lkq + 1][lrow] = av.y;
    As[lkq + 2][lrow] = av.z; As[lkq + 3][lrow] = av.w;
    float4 wv = *(const float4*)(W + (size_t)(nt + lrow) * K + k0 + lkq);
    Ws[lkq + 0][lrow] = wv.x; Ws[lkq + 1][lrow] = wv.y;
    Ws[lkq + 2][lrow] = wv.z; Ws[lkq + 3][lrow] = wv.w;
    __syncthreads();
#pragma unroll
    for (int kk = 0; kk < 16; kk++) {
      float4 a = *(const float4*)&As[kk][lm * 4];
      float4 w = *(const float4*)&Ws[kk][ln * 4];
      acc[0][0] += a.x * w.x; acc[0][1] += a.x * w.y; acc[0][2] += a.x * w.z; acc[0][3] += a.x * w.w;
      acc[1][0] += a.y * w.x; acc[1][1] += a.y * w.y; acc[1][2] += a.y * w.z; acc[1][3] += a.y * w.w;
      acc[2][0] += a.z * w.x; acc[2][1] += a.z * w.y; acc[2][2] += a.z * w.z; acc[2][3] += a.z * w.w;
      acc[3][0] += a.w * w.x; acc[3][1] += a.w * w.y; acc[3][2] += a.w * w.z; acc[3][3] += a.w * w.w;
    }
  }
  float4 bv = make_float4(0.f, 0.f, 0.f, 0.f);
  if (bias) bv = *(const float4*)(bias + nt + ln * 4);
#pragma unroll
  for (int i = 0; i < 4; i++) {
    int m = mt + lm * 4 + i;
    if (m < M) {
      float4 v = make_float4(acc[i][0] + bv.x, acc[i][1] + bv.y,
                             acc[i][2] + bv.z, acc[i][3] + bv.w);
      *(float4*)(C + (size_t)m * Ncols + nt + ln * 4) = v;
    }
  }
}

// ---------- P_GAT sq/sk
__global__ __launch_bounds__(256) void pgat_sqsk(
    const float* __restrict__ qk, const float* __restrict__ attnw,
    float* __restrict__ sqT, float* __restrict__ skT)
{
  __shared__ float aw[CPH * 64];
  const int t = threadIdx.x;
  for (int i = t; i < CPH * 64; i += 256) aw[i] = attnw[i];
  __syncthreads();
  const int r = blockIdx.x * 32 + (t >> 3);
  const int h = t & 7;
  const float* p  = qk + (size_t)r * CD + h * CDH;
  const float* w1 = &aw[h * 64];
  const float* w2 = &aw[h * 64 + 32];
  float s1 = 0.f, s2 = 0.f;
#pragma unroll
  for (int j = 0; j < CDH; j += 4) {
    float4 v = *(const float4*)(p + j);
    s1 += v.x * w1[j] + v.y * w1[j + 1] + v.z * w1[j + 2] + v.w * w1[j + 3];
    s2 += v.x * w2[j] + v.y * w2[j + 1] + v.z * w2[j + 2] + v.w * w2[j + 3];
  }
  const int b = r >> 9, n = r & 511;
  sqT[((size_t)b * CPH + h) * CN + n] = s1;
  skT[((size_t)b * CPH + h) * CN + n] = s2;
}

// ---------- P_GAT attention + tanh + residual
__global__ __launch_bounds__(256) void pgat_attn_kern(
    const float* __restrict__ qk, const float* __restrict__ sqT,
    const float* __restrict__ skT, const float* __restrict__ pmask,
    const float* __restrict__ fin, float* __restrict__ fout, int outStride)
{
  const int qt = blockIdx.x;
  const int h  = blockIdx.y;
  const int b  = blockIdx.z;
  const int t  = threadIdx.x;
  const int qg = t >> 3;
  const int dg = t & 7;

  __shared__ float skl[CN];
  __shared__ float pml[CN];
  __shared__ float sql[64];
  __shared__ float pmq[64];
  __shared__ float wbuf[64][64];
  __shared__ float chunk[64][40];

  for (int k = t; k < CN; k += 256) {
    skl[k] = skT[((size_t)b * CPH + h) * CN + k];
    pml[k] = pmask[b * CN + k];
  }
  if (t < 64) {
    sql[t] = sqT[((size_t)b * CPH + h) * CN + qt * 64 + t];
    pmq[t] = pmask[b * CN + qt * 64 + t];
  }

  float acc[2][4];
  float den[2];
#pragma unroll
  for (int i = 0; i < 2; i++) {
    den[i] = 0.f;
#pragma unroll
    for (int j = 0; j < 4; j++) acc[i][j] = 0.f;
  }

  for (int k0 = 0; k0 < CN; k0 += 64) {
    __syncthreads();
#pragma unroll
    for (int j = 0; j < 2; j++) {
      int f4 = t + 256 * j;
      int kk = f4 >> 3, dq = f4 & 7;
      float4 v = *(const float4*)(qk + ((size_t)(b * CN + k0 + kk)) * CD + h * CDH + dq * 4);
      *(float4*)&chunk[kk][dq * 4] = v;
    }
#pragma unroll
    for (int j = 0; j < 16; j++) {
      int id = t + 256 * j;
      int kk = id >> 6, q = id & 63;
      float s = tanh_fast(sql[q] + skl[k0 + kk]);
      if (pmq[q] * pml[k0 + kk] == 0.f) s = -1e-8f;
      wbuf[kk][q] = __expf(s);
    }
    __syncthreads();
#pragma unroll 8
    for (int kk = 0; kk < 64; kk++) {
      float4 qv = *(const float4*)&chunk[kk][dg * 4];
#pragma unroll
      for (int i = 0; i < 2; i++) {
        float w = wbuf[kk][qg * 2 + i];
        acc[i][0] += w * qv.x; acc[i][1] += w * qv.y;
        acc[i][2] += w * qv.z; acc[i][3] += w * qv.w;
        den[i] += w;
      }
    }
  }
#pragma unroll
  for (int i = 0; i < 2; i++) {
    int q = qt * 64 + qg * 2 + i;
    float inv = 1.f / den[i];
    const float* ip = fin + ((size_t)b * CN + q) * CD + h * CDH + dg * 4;
    float*       op = fout + ((size_t)b * outStride + q) * CD + h * CDH + dg * 4;
    float4 r = *(const float4*)ip;
    float4 o;
    o.x = r.x + tanh_fast(acc[i][0] * inv);
    o.y = r.y + tanh_fast(acc[i][1] * inv);
    o.z = r.z + tanh_fast(acc[i][2] * inv);
    o.w = r.w + tanh_fast(acc[i][3] * inv);
    *(float4*)op = o;
  }
}

// ---------- append c_node row into comb
__global__ __launch_bounds__(256) void cnode_copy(
    const float* __restrict__ c, float* __restrict__ comb)
{
  int b = blockIdx.x, t = threadIdx.x;
  comb[((size_t)b * CNP1 + CN) * CD + t] = c[b * CD + t];
}

// ========== UP_GAT stage (kmat GEMM eliminated: sim = (q@kw).comb + q.kb) ====

// grid (b=16), 256 threads; one up per launch.
__global__ __launch_bounds__(256) void up_q(
    const float* __restrict__ cnode,
    const float* __restrict__ qw, const float* __restrict__ qb,
    const float* __restrict__ kw, const float* __restrict__ kb,
    float* __restrict__ qt, float* __restrict__ qkb)
{
  const int b = blockIdx.x, t = threadIdx.x;
  __shared__ float cl[CD];
  __shared__ float ql[CD];
  __shared__ float red[256];
  cl[t] = cnode[b * CD + t];
  __syncthreads();
  {
    const float* wr = qw + (size_t)t * CD;
    float a = qb[t];
#pragma unroll 4
    for (int k = 0; k < CD; k += 4) {
      float4 w4 = *(const float4*)(wr + k);
      a += cl[k] * w4.x + cl[k + 1] * w4.y + cl[k + 2] * w4.z + cl[k + 3] * w4.w;
    }
    ql[t] = a;
  }
  __syncthreads();
  {
    float a = 0.f;
    for (int d = 0; d < CD; d++) a += ql[d] * kw[d * CD + t];
    qt[(size_t)b * CD + t] = a;
  }
  red[t] = ql[t] * kb[t];
  __syncthreads();
  for (int s = 128; s > 0; s >>= 1) { if (t < s) red[t] += red[t + s]; __syncthreads(); }
  if (t == 0) qkb[b] = red[0];
}

// sim[b][up][n]; grid (129, 16), 256 threads = 4 waves, one wave per n.
__global__ __launch_bounds__(256) void up_sim(
    const float* __restrict__ comb, const float* __restrict__ qt,
    const float* __restrict__ qkb, const float* __restrict__ pmask,
    float* __restrict__ sim)
{
  const int b = blockIdx.y, t = threadIdx.x;
  const int w = t >> 6, l = t & 63;
  __shared__ float qtl[4 * CD];
  __shared__ float qkbl[4];
  for (int i = t; i < 4 * CD; i += 256)
    qtl[i] = qt[((size_t)(i >> 8) * CB + b) * CD + (i & 255)];
  if (t < 4) qkbl[t] = qkb[t * CB + b];
  __syncthreads();
  const int n = blockIdx.x * 4 + w;
  if (n >= CNP1) return;
  float4 c4 = *(const float4*)(comb + ((size_t)b * CNP1 + n) * CD + l * 4);
  float p[4];
#pragma unroll
  for (int u = 0; u < 4; u++) {
    float4 q4 = *(const float4*)&qtl[u * CD + l * 4];
    p[u] = c4.x * q4.x + c4.y * q4.y + c4.z * q4.z + c4.w * q4.w;
  }
#pragma unroll
  for (int off = 32; off > 0; off >>= 1) {
#pragma unroll
    for (int u = 0; u < 4; u++) p[u] += __shfl_xor(p[u], off);
  }
  if (l == 0) {
    float m = (n < CN) ? pmask[b * CN + n] : 1.f;
#pragma unroll
    for (int u = 0; u < 4; u++) {
      float s = (p[u] + qkbl[u]) * 0.0625f;
      if (m == 0.f) s = 1e-8f;
      sim[((size_t)b * 4 + u) * CNP1 + n] = s;
    }
  }
}

// softmax over n: row -> exp(row-max) in place, inv = 1/sum. grid (16,4)
__global__ __launch_bounds__(256) void up_softmax(
    float* __restrict__ sim, float* __restrict__ inv)
{
  const int b = blockIdx.x, u = blockIdx.y, t = threadIdx.x;
  float* row = sim + ((size_t)b * 4 + u) * CNP1;
  __shared__ float red[256];
  float lm = -1e30f;
  for (int k = t; k < CNP1; k += 256) lm = fmaxf(lm, row[k]);
  red[t] = lm; __syncthreads();
  for (int s = 128; s > 0; s >>= 1) { if (t < s) red[t] = fmaxf(red[t], red[t + s]); __syncthreads(); }
  float mx = red[0];
  __syncthreads();
  float ls = 0.f;
  for (int k = t; k < CNP1; k += 256) { float e = __expf(row[k] - mx); row[k] = e; ls += e; }
  red[t] = ls; __syncthreads();
  for (int s = 128; s > 0; s >>= 1) { if (t < s) red[t] += red[t + s]; __syncthreads(); }
  if (t == 0) inv[b * 4 + u] = 1.f / red[0];
}

// head partials over n-chunks, atomic accumulate. grid (16, 9), 256 threads.
__global__ __launch_bounds__(256) void up_head(
    const float* __restrict__ comb, const float* __restrict__ att,
    float* __restrict__ head)
{
  const int b = blockIdx.x, n0 = blockIdx.y * 64, t = threadIdx.x;
  const int up = t >> 6, dq = t & 63;
  __shared__ float attl[4][64];
  attl[t >> 6][t & 63] = (n0 + (t & 63) < CNP1)
      ? att[((size_t)b * 4 + (t >> 6)) * CNP1 + n0 + (t & 63)] : 0.f;
  __syncthreads();
  float4 acc = make_float4(0.f, 0.f, 0.f, 0.f);
  const int nmax = min(64, CNP1 - n0);
  for (int j = 0; j < nmax; j++) {
    float a = attl[up][j];
    float4 c4 = *(const float4*)(comb + ((size_t)b * CNP1 + n0 + j) * CD + dq * 4);
    acc.x += a * c4.x; acc.y += a * c4.y; acc.z += a * c4.z; acc.w += a * c4.w;
  }
  float* hp = head + ((size_t)b * 4 + up) * CD + dq * 4;
  atomicAdd(hp + 0, acc.x); atomicAdd(hp + 1, acc.y);
  atomicAdd(hp + 2, acc.z); atomicAdd(hp + 3, acc.w);
}

// u[b][up][d] = ob[d] + sum_e (sum_r ow[d][r*256+e]) * head[e]*inv. grid (16)
__global__ __launch_bounds__(256) void up_out(
    const float* __restrict__ head, const float* __restrict__ inv,
    const float* __restrict__ ow, const float* __restrict__ ob,
    float* __restrict__ uout, int up)
{
  const int b = blockIdx.x, t = threadIdx.x;
  __shared__ float hl[CD];
  hl[t] = head[((size_t)b * 4 + up) * CD + t] * inv[b * 4 + up];
  __syncthreads();
  const float* r0 = ow + (size_t)t * 4 * CD;
  float a = ob[t];
#pragma unroll 2
  for (int dd = 0; dd < CD; dd += 4) {
    float4 w0 = *(const float4*)(r0 + dd);
    float4 w1 = *(const float4*)(r0 + CD + dd);
    float4 w2 = *(const float4*)(r0 + 2 * CD + dd);
    float4 w3 = *(const float4*)(r0 + 3 * CD + dd);
    a += hl[dd]     * (w0.x + w1.x + w2.x + w3.x)
       + hl[dd + 1] * (w0.y + w1.y + w2.y + w3.y)
       + hl[dd + 2] * (w0.z + w1.z + w2.z + w3.z)
       + hl[dd + 3] * (w0.w + w1.w + w2.w + w3.w);
  }
  uout[((size_t)b * 4 + up) * CD + t] = a;
}

// ---------- U_GAT attention
__global__ __launch_bounds__(256) void ugat_attn_kern(
    const float* __restrict__ uqk, const float* __restrict__ attnw,
    float* __restrict__ u)
{
  const int b = blockIdx.x, t = threadIdx.x;
  __shared__ float uq[4][CD];
  __shared__ float sql[4][4], skl[4][4];
  for (int i = t; i < 4 * CD; i += 256) uq[i >> 8][i & 255] = uqk[(size_t)b * 4 * CD + i];
  __syncthreads();
  if (t < 32) {
    int node = t >> 3, h = (t >> 1) & 3, which = t & 1;
    const float* w = attnw + h * 128 + which * 64;
    float a = 0.f;
    for (int j = 0; j < 64; j++) a += uq[node][h * 64 + j] * w[j];
    if (which == 0) sql[node][h] = a; else skl[node][h] = a;
  }
  __syncthreads();
  const int h = t >> 6;
#pragma unroll
  for (int q = 0; q < 4; q++) {
    float e[4]; float ssum = 0.f;
#pragma unroll
    for (int k = 0; k < 4; k++) { e[k] = __expf(tanh_fast(sql[q][h] + skl[k][h])); ssum += e[k]; }
    float hid = 0.f;
#pragma unroll
    for (int k = 0; k < 4; k++) hid += e[k] * uq[k][t];
    hid = tanh_fast(hid / ssum);
    size_t idx = (size_t)b * 4 * CD + q * CD + t;
    u[idx] = u[idx] + hid;
  }
}

// ---------- MLP + classifier heads
__global__ __launch_bounds__(128) void mlp_kernel(
    const float* __restrict__ u,
    const float* __restrict__ w1, const float* __restrict__ b1,
    const float* __restrict__ w2, const float* __restrict__ b2,
    const float* __restrict__ f1w, const float* __restrict__ f1b,
    const float* __restrict__ f2w, const float* __restrict__ f2b,
    const float* __restrict__ f3w, const float* __restrict__ f3b,
    const float* __restrict__ f4w, const float* __restrict__ f4b,
    float* __restrict__ out)
{
  const int b = blockIdx.x, i = blockIdx.y, t = threadIdx.x;
  __shared__ float xl[CD];
  __shared__ float h1[CFH];
  __shared__ float h2[CFH];
  xl[t]       = u[((size_t)b * 4 + i) * CD + t];
  xl[t + 128] = u[((size_t)b * 4 + i) * CD + t + 128];
  __syncthreads();
  {
    const float* r = w1 + (size_t)t * CD;
    float a = b1[t];
#pragma unroll 4
    for (int k = 0; k < CD; k += 4) {
      float4 v = *(const float4*)(r + k);
      a += xl[k] * v.x + xl[k + 1] * v.y + xl[k + 2] * v.z + xl[k + 3] * v.w;
    }
    h1[t] = fmaxf(a, 0.f);
  }
  __syncthreads();
  {
    const float* r = w2 + (size_t)t * CFH;
    float a = b2[t];
#pragma unroll 4
    for (int k = 0; k < CFH; k += 4) {
      float4 v = *(const float4*)(r + k);
      a += h1[k] * v.x + h1[k + 1] * v.y + h1[k + 2] * v.z + h1[k + 3] * v.w;
    }
    h2[t] = fmaxf(a, 0.f);
  }
  __syncthreads();
  if (t < CNC) {
    const float* fw; const float* fb;
    switch (i) {
      case 0:  fw = f1w; fb = f1b; break;
      case 1:  fw = f2w; fb = f2b; break;
      case 2:  fw = f3w; fb = f3b; break;
      default: fw = f4w; fb = f4b; break;
    }
    const float* r = fw + (size_t)t * CFH;
    float a = fb[t];
    for (int k = 0; k < CFH; k++) a += h2[k] * r[k];
    out[(size_t)i * (CB * CNC) + b * CNC + t] = a;
  }
}

extern "C" void kernel_launch(void* const* d_in, const int* in_sizes, int n_in,
                              void* d_out, int out_size, void* d_ws, size_t ws_size,
                              hipStream_t stream) {
  (void)in_sizes; (void)n_in; (void)out_size; (void)ws_size;
  const float* pmask    = (const float*)d_in[0];
  const float* feature  = (const float*)d_in[1];
  const float* cnode    = (const float*)d_in[2];
  const float* pgat_W   = (const float*)d_in[3];
  const float* pgat_att = (const float*)d_in[4];
  const float* upw[4][6];
  for (int i = 0; i < 4; i++)
    for (int j = 0; j < 6; j++) upw[i][j] = (const float*)d_in[5 + i * 6 + j];
  const float* ugat_W   = (const float*)d_in[29];
  const float* ugat_att = (const float*)d_in[30];
  const float* mlp_w1 = (const float*)d_in[31];
  const float* mlp_b1 = (const float*)d_in[32];
  const float* mlp_w2 = (const float*)d_in[33];
  const float* mlp_b2 = (const float*)d_in[34];
  const float* fcf[8];
  for (int j = 0; j < 8; j++) fcf[j] = (const float*)d_in[35 + j];

  float* ws = (float*)d_ws;
  size_t o = 0;
  float* ws_qk   = ws + o; o += (size_t)CB * CN * CD;
  float* ws_feat = ws + o; o += (size_t)CB * CN * CD;
  float* ws_comb = ws + o; o += (size_t)CB * CNP1 * CD;
  float* ws_sq   = ws + o; o += (size_t)CB * CPH * CN;
  float* ws_sk   = ws + o; o += (size_t)CB * CPH * CN;
  float* ws_qt   = ws + o; o += (size_t)4 * CB * CD;
  float* ws_qkb  = ws + o; o += 4 * CB;
  float* ws_sim  = ws + o; o += (size_t)CB * 4 * CNP1;
  float* ws_inv  = ws + o; o += CB * 4;
  float* ws_head = ws + o; o += (size_t)CB * 4 * CD;
  float* ws_u    = ws + o; o += (size_t)CB * 4 * CD;
  float* ws_uqk  = ws + o; o += (size_t)CB * 4 * CD;

  const dim3 gemmGridBig(CD / 64, (CB * CN) / 64);
  const dim3 attnGrid(CN / 64, CPH, CB);

  // P_GAT layer 1
  gemm_nt<<<gemmGridBig, 256, 0, stream>>>(feature, pgat_W, nullptr, ws_qk, CB * CN, CD, CD);
  pgat_sqsk<<<dim3(CB * CN / 32), 256, 0, stream>>>(ws_qk, pgat_att, ws_sq, ws_sk);
  pgat_attn_kern<<<attnGrid, 256, 0, stream>>>(ws_qk, ws_sq, ws_sk, pmask, feature, ws_feat, CN);
  // P_GAT layer 2 (writes straight into comb rows, stride 513)
  gemm_nt<<<gemmGridBig, 256, 0, stream>>>(ws_feat, pgat_W, nullptr, ws_qk, CB * CN, CD, CD);
  pgat_sqsk<<<dim3(CB * CN / 32), 256, 0, stream>>>(ws_qk, pgat_att, ws_sq, ws_sk);
  pgat_attn_kern<<<attnGrid, 256, 0, stream>>>(ws_qk, ws_sq, ws_sk, pmask, ws_feat, ws_comb, CNP1);
  cnode_copy<<<dim3(CB), 256, 0, stream>>>(cnode, ws_comb);

  // UP_GAT x4 (no kmat GEMM)
  hipMemsetAsync(ws_head, 0, (size_t)CB * 4 * CD * sizeof(float), stream);
  for (int i = 0; i < 4; i++)
    up_q<<<dim3(CB), 256, 0, stream>>>(cnode, upw[i][0], upw[i][1], upw[i][2], upw[i][3],
                                       ws_qt + (size_t)i * CB * CD, ws_qkb + i * CB);
  up_sim<<<dim3((CNP1 + 3) / 4, CB), 256, 0, stream>>>(ws_comb, ws_qt, ws_qkb, pmask, ws_sim);
  up_softmax<<<dim3(CB, 4), 256, 0, stream>>>(ws_sim, ws_inv);
  up_head<<<dim3(CB, (CNP1 + 63) / 64), 256, 0, stream>>>(ws_comb, ws_sim, ws_head);
  for (int i = 0; i < 4; i++)
    up_out<<<dim3(CB), 256, 0, stream>>>(ws_head, ws_inv, upw[i][4], upw[i][5], ws_u, i);

  // U_GAT
  gemm_nt<<<dim3(CD / 64, 1), 256, 0, stream>>>(ws_u, ugat_W, nullptr, ws_uqk, CB * 4, CD, CD);
  ugat_attn_kern<<<dim3(CB), 256, 0, stream>>>(ws_uqk, ugat_att, ws_u);

  // MLP + heads
  mlp_kernel<<<dim3(CB, 4), 128, 0, stream>>>(ws_u, mlp_w1, mlp_b1, mlp_w2, mlp_b2,
                                              fcf[0], fcf[1], fcf[2], fcf[3],
                                              fcf[4], fcf[5], fcf[6], fcf[7],
                                              (float*)d_out);
}

// Round 3
// 434.949 us; speedup vs baseline: 1.7655x; 1.2928x over previous
//
#include <hip/hip_runtime.h>

constexpr int CB   = 16;    // batch
constexpr int CN   = 512;   // nodes
constexpr int CD   = 256;   // dim
constexpr int CPH  = 8;     // pgat heads
constexpr int CDH  = 32;    // CD / CPH
constexpr int CNP1 = 513;   // nodes + c_node
constexpr int CFH  = 128;
constexpr int CNC  = 2;

__device__ __forceinline__ float tanh_fast(float x) {
  x = fminf(fmaxf(x, -15.f), 15.f);
  float e = __expf(2.f * x);
  return (e - 1.f) / (e + 1.f);
}

// ---------- generic fp32 GEMM: C[m,n] = sum_k A[m,k]*W[n,k] (+bias[n])
__global__ __launch_bounds__(256) void gemm_nt(
    const float* __restrict__ A, const float* __restrict__ W,
    const float* __restrict__ bias, float* __restrict__ C,
    int M, int Ncols, int K)
{
  __shared__ float As[16][68];
  __shared__ float Ws[16][68];
  const int t  = threadIdx.x;
  const int mt = blockIdx.y * 64;
  const int nt = blockIdx.x * 64;
  const int lm = t >> 4;
  const int ln = t & 15;
  const int lrow = t >> 2;
  const int lkq  = (t & 3) * 4;

  float acc[4][4];
#pragma unroll
  for (int i = 0; i < 4; i++)
#pragma unroll
    for (int j = 0; j < 4; j++) acc[i][j] = 0.f;

  for (int k0 = 0; k0 < K; k0 += 16) {
    __syncthreads();
    float4 av = make_float4(0.f, 0.f, 0.f, 0.f);
    if (mt + lrow < M)
      av = *(const float4*)(A + (size_t)(mt + lrow) * K + k0 + lkq);
    As[lkq + 0][lrow] = av.x; As[lkq + 1][lrow] = av.y;
    As[lkq + 2][lrow] = av.z; As[lkq + 3][lrow] = av.w;
    float4 wv = *(const float4*)(W + (size_t)(nt + lrow) * K + k0 + lkq);
    Ws[lkq + 0][lrow] = wv.x; Ws[lkq + 1][lrow] = wv.y;
    Ws[lkq + 2][lrow] = wv.z; Ws[lkq + 3][lrow] = wv.w;
    __syncthreads();
#pragma unroll
    for (int kk = 0; kk < 16; kk++) {
      float4 a = *(const float4*)&As[kk][lm * 4];
      float4 w = *(const float4*)&Ws[kk][ln * 4];
      acc[0][0] += a.x * w.x; acc[0][1] += a.x * w.y; acc[0][2] += a.x * w.z; acc[0][3] += a.x * w.w;
      acc[1][0] += a.y * w.x; acc[1][1] += a.y * w.y; acc[1][2] += a.y * w.z; acc[1][3] += a.y * w.w;
      acc[2][0] += a.z * w.x; acc[2][1] += a.z * w.y; acc[2][2] += a.z * w.z; acc[2][3] += a.z * w.w;
      acc[3][0] += a.w * w.x; acc[3][1] += a.w * w.y; acc[3][2] += a.w * w.z; acc[3][3] += a.w * w.w;
    }
  }
  float4 bv = make_float4(0.f, 0.f, 0.f, 0.f);
  if (bias) bv = *(const float4*)(bias + nt + ln * 4);
#pragma unroll
  for (int i = 0; i < 4; i++) {
    int m = mt + lm * 4 + i;
    if (m < M) {
      float4 v = make_float4(acc[i][0] + bv.x, acc[i][1] + bv.y,
                             acc[i][2] + bv.z, acc[i][3] + bv.w);
      *(float4*)(C + (size_t)m * Ncols + nt + ln * 4) = v;
    }
  }
}

// ---------- P_GAT sq/sk
__global__ __launch_bounds__(256) void pgat_sqsk(
    const float* __restrict__ qk, const float* __restrict__ attnw,
    float* __restrict__ sqT, float* __restrict__ skT)
{
  __shared__ float aw[CPH * 64];
  const int t = threadIdx.x;
  for (int i = t; i < CPH * 64; i += 256) aw[i] = attnw[i];
  __syncthreads();
  const int r = blockIdx.x * 32 + (t >> 3);
  const int h = t & 7;
  const float* p  = qk + (size_t)r * CD + h * CDH;
  const float* w1 = &aw[h * 64];
  const float* w2 = &aw[h * 64 + 32];
  float s1 = 0.f, s2 = 0.f;
#pragma unroll
  for (int j = 0; j < CDH; j += 4) {
    float4 v = *(const float4*)(p + j);
    s1 += v.x * w1[j] + v.y * w1[j + 1] + v.z * w1[j + 2] + v.w * w1[j + 3];
    s2 += v.x * w2[j] + v.y * w2[j + 1] + v.z * w2[j + 2] + v.w * w2[j + 3];
  }
  const int b = r >> 9, n = r & 511;
  sqT[((size_t)b * CPH + h) * CN + n] = s1;
  skT[((size_t)b * CPH + h) * CN + n] = s2;
}

// ---------- P_GAT attention + tanh + residual, 4q x 4d register tile.
// grid (qt=8, hp=4, b=16), 256 thr. Block = 64 q x 64 d (2 heads).
__global__ __launch_bounds__(256) void pgat_attn2(
    const float* __restrict__ qk, const float* __restrict__ sqT,
    const float* __restrict__ skT, const float* __restrict__ pmask,
    const float* __restrict__ fin, float* __restrict__ fout, int outStride)
{
  const int qt = blockIdx.x;
  const int hp = blockIdx.y;
  const int b  = blockIdx.z;
  const int t  = threadIdx.x;
  const int qg = t >> 4;       // 0..15 -> q quad
  const int dg = t & 15;       // 0..15 -> d quad (within 64 cols)
  const int h2 = dg >> 3;      // which of the 2 heads

  __shared__ float chunk[64][64];   // [kk][c]  16 KB
  __shared__ float wbuf[64][128];   // [kk][h2*64+q]  32 KB
  __shared__ float skl[2][CN];      // 4 KB
  __shared__ float pml[CN];         // 2 KB
  __shared__ float sql[2][64];
  __shared__ float pmq[64];

  for (int i = t; i < 2 * CN; i += 256) {
    int hh = i >> 9, k = i & 511;
    skl[hh][k] = skT[((size_t)b * CPH + hp * 2 + hh) * CN + k];
  }
  for (int i = t; i < CN; i += 256) pml[i] = pmask[b * CN + i];
  if (t < 128) {
    int hh = t >> 6, q = t & 63;
    sql[hh][q] = sqT[((size_t)b * CPH + hp * 2 + hh) * CN + qt * 64 + q];
  }
  if (t < 64) pmq[t] = pmask[b * CN + qt * 64 + t];

  float acc[4][4];
  float den[4];
#pragma unroll
  for (int i = 0; i < 4; i++) {
    den[i] = 0.f;
#pragma unroll
    for (int j = 0; j < 4; j++) acc[i][j] = 0.f;
  }

  for (int k0 = 0; k0 < CN; k0 += 64) {
    __syncthreads();
    // stage qk chunk: 64 k x 64 c
#pragma unroll
    for (int j = 0; j < 4; j++) {
      int id = t + 256 * j;              // 0..1023 float4s
      int kk = id >> 4, c4 = id & 15;
      *(float4*)&chunk[kk][c4 * 4] =
          *(const float4*)(qk + ((size_t)(b * CN + k0 + kk)) * CD + hp * 64 + c4 * 4);
    }
    // softmax weights for both heads: 64 kk x 128 (h2,q)
#pragma unroll
    for (int j = 0; j < 32; j++) {
      int id = t + 256 * j;              // 0..8191
      int kk = id >> 7, r = id & 127, hh = r >> 6, q = r & 63;
      float s = tanh_fast(sql[hh][q] + skl[hh][k0 + kk]);
      if (pmq[q] * pml[k0 + kk] == 0.f) s = -1e-8f;
      wbuf[kk][r] = __expf(s);
    }
    __syncthreads();
#pragma unroll 16
    for (int kk = 0; kk < 64; kk++) {
      float4 c = *(const float4*)&chunk[kk][dg * 4];
      float4 w = *(const float4*)&wbuf[kk][h2 * 64 + qg * 4];
      acc[0][0] += w.x * c.x; acc[0][1] += w.x * c.y; acc[0][2] += w.x * c.z; acc[0][3] += w.x * c.w;
      acc[1][0] += w.y * c.x; acc[1][1] += w.y * c.y; acc[1][2] += w.y * c.z; acc[1][3] += w.y * c.w;
      acc[2][0] += w.z * c.x; acc[2][1] += w.z * c.y; acc[2][2] += w.z * c.z; acc[2][3] += w.z * c.w;
      acc[3][0] += w.w * c.x; acc[3][1] += w.w * c.y; acc[3][2] += w.w * c.z; acc[3][3] += w.w * c.w;
      den[0] += w.x; den[1] += w.y; den[2] += w.z; den[3] += w.w;
    }
  }
  const int col = hp * 64 + dg * 4;
#pragma unroll
  for (int i = 0; i < 4; i++) {
    int q = qt * 64 + qg * 4 + i;
    float inv = 1.f / den[i];
    const float* ip = fin + ((size_t)b * CN + q) * CD + col;
    float*       op = fout + ((size_t)b * outStride + q) * CD + col;
    float4 r = *(const float4*)ip;
    float4 o;
    o.x = r.x + tanh_fast(acc[i][0] * inv);
    o.y = r.y + tanh_fast(acc[i][1] * inv);
    o.z = r.z + tanh_fast(acc[i][2] * inv);
    o.w = r.w + tanh_fast(acc[i][3] * inv);
    *(float4*)op = o;
  }
}

// ---------- append c_node row into comb
__global__ __launch_bounds__(256) void cnode_copy(
    const float* __restrict__ c, float* __restrict__ comb)
{
  int b = blockIdx.x, t = threadIdx.x;
  comb[((size_t)b * CNP1 + CN) * CD + t] = c[b * CD + t];
}

// ========== UP_GAT stage ==========

// grid (up=4, b=16), 256 threads.
__global__ __launch_bounds__(256) void up_q_all(
    const float* __restrict__ cnode,
    const float* __restrict__ qw0, const float* __restrict__ qb0,
    const float* __restrict__ kw0, const float* __restrict__ kb0,
    const float* __restrict__ qw1, const float* __restrict__ qb1,
    const float* __restrict__ kw1, const float* __restrict__ kb1,
    const float* __restrict__ qw2, const float* __restrict__ qb2,
    const float* __restrict__ kw2, const float* __restrict__ kb2,
    const float* __restrict__ qw3, const float* __restrict__ qb3,
    const float* __restrict__ kw3, const float* __restrict__ kb3,
    float* __restrict__ qt_, float* __restrict__ qkb)
{
  const int up = blockIdx.x, b = blockIdx.y, t = threadIdx.x;
  const float* qw = (up == 0) ? qw0 : (up == 1) ? qw1 : (up == 2) ? qw2 : qw3;
  const float* qb = (up == 0) ? qb0 : (up == 1) ? qb1 : (up == 2) ? qb2 : qb3;
  const float* kw = (up == 0) ? kw0 : (up == 1) ? kw1 : (up == 2) ? kw2 : kw3;
  const float* kb = (up == 0) ? kb0 : (up == 1) ? kb1 : (up == 2) ? kb2 : kb3;
  __shared__ float cl[CD];
  __shared__ float ql[CD];
  __shared__ float red[256];
  cl[t] = cnode[b * CD + t];
  __syncthreads();
  {
    const float* wr = qw + (size_t)t * CD;
    float a = qb[t];
#pragma unroll 4
    for (int k = 0; k < CD; k += 4) {
      float4 w4 = *(const float4*)(wr + k);
      a += cl[k] * w4.x + cl[k + 1] * w4.y + cl[k + 2] * w4.z + cl[k + 3] * w4.w;
    }
    ql[t] = a;
  }
  __syncthreads();
  {
    float a = 0.f;
    for (int d = 0; d < CD; d++) a += ql[d] * kw[d * CD + t];
    qt_[((size_t)up * CB + b) * CD + t] = a;
  }
  red[t] = ql[t] * kb[t];
  __syncthreads();
  for (int s = 128; s > 0; s >>= 1) { if (t < s) red[t] += red[t + s]; __syncthreads(); }
  if (t == 0) qkb[up * CB + b] = red[0];
}

// sim[b][up][n]; grid (129, 16), 256 threads = 4 waves, one wave per n.
__global__ __launch_bounds__(256) void up_sim(
    const float* __restrict__ comb, const float* __restrict__ qt,
    const float* __restrict__ qkb, const float* __restrict__ pmask,
    float* __restrict__ sim)
{
  const int b = blockIdx.y, t = threadIdx.x;
  const int w = t >> 6, l = t & 63;
  __shared__ float qtl[4 * CD];
  __shared__ float qkbl[4];
  for (int i = t; i < 4 * CD; i += 256)
    qtl[i] = qt[((size_t)(i >> 8) * CB + b) * CD + (i & 255)];
  if (t < 4) qkbl[t] = qkb[t * CB + b];
  __syncthreads();
  const int n = blockIdx.x * 4 + w;
  if (n >= CNP1) return;
  float4 c4 = *(const float4*)(comb + ((size_t)b * CNP1 + n) * CD + l * 4);
  float p[4];
#pragma unroll
  for (int u = 0; u < 4; u++) {
    float4 q4 = *(const float4*)&qtl[u * CD + l * 4];
    p[u] = c4.x * q4.x + c4.y * q4.y + c4.z * q4.z + c4.w * q4.w;
  }
#pragma unroll
  for (int off = 32; off > 0; off >>= 1) {
#pragma unroll
    for (int u = 0; u < 4; u++) p[u] += __shfl_xor(p[u], off);
  }
  if (l == 0) {
    float m = (n < CN) ? pmask[b * CN + n] : 1.f;
#pragma unroll
    for (int u = 0; u < 4; u++) {
      float s = (p[u] + qkbl[u]) * 0.0625f;
      if (m == 0.f) s = 1e-8f;
      sim[((size_t)b * 4 + u) * CNP1 + n] = s;
    }
  }
}

// softmax over n: row -> exp(row-max) in place, inv = 1/sum. grid (16,4)
__global__ __launch_bounds__(256) void up_softmax(
    float* __restrict__ sim, float* __restrict__ inv)
{
  const int b = blockIdx.x, u = blockIdx.y, t = threadIdx.x;
  float* row = sim + ((size_t)b * 4 + u) * CNP1;
  __shared__ float red[256];
  float lm = -1e30f;
  for (int k = t; k < CNP1; k += 256) lm = fmaxf(lm, row[k]);
  red[t] = lm; __syncthreads();
  for (int s = 128; s > 0; s >>= 1) { if (t < s) red[t] = fmaxf(red[t], red[t + s]); __syncthreads(); }
  float mx = red[0];
  __syncthreads();
  float ls = 0.f;
  for (int k = t; k < CNP1; k += 256) { float e = __expf(row[k] - mx); row[k] = e; ls += e; }
  red[t] = ls; __syncthreads();
  for (int s = 128; s > 0; s >>= 1) { if (t < s) red[t] += red[t + s]; __syncthreads(); }
  if (t == 0) inv[b * 4 + u] = 1.f / red[0];
}

// head partials over n-chunks, atomic accumulate. grid (16, 9), 256 threads.
__global__ __launch_bounds__(256) void up_head(
    const float* __restrict__ comb, const float* __restrict__ att,
    float* __restrict__ head)
{
  const int b = blockIdx.x, n0 = blockIdx.y * 64, t = threadIdx.x;
  const int up = t >> 6, dq = t & 63;
  __shared__ float attl[4][64];
  attl[t >> 6][t & 63] = (n0 + (t & 63) < CNP1)
      ? att[((size_t)b * 4 + (t >> 6)) * CNP1 + n0 + (t & 63)] : 0.f;
  __syncthreads();
  float4 acc = make_float4(0.f, 0.f, 0.f, 0.f);
  const int nmax = min(64, CNP1 - n0);
  for (int j = 0; j < nmax; j++) {
    float a = attl[up][j];
    float4 c4 = *(const float4*)(comb + ((size_t)b * CNP1 + n0 + j) * CD + dq * 4);
    acc.x += a * c4.x; acc.y += a * c4.y; acc.z += a * c4.z; acc.w += a * c4.w;
  }
  float* hp = head + ((size_t)b * 4 + up) * CD + dq * 4;
  atomicAdd(hp + 0, acc.x); atomicAdd(hp + 1, acc.y);
  atomicAdd(hp + 2, acc.z); atomicAdd(hp + 3, acc.w);
}

// grid (16, 4): u[b][up][d]
__global__ __launch_bounds__(256) void up_out_all(
    const float* __restrict__ head, const float* __restrict__ inv,
    const float* __restrict__ ow0, const float* __restrict__ ob0,
    const float* __restrict__ ow1, const float* __restrict__ ob1,
    const float* __restrict__ ow2, const float* __restrict__ ob2,
    const float* __restrict__ ow3, const float* __restrict__ ob3,
    float* __restrict__ uout)
{
  const int b = blockIdx.x, up = blockIdx.y, t = threadIdx.x;
  const float* ow = (up == 0) ? ow0 : (up == 1) ? ow1 : (up == 2) ? ow2 : ow3;
  const float* ob = (up == 0) ? ob0 : (up == 1) ? ob1 : (up == 2) ? ob2 : ob3;
  __shared__ float hl[CD];
  hl[t] = head[((size_t)b * 4 + up) * CD + t] * inv[b * 4 + up];
  __syncthreads();
  const float* r0 = ow + (size_t)t * 4 * CD;
  float a = ob[t];
#pragma unroll 2
  for (int dd = 0; dd < CD; dd += 4) {
    float4 w0 = *(const float4*)(r0 + dd);
    float4 w1 = *(const float4*)(r0 + CD + dd);
    float4 w2 = *(const float4*)(r0 + 2 * CD + dd);
    float4 w3 = *(const float4*)(r0 + 3 * CD + dd);
    a += hl[dd]     * (w0.x + w1.x + w2.x + w3.x)
       + hl[dd + 1] * (w0.y + w1.y + w2.y + w3.y)
       + hl[dd + 2] * (w0.z + w1.z + w2.z + w3.z)
       + hl[dd + 3] * (w0.w + w1.w + w2.w + w3.w);
  }
  uout[((size_t)b * 4 + up) * CD + t] = a;
}

// ---------- U_GAT attention
__global__ __launch_bounds__(256) void ugat_attn_kern(
    const float* __restrict__ uqk, const float* __restrict__ attnw,
    float* __restrict__ u)
{
  const int b = blockIdx.x, t = threadIdx.x;
  __shared__ float uq[4][CD];
  __shared__ float sql[4][4], skl[4][4];
  for (int i = t; i < 4 * CD; i += 256) uq[i >> 8][i & 255] = uqk[(size_t)b * 4 * CD + i];
  __syncthreads();
  if (t < 32) {
    int node = t >> 3, h = (t >> 1) & 3, which = t & 1;
    const float* w = attnw + h * 128 + which * 64;
    float a = 0.f;
    for (int j = 0; j < 64; j++) a += uq[node][h * 64 + j] * w[j];
    if (which == 0) sql[node][h] = a; else skl[node][h] = a;
  }
  __syncthreads();
  const int h = t >> 6;
#pragma unroll
  for (int q = 0; q < 4; q++) {
    float e[4]; float ssum = 0.f;
#pragma unroll
    for (int k = 0; k < 4; k++) { e[k] = __expf(tanh_fast(sql[q][h] + skl[k][h])); ssum += e[k]; }
    float hid = 0.f;
#pragma unroll
    for (int k = 0; k < 4; k++) hid += e[k] * uq[k][t];
    hid = tanh_fast(hid / ssum);
    size_t idx = (size_t)b * 4 * CD + q * CD + t;
    u[idx] = u[idx] + hid;
  }
}

// ---------- MLP + classifier heads
__global__ __launch_bounds__(128) void mlp_kernel(
    const float* __restrict__ u,
    const float* __restrict__ w1, const float* __restrict__ b1,
    const float* __restrict__ w2, const float* __restrict__ b2,
    const float* __restrict__ f1w, const float* __restrict__ f1b,
    const float* __restrict__ f2w, const float* __restrict__ f2b,
    const float* __restrict__ f3w, const float* __restrict__ f3b,
    const float* __restrict__ f4w, const float* __restrict__ f4b,
    float* __restrict__ out)
{
  const int b = blockIdx.x, i = blockIdx.y, t = threadIdx.x;
  __shared__ float xl[CD];
  __shared__ float h1[CFH];
  __shared__ float h2[CFH];
  xl[t]       = u[((size_t)b * 4 + i) * CD + t];
  xl[t + 128] = u[((size_t)b * 4 + i) * CD + t + 128];
  __syncthreads();
  {
    const float* r = w1 + (size_t)t * CD;
    float a = b1[t];
#pragma unroll 4
    for (int k = 0; k < CD; k += 4) {
      float4 v = *(const float4*)(r + k);
      a += xl[k] * v.x + xl[k + 1] * v.y + xl[k + 2] * v.z + xl[k + 3] * v.w;
    }
    h1[t] = fmaxf(a, 0.f);
  }
  __syncthreads();
  {
    const float* r = w2 + (size_t)t * CFH;
    float a = b2[t];
#pragma unroll 4
    for (int k = 0; k < CFH; k += 4) {
      float4 v = *(const float4*)(r + k);
      a += h1[k] * v.x + h1[k + 1] * v.y + h1[k + 2] * v.z + h1[k + 3] * v.w;
    }
    h2[t] = fmaxf(a, 0.f);
  }
  __syncthreads();
  if (t < CNC) {
    const float* fw; const float* fb;
    switch (i) {
      case 0:  fw = f1w; fb = f1b; break;
      case 1:  fw = f2w; fb = f2b; break;
      case 2:  fw = f3w; fb = f3b; break;
      default: fw = f4w; fb = f4b; break;
    }
    const float* r = fw + (size_t)t * CFH;
    float a = fb[t];
    for (int k = 0; k < CFH; k++) a += h2[k] * r[k];
    out[(size_t)i * (CB * CNC) + b * CNC + t] = a;
  }
}

extern "C" void kernel_launch(void* const* d_in, const int* in_sizes, int n_in,
                              void* d_out, int out_size, void* d_ws, size_t ws_size,
                              hipStream_t stream) {
  (void)in_sizes; (void)n_in; (void)out_size; (void)ws_size;
  const float* pmask    = (const float*)d_in[0];
  const float* feature  = (const float*)d_in[1];
  const float* cnode    = (const float*)d_in[2];
  const float* pgat_W   = (const float*)d_in[3];
  const float* pgat_att = (const float*)d_in[4];
  const float* upw[4][6];
  for (int i = 0; i < 4; i++)
    for (int j = 0; j < 6; j++) upw[i][j] = (const float*)d_in[5 + i * 6 + j];
  const float* ugat_W   = (const float*)d_in[29];
  const float* ugat_att = (const float*)d_in[30];
  const float* mlp_w1 = (const float*)d_in[31];
  const float* mlp_b1 = (const float*)d_in[32];
  const float* mlp_w2 = (const float*)d_in[33];
  const float* mlp_b2 = (const float*)d_in[34];
  const float* fcf[8];
  for (int j = 0; j < 8; j++) fcf[j] = (const float*)d_in[35 + j];

  float* ws = (float*)d_ws;
  size_t o = 0;
  float* ws_qk   = ws + o; o += (size_t)CB * CN * CD;
  float* ws_feat = ws + o; o += (size_t)CB * CN * CD;
  float* ws_comb = ws + o; o += (size_t)CB * CNP1 * CD;
  float* ws_sq   = ws + o; o += (size_t)CB * CPH * CN;
  float* ws_sk   = ws + o; o += (size_t)CB * CPH * CN;
  float* ws_qt   = ws + o; o += (size_t)4 * CB * CD;
  float* ws_qkb  = ws + o; o += 4 * CB;
  float* ws_sim  = ws + o; o += (size_t)CB * 4 * CNP1;
  float* ws_inv  = ws + o; o += CB * 4;
  float* ws_head = ws + o; o += (size_t)CB * 4 * CD;
  float* ws_u    = ws + o; o += (size_t)CB * 4 * CD;
  float* ws_uqk  = ws + o; o += (size_t)CB * 4 * CD;

  const dim3 gemmGridBig(CD / 64, (CB * CN) / 64);
  const dim3 attnGrid(CN / 64, CPH / 2, CB);   // (8, 4, 16)

  // P_GAT layer 1
  gemm_nt<<<gemmGridBig, 256, 0, stream>>>(feature, pgat_W, nullptr, ws_qk, CB * CN, CD, CD);
  pgat_sqsk<<<dim3(CB * CN / 32), 256, 0, stream>>>(ws_qk, pgat_att, ws_sq, ws_sk);
  pgat_attn2<<<attnGrid, 256, 0, stream>>>(ws_qk, ws_sq, ws_sk, pmask, feature, ws_feat, CN);
  // P_GAT layer 2 (writes straight into comb rows, stride 513)
  gemm_nt<<<gemmGridBig, 256, 0, stream>>>(ws_feat, pgat_W, nullptr, ws_qk, CB * CN, CD, CD);
  pgat_sqsk<<<dim3(CB * CN / 32), 256, 0, stream>>>(ws_qk, pgat_att, ws_sq, ws_sk);
  pgat_attn2<<<attnGrid, 256, 0, stream>>>(ws_qk, ws_sq, ws_sk, pmask, ws_feat, ws_comb, CNP1);
  cnode_copy<<<dim3(CB), 256, 0, stream>>>(cnode, ws_comb);

  // UP_GAT x4 (no kmat GEMM)
  hipMemsetAsync(ws_head, 0, (size_t)CB * 4 * CD * sizeof(float), stream);
  up_q_all<<<dim3(4, CB), 256, 0, stream>>>(cnode,
      upw[0][0], upw[0][1], upw[0][2], upw[0][3],
      upw[1][0], upw[1][1], upw[1][2], upw[1][3],
      upw[2][0], upw[2][1], upw[2][2], upw[2][3],
      upw[3][0], upw[3][1], upw[3][2], upw[3][3],
      ws_qt, ws_qkb);
  up_sim<<<dim3((CNP1 + 3) / 4, CB), 256, 0, stream>>>(ws_comb, ws_qt, ws_qkb, pmask, ws_sim);
  up_softmax<<<dim3(CB, 4), 256, 0, stream>>>(ws_sim, ws_inv);
  up_head<<<dim3(CB, (CNP1 + 63) / 64), 256, 0, stream>>>(ws_comb, ws_sim, ws_head);
  up_out_all<<<dim3(CB, 4), 256, 0, stream>>>(ws_head, ws_inv,
      upw[0][4], upw[0][5], upw[1][4], upw[1][5],
      upw[2][4], upw[2][5], upw[3][4], upw[3][5], ws_u);

  // U_GAT
  gemm_nt<<<dim3(CD / 64, 1), 256, 0, stream>>>(ws_u, ugat_W, nullptr, ws_uqk, CB * 4, CD, CD);
  ugat_attn_kern<<<dim3(CB), 256, 0, stream>>>(ws_uqk, ugat_att, ws_u);

  // MLP + heads
  mlp_kernel<<<dim3(CB, 4), 128, 0, stream>>>(ws_u, mlp_w1, mlp_b1, mlp_w2, mlp_b2,
                                              fcf[0], fcf[1], fcf[2], fcf[3],
                                              fcf[4], fcf[5], fcf[6], fcf[7],
                                              (float*)d_out);
}

// Round 4
// 356.360 us; speedup vs baseline: 2.1548x; 1.2205x over previous
//
#include <hip/hip_runtime.h>

constexpr int CB   = 16;    // batch
constexpr int CN   = 512;   // nodes
constexpr int CD   = 256;   // dim
constexpr int CPH  = 8;     // pgat heads
constexpr int CDH  = 32;    // CD / CPH
constexpr int CNP1 = 513;   // nodes + c_node
constexpr int CFH  = 128;
constexpr int CNC  = 2;

typedef __bf16 bf16x8 __attribute__((ext_vector_type(8)));
typedef float  f32x4  __attribute__((ext_vector_type(4)));

__device__ __forceinline__ float tanh_fast(float x) {
  x = fminf(fmaxf(x, -15.f), 15.f);
  float e = __expf(2.f * x);
  return (e - 1.f) / (e + 1.f);
}

// ---------- generic fp32 GEMM: C[m,n] = sum_k A[m,k]*W[n,k] (+bias[n])
__global__ __launch_bounds__(256) void gemm_nt(
    const float* __restrict__ A, const float* __restrict__ W,
    const float* __restrict__ bias, float* __restrict__ C,
    int M, int Ncols, int K)
{
  __shared__ float As[16][68];
  __shared__ float Ws[16][68];
  const int t  = threadIdx.x;
  const int mt = blockIdx.y * 64;
  const int nt = blockIdx.x * 64;
  const int lm = t >> 4;
  const int ln = t & 15;
  const int lrow = t >> 2;
  const int lkq  = (t & 3) * 4;

  float acc[4][4];
#pragma unroll
  for (int i = 0; i < 4; i++)
#pragma unroll
    for (int j = 0; j < 4; j++) acc[i][j] = 0.f;

  for (int k0 = 0; k0 < K; k0 += 16) {
    __syncthreads();
    float4 av = make_float4(0.f, 0.f, 0.f, 0.f);
    if (mt + lrow < M)
      av = *(const float4*)(A + (size_t)(mt + lrow) * K + k0 + lkq);
    As[lkq + 0][lrow] = av.x; As[lkq + 1][lrow] = av.y;
    As[lkq + 2][lrow] = av.z; As[lkq + 3][lrow] = av.w;
    float4 wv = *(const float4*)(W + (size_t)(nt + lrow) * K + k0 + lkq);
    Ws[lkq + 0][lrow] = wv.x; Ws[lkq + 1][lrow] = wv.y;
    Ws[lkq + 2][lrow] = wv.z; Ws[lkq + 3][lrow] = wv.w;
    __syncthreads();
#pragma unroll
    for (int kk = 0; kk < 16; kk++) {
      float4 a = *(const float4*)&As[kk][lm * 4];
      float4 w = *(const float4*)&Ws[kk][ln * 4];
      acc[0][0] += a.x * w.x; acc[0][1] += a.x * w.y; acc[0][2] += a.x * w.z; acc[0][3] += a.x * w.w;
      acc[1][0] += a.y * w.x; acc[1][1] += a.y * w.y; acc[1][2] += a.y * w.z; acc[1][3] += a.y * w.w;
      acc[2][0] += a.z * w.x; acc[2][1] += a.z * w.y; acc[2][2] += a.z * w.z; acc[2][3] += a.z * w.w;
      acc[3][0] += a.w * w.x; acc[3][1] += a.w * w.y; acc[3][2] += a.w * w.z; acc[3][3] += a.w * w.w;
    }
  }
  float4 bv = make_float4(0.f, 0.f, 0.f, 0.f);
  if (bias) bv = *(const float4*)(bias + nt + ln * 4);
#pragma unroll
  for (int i = 0; i < 4; i++) {
    int m = mt + lm * 4 + i;
    if (m < M) {
      float4 v = make_float4(acc[i][0] + bv.x, acc[i][1] + bv.y,
                             acc[i][2] + bv.z, acc[i][3] + bv.w);
      *(float4*)(C + (size_t)m * Ncols + nt + ln * 4) = v;
    }
  }
}

// ---------- P_GAT sq/sk
__global__ __launch_bounds__(256) void pgat_sqsk(
    const float* __restrict__ qk, const float* __restrict__ attnw,
    float* __restrict__ sqT, float* __restrict__ skT)
{
  __shared__ float aw[CPH * 64];
  const int t = threadIdx.x;
  for (int i = t; i < CPH * 64; i += 256) aw[i] = attnw[i];
  __syncthreads();
  const int r = blockIdx.x * 32 + (t >> 3);
  const int h = t & 7;
  const float* p  = qk + (size_t)r * CD + h * CDH;
  const float* w1 = &aw[h * 64];
  const float* w2 = &aw[h * 64 + 32];
  float s1 = 0.f, s2 = 0.f;
#pragma unroll
  for (int j = 0; j < CDH; j += 4) {
    float4 v = *(const float4*)(p + j);
    s1 += v.x * w1[j] + v.y * w1[j + 1] + v.z * w1[j + 2] + v.w * w1[j + 3];
    s2 += v.x * w2[j] + v.y * w2[j + 1] + v.z * w2[j + 2] + v.w * w2[j + 3];
  }
  const int b = r >> 9, n = r & 511;
  sqT[((size_t)b * CPH + h) * CN + n] = s1;
  skT[((size_t)b * CPH + h) * CN + n] = s2;
}

// ---------- P_GAT attention via bf16 MFMA.
// grid (qt=8, h=8, b=16), 256 thr (4 waves). Block: 64 q x 32 d (1 head), K=512.
// P (=exp(tanh(sq+sk))) generated per 64-k chunk in LDS bf16; V staged transposed.
// Denominator via third MFMA against ones-fragment (same bf16 P as numerator).
__global__ __launch_bounds__(256) void pgat_attn_mfma(
    const float* __restrict__ qk, const float* __restrict__ sqT,
    const float* __restrict__ skT, const float* __restrict__ pmask,
    const float* __restrict__ fin, float* __restrict__ fout, int outStride)
{
  const int qt = blockIdx.x;
  const int h  = blockIdx.y;
  const int b  = blockIdx.z;
  const int t  = threadIdx.x;
  const int wv = t >> 6;        // wave 0..3 -> q sub-tile
  const int ln = t & 63;
  const int quad = ln >> 4;     // 0..3
  const int lc   = ln & 15;

  __shared__ __align__(16) __bf16 pbuf[64][72];   // [q][k] pad->72 (2-way banks)
  __shared__ __align__(16) __bf16 vbuf[32][72];   // [d][k] transposed
  __shared__ float skl[CN];
  __shared__ float pml[CN];
  __shared__ float sql[64];
  __shared__ float pmq[64];

  for (int i = t; i < CN; i += 256) {
    skl[i] = skT[((size_t)b * CPH + h) * CN + i];
    pml[i] = pmask[b * CN + i];
  }
  if (t < 64) {
    sql[t] = sqT[((size_t)b * CPH + h) * CN + qt * 64 + t];
    pmq[t] = pmask[b * CN + qt * 64 + t];
  }

  f32x4 accV0 = {0.f, 0.f, 0.f, 0.f};
  f32x4 accV1 = {0.f, 0.f, 0.f, 0.f};
  f32x4 accD  = {0.f, 0.f, 0.f, 0.f};
  bf16x8 ones;
#pragma unroll
  for (int j = 0; j < 8; j++) ones[j] = (__bf16)1.0f;

  const int qg = t >> 2;          // P-gen: q row 0..63
  const int kb = (t & 3) * 16;    // P-gen: k sub-block

  const int vkk = t >> 3;         // V-stage: k row 0..31
  const int vdq = (t & 7) * 4;    // V-stage: d quad

  for (int k0 = 0; k0 < CN; k0 += 64) {
    __syncthreads();
    // ---- stage V chunk (64k x 32d) transposed to vbuf[d][k], bf16
    {
      float4 v0 = *(const float4*)(qk + ((size_t)(b * CN + k0 + vkk)) * CD + h * CDH + vdq);
      float4 v1 = *(const float4*)(qk + ((size_t)(b * CN + k0 + 32 + vkk)) * CD + h * CDH + vdq);
      vbuf[vdq + 0][vkk] = (__bf16)v0.x; vbuf[vdq + 1][vkk] = (__bf16)v0.y;
      vbuf[vdq + 2][vkk] = (__bf16)v0.z; vbuf[vdq + 3][vkk] = (__bf16)v0.w;
      vbuf[vdq + 0][32 + vkk] = (__bf16)v1.x; vbuf[vdq + 1][32 + vkk] = (__bf16)v1.y;
      vbuf[vdq + 2][32 + vkk] = (__bf16)v1.z; vbuf[vdq + 3][32 + vkk] = (__bf16)v1.w;
    }
    // ---- generate P chunk: w = exp(tanh(sq+sk)) (masked -> exp(-1e-8)=1)
    {
      float sq_ = sql[qg];
      float mq  = pmq[qg];
      bf16x8 w0, w1;
#pragma unroll
      for (int j = 0; j < 8; j++) {
        float s = tanh_fast(sq_ + skl[k0 + kb + j]);
        if (mq * pml[k0 + kb + j] == 0.f) s = -1e-8f;
        w0[j] = (__bf16)__expf(s);
      }
#pragma unroll
      for (int j = 0; j < 8; j++) {
        float s = tanh_fast(sq_ + skl[k0 + kb + 8 + j]);
        if (mq * pml[k0 + kb + 8 + j] == 0.f) s = -1e-8f;
        w1[j] = (__bf16)__expf(s);
      }
      *(bf16x8*)&pbuf[qg][kb]     = w0;
      *(bf16x8*)&pbuf[qg][kb + 8] = w1;
    }
    __syncthreads();
    // ---- MFMA: wave wv owns q rows [wv*16, wv*16+16)
#pragma unroll
    for (int s = 0; s < 2; s++) {
      bf16x8 a  = *(const bf16x8*)&pbuf[wv * 16 + lc][s * 32 + quad * 8];
      bf16x8 b0 = *(const bf16x8*)&vbuf[lc][s * 32 + quad * 8];
      bf16x8 b1 = *(const bf16x8*)&vbuf[16 + lc][s * 32 + quad * 8];
      accV0 = __builtin_amdgcn_mfma_f32_16x16x32_bf16(a, b0, accV0, 0, 0, 0);
      accV1 = __builtin_amdgcn_mfma_f32_16x16x32_bf16(a, b1, accV1, 0, 0, 0);
      accD  = __builtin_amdgcn_mfma_f32_16x16x32_bf16(a, ones, accD, 0, 0, 0);
    }
  }
  // ---- epilogue: C layout col=lane&15, row=quad*4+reg
#pragma unroll
  for (int r = 0; r < 4; r++) {
    int q = qt * 64 + wv * 16 + quad * 4 + r;
    float inv = 1.f / accD[r];
    int d0 = h * CDH + lc;
    const float* ip = fin + ((size_t)b * CN + q) * CD;
    float*       op = fout + ((size_t)b * outStride + q) * CD;
    op[d0]      = ip[d0]      + tanh_fast(accV0[r] * inv);
    op[d0 + 16] = ip[d0 + 16] + tanh_fast(accV1[r] * inv);
  }
}

// ---------- append c_node row into comb
__global__ __launch_bounds__(256) void cnode_copy(
    const float* __restrict__ c, float* __restrict__ comb)
{
  int b = blockIdx.x, t = threadIdx.x;
  comb[((size_t)b * CNP1 + CN) * CD + t] = c[b * CD + t];
}

// ========== UP_GAT stage ==========

// grid (up=4, b=16), 256 threads.
__global__ __launch_bounds__(256) void up_q_all(
    const float* __restrict__ cnode,
    const float* __restrict__ qw0, const float* __restrict__ qb0,
    const float* __restrict__ kw0, const float* __restrict__ kb0,
    const float* __restrict__ qw1, const float* __restrict__ qb1,
    const float* __restrict__ kw1, const float* __restrict__ kb1,
    const float* __restrict__ qw2, const float* __restrict__ qb2,
    const float* __restrict__ kw2, const float* __restrict__ kb2,
    const float* __restrict__ qw3, const float* __restrict__ qb3,
    const float* __restrict__ kw3, const float* __restrict__ kb3,
    float* __restrict__ qt_, float* __restrict__ qkb)
{
  const int up = blockIdx.x, b = blockIdx.y, t = threadIdx.x;
  const float* qw = (up == 0) ? qw0 : (up == 1) ? qw1 : (up == 2) ? qw2 : qw3;
  const float* qb = (up == 0) ? qb0 : (up == 1) ? qb1 : (up == 2) ? qb2 : qb3;
  const float* kw = (up == 0) ? kw0 : (up == 1) ? kw1 : (up == 2) ? kw2 : kw3;
  const float* kb = (up == 0) ? kb0 : (up == 1) ? kb1 : (up == 2) ? kb2 : kb3;
  __shared__ float cl[CD];
  __shared__ float ql[CD];
  __shared__ float red[256];
  cl[t] = cnode[b * CD + t];
  __syncthreads();
  {
    const float* wr = qw + (size_t)t * CD;
    float a = qb[t];
#pragma unroll 4
    for (int k = 0; k < CD; k += 4) {
      float4 w4 = *(const float4*)(wr + k);
      a += cl[k] * w4.x + cl[k + 1] * w4.y + cl[k + 2] * w4.z + cl[k + 3] * w4.w;
    }
    ql[t] = a;
  }
  __syncthreads();
  {
    float a = 0.f;
    for (int d = 0; d < CD; d++) a += ql[d] * kw[d * CD + t];
    qt_[((size_t)up * CB + b) * CD + t] = a;
  }
  red[t] = ql[t] * kb[t];
  __syncthreads();
  for (int s = 128; s > 0; s >>= 1) { if (t < s) red[t] += red[t + s]; __syncthreads(); }
  if (t == 0) qkb[up * CB + b] = red[0];
}

// sim[b][up][n]; grid (129, 16), 256 threads = 4 waves, one wave per n.
__global__ __launch_bounds__(256) void up_sim(
    const float* __restrict__ comb, const float* __restrict__ qt,
    const float* __restrict__ qkb, const float* __restrict__ pmask,
    float* __restrict__ sim)
{
  const int b = blockIdx.y, t = threadIdx.x;
  const int w = t >> 6, l = t & 63;
  __shared__ float qtl[4 * CD];
  __shared__ float qkbl[4];
  for (int i = t; i < 4 * CD; i += 256)
    qtl[i] = qt[((size_t)(i >> 8) * CB + b) * CD + (i & 255)];
  if (t < 4) qkbl[t] = qkb[t * CB + b];
  __syncthreads();
  const int n = blockIdx.x * 4 + w;
  if (n >= CNP1) return;
  float4 c4 = *(const float4*)(comb + ((size_t)b * CNP1 + n) * CD + l * 4);
  float p[4];
#pragma unroll
  for (int u = 0; u < 4; u++) {
    float4 q4 = *(const float4*)&qtl[u * CD + l * 4];
    p[u] = c4.x * q4.x + c4.y * q4.y + c4.z * q4.z + c4.w * q4.w;
  }
#pragma unroll
  for (int off = 32; off > 0; off >>= 1) {
#pragma unroll
    for (int u = 0; u < 4; u++) p[u] += __shfl_xor(p[u], off);
  }
  if (l == 0) {
    float m = (n < CN) ? pmask[b * CN + n] : 1.f;
#pragma unroll
    for (int u = 0; u < 4; u++) {
      float s = (p[u] + qkbl[u]) * 0.0625f;
      if (m == 0.f) s = 1e-8f;
      sim[((size_t)b * 4 + u) * CNP1 + n] = s;
    }
  }
}

// softmax over n: row -> exp(row-max) in place, inv = 1/sum. grid (16,4)
__global__ __launch_bounds__(256) void up_softmax(
    float* __restrict__ sim, float* __restrict__ inv)
{
  const int b = blockIdx.x, u = blockIdx.y, t = threadIdx.x;
  float* row = sim + ((size_t)b * 4 + u) * CNP1;
  __shared__ float red[256];
  float lm = -1e30f;
  for (int k = t; k < CNP1; k += 256) lm = fmaxf(lm, row[k]);
  red[t] = lm; __syncthreads();
  for (int s = 128; s > 0; s >>= 1) { if (t < s) red[t] = fmaxf(red[t], red[t + s]); __syncthreads(); }
  float mx = red[0];
  __syncthreads();
  float ls = 0.f;
  for (int k = t; k < CNP1; k += 256) { float e = __expf(row[k] - mx); row[k] = e; ls += e; }
  red[t] = ls; __syncthreads();
  for (int s = 128; s > 0; s >>= 1) { if (t < s) red[t] += red[t + s]; __syncthreads(); }
  if (t == 0) inv[b * 4 + u] = 1.f / red[0];
}

// head partials over n-chunks, atomic accumulate. grid (16, 9), 256 threads.
__global__ __launch_bounds__(256) void up_head(
    const float* __restrict__ comb, const float* __restrict__ att,
    float* __restrict__ head)
{
  const int b = blockIdx.x, n0 = blockIdx.y * 64, t = threadIdx.x;
  const int up = t >> 6, dq = t & 63;
  __shared__ float attl[4][64];
  attl[t >> 6][t & 63] = (n0 + (t & 63) < CNP1)
      ? att[((size_t)b * 4 + (t >> 6)) * CNP1 + n0 + (t & 63)] : 0.f;
  __syncthreads();
  float4 acc = make_float4(0.f, 0.f, 0.f, 0.f);
  const int nmax = min(64, CNP1 - n0);
  for (int j = 0; j < nmax; j++) {
    float a = attl[up][j];
    float4 c4 = *(const float4*)(comb + ((size_t)b * CNP1 + n0 + j) * CD + dq * 4);
    acc.x += a * c4.x; acc.y += a * c4.y; acc.z += a * c4.z; acc.w += a * c4.w;
  }
  float* hp = head + ((size_t)b * 4 + up) * CD + dq * 4;
  atomicAdd(hp + 0, acc.x); atomicAdd(hp + 1, acc.y);
  atomicAdd(hp + 2, acc.z); atomicAdd(hp + 3, acc.w);
}

// grid (16, 4): u[b][up][d]
__global__ __launch_bounds__(256) void up_out_all(
    const float* __restrict__ head, const float* __restrict__ inv,
    const float* __restrict__ ow0, const float* __restrict__ ob0,
    const float* __restrict__ ow1, const float* __restrict__ ob1,
    const float* __restrict__ ow2, const float* __restrict__ ob2,
    const float* __restrict__ ow3, const float* __restrict__ ob3,
    float* __restrict__ uout)
{
  const int b = blockIdx.x, up = blockIdx.y, t = threadIdx.x;
  const float* ow = (up == 0) ? ow0 : (up == 1) ? ow1 : (up == 2) ? ow2 : ow3;
  const float* ob = (up == 0) ? ob0 : (up == 1) ? ob1 : (up == 2) ? ob2 : ob3;
  __shared__ float hl[CD];
  hl[t] = head[((size_t)b * 4 + up) * CD + t] * inv[b * 4 + up];
  __syncthreads();
  const float* r0 = ow + (size_t)t * 4 * CD;
  float a = ob[t];
#pragma unroll 2
  for (int dd = 0; dd < CD; dd += 4) {
    float4 w0 = *(const float4*)(r0 + dd);
    float4 w1 = *(const float4*)(r0 + CD + dd);
    float4 w2 = *(const float4*)(r0 + 2 * CD + dd);
    float4 w3 = *(const float4*)(r0 + 3 * CD + dd);
    a += hl[dd]     * (w0.x + w1.x + w2.x + w3.x)
       + hl[dd + 1] * (w0.y + w1.y + w2.y + w3.y)
       + hl[dd + 2] * (w0.z + w1.z + w2.z + w3.z)
       + hl[dd + 3] * (w0.w + w1.w + w2.w + w3.w);
  }
  uout[((size_t)b * 4 + up) * CD + t] = a;
}

// ---------- U_GAT attention
__global__ __launch_bounds__(256) void ugat_attn_kern(
    const float* __restrict__ uqk, const float* __restrict__ attnw,
    float* __restrict__ u)
{
  const int b = blockIdx.x, t = threadIdx.x;
  __shared__ float uq[4][CD];
  __shared__ float sql[4][4], skl[4][4];
  for (int i = t; i < 4 * CD; i += 256) uq[i >> 8][i & 255] = uqk[(size_t)b * 4 * CD + i];
  __syncthreads();
  if (t < 32) {
    int node = t >> 3, h = (t >> 1) & 3, which = t & 1;
    const float* w = attnw + h * 128 + which * 64;
    float a = 0.f;
    for (int j = 0; j < 64; j++) a += uq[node][h * 64 + j] * w[j];
    if (which == 0) sql[node][h] = a; else skl[node][h] = a;
  }
  __syncthreads();
  const int h = t >> 6;
#pragma unroll
  for (int q = 0; q < 4; q++) {
    float e[4]; float ssum = 0.f;
#pragma unroll
    for (int k = 0; k < 4; k++) { e[k] = __expf(tanh_fast(sql[q][h] + skl[k][h])); ssum += e[k]; }
    float hid = 0.f;
#pragma unroll
    for (int k = 0; k < 4; k++) hid += e[k] * uq[k][t];
    hid = tanh_fast(hid / ssum);
    size_t idx = (size_t)b * 4 * CD + q * CD + t;
    u[idx] = u[idx] + hid;
  }
}

// ---------- MLP + classifier heads
__global__ __launch_bounds__(128) void mlp_kernel(
    const float* __restrict__ u,
    const float* __restrict__ w1, const float* __restrict__ b1,
    const float* __restrict__ w2, const float* __restrict__ b2,
    const float* __restrict__ f1w, const float* __restrict__ f1b,
    const float* __restrict__ f2w, const float* __restrict__ f2b,
    const float* __restrict__ f3w, const float* __restrict__ f3b,
    const float* __restrict__ f4w, const float* __restrict__ f4b,
    float* __restrict__ out)
{
  const int b = blockIdx.x, i = blockIdx.y, t = threadIdx.x;
  __shared__ float xl[CD];
  __shared__ float h1[CFH];
  __shared__ float h2[CFH];
  xl[t]       = u[((size_t)b * 4 + i) * CD + t];
  xl[t + 128] = u[((size_t)b * 4 + i) * CD + t + 128];
  __syncthreads();
  {
    const float* r = w1 + (size_t)t * CD;
    float a = b1[t];
#pragma unroll 4
    for (int k = 0; k < CD; k += 4) {
      float4 v = *(const float4*)(r + k);
      a += xl[k] * v.x + xl[k + 1] * v.y + xl[k + 2] * v.z + xl[k + 3] * v.w;
    }
    h1[t] = fmaxf(a, 0.f);
  }
  __syncthreads();
  {
    const float* r = w2 + (size_t)t * CFH;
    float a = b2[t];
#pragma unroll 4
    for (int k = 0; k < CFH; k += 4) {
      float4 v = *(const float4*)(r + k);
      a += h1[k] * v.x + h1[k + 1] * v.y + h1[k + 2] * v.z + h1[k + 3] * v.w;
    }
    h2[t] = fmaxf(a, 0.f);
  }
  __syncthreads();
  if (t < CNC) {
    const float* fw; const float* fb;
    switch (i) {
      case 0:  fw = f1w; fb = f1b; break;
      case 1:  fw = f2w; fb = f2b; break;
      case 2:  fw = f3w; fb = f3b; break;
      default: fw = f4w; fb = f4b; break;
    }
    const float* r = fw + (size_t)t * CFH;
    float a = fb[t];
    for (int k = 0; k < CFH; k++) a += h2[k] * r[k];
    out[(size_t)i * (CB * CNC) + b * CNC + t] = a;
  }
}

extern "C" void kernel_launch(void* const* d_in, const int* in_sizes, int n_in,
                              void* d_out, int out_size, void* d_ws, size_t ws_size,
                              hipStream_t stream) {
  (void)in_sizes; (void)n_in; (void)out_size; (void)ws_size;
  const float* pmask    = (const float*)d_in[0];
  const float* feature  = (const float*)d_in[1];
  const float* cnode    = (const float*)d_in[2];
  const float* pgat_W   = (const float*)d_in[3];
  const float* pgat_att = (const float*)d_in[4];
  const float* upw[4][6];
  for (int i = 0; i < 4; i++)
    for (int j = 0; j < 6; j++) upw[i][j] = (const float*)d_in[5 + i * 6 + j];
  const float* ugat_W   = (const float*)d_in[29];
  const float* ugat_att = (const float*)d_in[30];
  const float* mlp_w1 = (const float*)d_in[31];
  const float* mlp_b1 = (const float*)d_in[32];
  const float* mlp_w2 = (const float*)d_in[33];
  const float* mlp_b2 = (const float*)d_in[34];
  const float* fcf[8];
  for (int j = 0; j < 8; j++) fcf[j] = (const float*)d_in[35 + j];

  float* ws = (float*)d_ws;
  size_t o = 0;
  float* ws_qk   = ws + o; o += (size_t)CB * CN * CD;
  float* ws_feat = ws + o; o += (size_t)CB * CN * CD;
  float* ws_comb = ws + o; o += (size_t)CB * CNP1 * CD;
  float* ws_sq   = ws + o; o += (size_t)CB * CPH * CN;
  float* ws_sk   = ws + o; o += (size_t)CB * CPH * CN;
  float* ws_qt   = ws + o; o += (size_t)4 * CB * CD;
  float* ws_qkb  = ws + o; o += 4 * CB;
  float* ws_sim  = ws + o; o += (size_t)CB * 4 * CNP1;
  float* ws_inv  = ws + o; o += CB * 4;
  float* ws_head = ws + o; o += (size_t)CB * 4 * CD;
  float* ws_u    = ws + o; o += (size_t)CB * 4 * CD;
  float* ws_uqk  = ws + o; o += (size_t)CB * 4 * CD;

  const dim3 gemmGridBig(CD / 64, (CB * CN) / 64);
  const dim3 attnGrid(CN / 64, CPH, CB);   // (8, 8, 16)

  // P_GAT layer 1
  gemm_nt<<<gemmGridBig, 256, 0, stream>>>(feature, pgat_W, nullptr, ws_qk, CB * CN, CD, CD);
  pgat_sqsk<<<dim3(CB * CN / 32), 256, 0, stream>>>(ws_qk, pgat_att, ws_sq, ws_sk);
  pgat_attn_mfma<<<attnGrid, 256, 0, stream>>>(ws_qk, ws_sq, ws_sk, pmask, feature, ws_feat, CN);
  // P_GAT layer 2 (writes straight into comb rows, stride 513)
  gemm_nt<<<gemmGridBig, 256, 0, stream>>>(ws_feat, pgat_W, nullptr, ws_qk, CB * CN, CD, CD);
  pgat_sqsk<<<dim3(CB * CN / 32), 256, 0, stream>>>(ws_qk, pgat_att, ws_sq, ws_sk);
  pgat_attn_mfma<<<attnGrid, 256, 0, stream>>>(ws_qk, ws_sq, ws_sk, pmask, ws_feat, ws_comb, CNP1);
  cnode_copy<<<dim3(CB), 256, 0, stream>>>(cnode, ws_comb);

  // UP_GAT x4 (no kmat GEMM)
  hipMemsetAsync(ws_head, 0, (size_t)CB * 4 * CD * sizeof(float), stream);
  up_q_all<<<dim3(4, CB), 256, 0, stream>>>(cnode,
      upw[0][0], upw[0][1], upw[0][2], upw[0][3],
      upw[1][0], upw[1][1], upw[1][2], upw[1][3],
      upw[2][0], upw[2][1], upw[2][2], upw[2][3],
      upw[3][0], upw[3][1], upw[3][2], upw[3][3],
      ws_qt, ws_qkb);
  up_sim<<<dim3((CNP1 + 3) / 4, CB), 256, 0, stream>>>(ws_comb, ws_qt, ws_qkb, pmask, ws_sim);
  up_softmax<<<dim3(CB, 4), 256, 0, stream>>>(ws_sim, ws_inv);
  up_head<<<dim3(CB, (CNP1 + 63) / 64), 256, 0, stream>>>(ws_comb, ws_sim, ws_head);
  up_out_all<<<dim3(CB, 4), 256, 0, stream>>>(ws_head, ws_inv,
      upw[0][4], upw[0][5], upw[1][4], upw[1][5],
      upw[2][4], upw[2][5], upw[3][4], upw[3][5], ws_u);

  // U_GAT
  gemm_nt<<<dim3(CD / 64, 1), 256, 0, stream>>>(ws_u, ugat_W, nullptr, ws_uqk, CB * 4, CD, CD);
  ugat_attn_kern<<<dim3(CB), 256, 0, stream>>>(ws_uqk, ugat_att, ws_u);

  // MLP + heads
  mlp_kernel<<<dim3(CB, 4), 128, 0, stream>>>(ws_u, mlp_w1, mlp_b1, mlp_w2, mlp_b2,
                                              fcf[0], fcf[1], fcf[2], fcf[3],
                                              fcf[4], fcf[5], fcf[6], fcf[7],
                                              (float*)d_out);
}

// Round 5
// 333.865 us; speedup vs baseline: 2.3000x; 1.0674x over previous
//
#include <hip/hip_runtime.h>

constexpr int CB   = 16;    // batch
constexpr int CN   = 512;   // nodes
constexpr int CD   = 256;   // dim
constexpr int CPH  = 8;     // pgat heads
constexpr int CDH  = 32;    // CD / CPH
constexpr int CNP1 = 513;   // nodes + c_node
constexpr int CFH  = 128;
constexpr int CNC  = 2;

typedef __bf16 bf16x8 __attribute__((ext_vector_type(8)));
typedef float  f32x4  __attribute__((ext_vector_type(4)));

__device__ __forceinline__ float tanh_fast(float x) {
  x = fminf(fmaxf(x, -15.f), 15.f);
  float e = __expf(2.f * x);
  return (e - 1.f) / (e + 1.f);
}

// ---------- bf16-split MFMA GEMM: C[m,n] = sum_k A[m,k] * W[n,k]
// M=8192, N=256, K=256 fixed. a = hi+lo bf16 split; 3 MFMAs per tile
// (hi*whi + hi*wlo + lo*whi; dropped lo*wlo ~2^-18 rel). 64x64 tile,
// grid (4, 128) = 512 blocks, 4 waves. LDS stride 56 bf16 = 112 B -> 2-way banks.
__global__ __launch_bounds__(256) void gemm_bf16s(
    const float* __restrict__ A, const float* __restrict__ W,
    float* __restrict__ C)
{
  const int t  = threadIdx.x;
  const int nt = blockIdx.x * 64;
  const int mt = blockIdx.y * 64;
  const int wv = t >> 6, ln = t & 63;
  const int quad = ln >> 4, lc = ln & 15;

  __shared__ __align__(16) __bf16 aHi[64][56];
  __shared__ __align__(16) __bf16 aLo[64][56];
  __shared__ __align__(16) __bf16 bHi[64][56];
  __shared__ __align__(16) __bf16 bLo[64][56];

  f32x4 acc[4];
#pragma unroll
  for (int j = 0; j < 4; j++)
#pragma unroll
    for (int r = 0; r < 4; r++) acc[j][r] = 0.f;

  const int sr  = t >> 2;        // staging row 0..63
  const int skq = (t & 3) * 8;   // staging k offset 0/8/16/24

  for (int k0 = 0; k0 < 256; k0 += 32) {
    __syncthreads();
    {
      const float* ap = A + (size_t)(mt + sr) * 256 + k0 + skq;
      const float* wp = W + (size_t)(nt + sr) * 256 + k0 + skq;
      float4 a0 = *(const float4*)ap, a1 = *(const float4*)(ap + 4);
      float4 w0 = *(const float4*)wp, w1 = *(const float4*)(wp + 4);
      float av[8] = {a0.x, a0.y, a0.z, a0.w, a1.x, a1.y, a1.z, a1.w};
      float wvv[8] = {w0.x, w0.y, w0.z, w0.w, w1.x, w1.y, w1.z, w1.w};
      bf16x8 ah, al, bh, bl;
#pragma unroll
      for (int j = 0; j < 8; j++) {
        ah[j] = (__bf16)av[j];
        al[j] = (__bf16)(av[j] - (float)ah[j]);
        bh[j] = (__bf16)wvv[j];
        bl[j] = (__bf16)(wvv[j] - (float)bh[j]);
      }
      *(bf16x8*)&aHi[sr][skq] = ah;
      *(bf16x8*)&aLo[sr][skq] = al;
      *(bf16x8*)&bHi[sr][skq] = bh;
      *(bf16x8*)&bLo[sr][skq] = bl;
    }
    __syncthreads();
    bf16x8 fah = *(const bf16x8*)&aHi[wv * 16 + lc][quad * 8];
    bf16x8 fal = *(const bf16x8*)&aLo[wv * 16 + lc][quad * 8];
#pragma unroll
    for (int j = 0; j < 4; j++) {
      bf16x8 fbh = *(const bf16x8*)&bHi[j * 16 + lc][quad * 8];
      bf16x8 fbl = *(const bf16x8*)&bLo[j * 16 + lc][quad * 8];
      acc[j] = __builtin_amdgcn_mfma_f32_16x16x32_bf16(fah, fbh, acc[j], 0, 0, 0);
      acc[j] = __builtin_amdgcn_mfma_f32_16x16x32_bf16(fah, fbl, acc[j], 0, 0, 0);
      acc[j] = __builtin_amdgcn_mfma_f32_16x16x32_bf16(fal, fbh, acc[j], 0, 0, 0);
    }
  }
  // C layout: row(m) = quad*4+r, col(n) = lc
#pragma unroll
  for (int j = 0; j < 4; j++)
#pragma unroll
    for (int r = 0; r < 4; r++)
      C[(size_t)(mt + wv * 16 + quad * 4 + r) * 256 + nt + j * 16 + lc] = acc[j][r];
}

// ---------- P_GAT sq/sk
__global__ __launch_bounds__(256) void pgat_sqsk(
    const float* __restrict__ qk, const float* __restrict__ attnw,
    float* __restrict__ sqT, float* __restrict__ skT)
{
  __shared__ float aw[CPH * 64];
  const int t = threadIdx.x;
  for (int i = t; i < CPH * 64; i += 256) aw[i] = attnw[i];
  __syncthreads();
  const int r = blockIdx.x * 32 + (t >> 3);
  const int h = t & 7;
  const float* p  = qk + (size_t)r * CD + h * CDH;
  const float* w1 = &aw[h * 64];
  const float* w2 = &aw[h * 64 + 32];
  float s1 = 0.f, s2 = 0.f;
#pragma unroll
  for (int j = 0; j < CDH; j += 4) {
    float4 v = *(const float4*)(p + j);
    s1 += v.x * w1[j] + v.y * w1[j + 1] + v.z * w1[j + 2] + v.w * w1[j + 3];
    s2 += v.x * w2[j] + v.y * w2[j + 1] + v.z * w2[j + 2] + v.w * w2[j + 3];
  }
  const int b = r >> 9, n = r & 511;
  sqT[((size_t)b * CPH + h) * CN + n] = s1;
  skT[((size_t)b * CPH + h) * CN + n] = s2;
}

// ---------- P_GAT attention via bf16 MFMA (unchanged from R4, passes)
__global__ __launch_bounds__(256) void pgat_attn_mfma(
    const float* __restrict__ qk, const float* __restrict__ sqT,
    const float* __restrict__ skT, const float* __restrict__ pmask,
    const float* __restrict__ fin, float* __restrict__ fout, int outStride)
{
  const int qt = blockIdx.x;
  const int h  = blockIdx.y;
  const int b  = blockIdx.z;
  const int t  = threadIdx.x;
  const int wv = t >> 6;
  const int ln = t & 63;
  const int quad = ln >> 4;
  const int lc   = ln & 15;

  __shared__ __align__(16) __bf16 pbuf[64][72];
  __shared__ __align__(16) __bf16 vbuf[32][72];
  __shared__ float skl[CN];
  __shared__ float pml[CN];
  __shared__ float sql[64];
  __shared__ float pmq[64];

  for (int i = t; i < CN; i += 256) {
    skl[i] = skT[((size_t)b * CPH + h) * CN + i];
    pml[i] = pmask[b * CN + i];
  }
  if (t < 64) {
    sql[t] = sqT[((size_t)b * CPH + h) * CN + qt * 64 + t];
    pmq[t] = pmask[b * CN + qt * 64 + t];
  }

  f32x4 accV0 = {0.f, 0.f, 0.f, 0.f};
  f32x4 accV1 = {0.f, 0.f, 0.f, 0.f};
  f32x4 accD  = {0.f, 0.f, 0.f, 0.f};
  bf16x8 ones;
#pragma unroll
  for (int j = 0; j < 8; j++) ones[j] = (__bf16)1.0f;

  const int qg = t >> 2;
  const int kb = (t & 3) * 16;
  const int vkk = t >> 3;
  const int vdq = (t & 7) * 4;

  for (int k0 = 0; k0 < CN; k0 += 64) {
    __syncthreads();
    {
      float4 v0 = *(const float4*)(qk + ((size_t)(b * CN + k0 + vkk)) * CD + h * CDH + vdq);
      float4 v1 = *(const float4*)(qk + ((size_t)(b * CN + k0 + 32 + vkk)) * CD + h * CDH + vdq);
      vbuf[vdq + 0][vkk] = (__bf16)v0.x; vbuf[vdq + 1][vkk] = (__bf16)v0.y;
      vbuf[vdq + 2][vkk] = (__bf16)v0.z; vbuf[vdq + 3][vkk] = (__bf16)v0.w;
      vbuf[vdq + 0][32 + vkk] = (__bf16)v1.x; vbuf[vdq + 1][32 + vkk] = (__bf16)v1.y;
      vbuf[vdq + 2][32 + vkk] = (__bf16)v1.z; vbuf[vdq + 3][32 + vkk] = (__bf16)v1.w;
    }
    {
      float sq_ = sql[qg];
      float mq  = pmq[qg];
      bf16x8 w0, w1;
#pragma unroll
      for (int j = 0; j < 8; j++) {
        float s = tanh_fast(sq_ + skl[k0 + kb + j]);
        if (mq * pml[k0 + kb + j] == 0.f) s = -1e-8f;
        w0[j] = (__bf16)__expf(s);
      }
#pragma unroll
      for (int j = 0; j < 8; j++) {
        float s = tanh_fast(sq_ + skl[k0 + kb + 8 + j]);
        if (mq * pml[k0 + kb + 8 + j] == 0.f) s = -1e-8f;
        w1[j] = (__bf16)__expf(s);
      }
      *(bf16x8*)&pbuf[qg][kb]     = w0;
      *(bf16x8*)&pbuf[qg][kb + 8] = w1;
    }
    __syncthreads();
#pragma unroll
    for (int s = 0; s < 2; s++) {
      bf16x8 a  = *(const bf16x8*)&pbuf[wv * 16 + lc][s * 32 + quad * 8];
      bf16x8 b0 = *(const bf16x8*)&vbuf[lc][s * 32 + quad * 8];
      bf16x8 b1 = *(const bf16x8*)&vbuf[16 + lc][s * 32 + quad * 8];
      accV0 = __builtin_amdgcn_mfma_f32_16x16x32_bf16(a, b0, accV0, 0, 0, 0);
      accV1 = __builtin_amdgcn_mfma_f32_16x16x32_bf16(a, b1, accV1, 0, 0, 0);
      accD  = __builtin_amdgcn_mfma_f32_16x16x32_bf16(a, ones, accD, 0, 0, 0);
    }
  }
#pragma unroll
  for (int r = 0; r < 4; r++) {
    int q = qt * 64 + wv * 16 + quad * 4 + r;
    float inv = 1.f / accD[r];
    int d0 = h * CDH + lc;
    const float* ip = fin + ((size_t)b * CN + q) * CD;
    float*       op = fout + ((size_t)b * outStride + q) * CD;
    op[d0]      = ip[d0]      + tanh_fast(accV0[r] * inv);
    op[d0 + 16] = ip[d0 + 16] + tanh_fast(accV1[r] * inv);
  }
}

// ========== UP_GAT stage ==========

// grid (up=4, b=16), 256 threads. Also: copies c_node into comb row 512
// (up==0 blocks) and zeroes head/den accumulators.
__global__ __launch_bounds__(256) void up_q_all(
    const float* __restrict__ cnode,
    const float* __restrict__ qw0, const float* __restrict__ qb0,
    const float* __restrict__ kw0, const float* __restrict__ kb0,
    const float* __restrict__ qw1, const float* __restrict__ qb1,
    const float* __restrict__ kw1, const float* __restrict__ kb1,
    const float* __restrict__ qw2, const float* __restrict__ qb2,
    const float* __restrict__ kw2, const float* __restrict__ kb2,
    const float* __restrict__ qw3, const float* __restrict__ qb3,
    const float* __restrict__ kw3, const float* __restrict__ kb3,
    float* __restrict__ qt_, float* __restrict__ qkb,
    float* __restrict__ comb, float* __restrict__ head, float* __restrict__ den)
{
  const int up = blockIdx.x, b = blockIdx.y, t = threadIdx.x;
  const float* qw = (up == 0) ? qw0 : (up == 1) ? qw1 : (up == 2) ? qw2 : qw3;
  const float* qb = (up == 0) ? qb0 : (up == 1) ? qb1 : (up == 2) ? qb2 : qb3;
  const float* kw = (up == 0) ? kw0 : (up == 1) ? kw1 : (up == 2) ? kw2 : kw3;
  const float* kb = (up == 0) ? kb0 : (up == 1) ? kb1 : (up == 2) ? kb2 : kb3;
  __shared__ float cl[CD];
  __shared__ float ql[CD];
  __shared__ float red[256];
  cl[t] = cnode[b * CD + t];
  // zero accumulators for up_head
  head[((size_t)b * 4 + up) * CD + t] = 0.f;
  if (t == 0) den[b * 4 + up] = 0.f;
  __syncthreads();
  if (up == 0) comb[((size_t)b * CNP1 + CN) * CD + t] = cl[t];
  {
    const float* wr = qw + (size_t)t * CD;
    float a = qb[t];
#pragma unroll 4
    for (int k = 0; k < CD; k += 4) {
      float4 w4 = *(const float4*)(wr + k);
      a += cl[k] * w4.x + cl[k + 1] * w4.y + cl[k + 2] * w4.z + cl[k + 3] * w4.w;
    }
    ql[t] = a;
  }
  __syncthreads();
  {
    float a = 0.f;
    for (int d = 0; d < CD; d++) a += ql[d] * kw[d * CD + t];
    qt_[((size_t)up * CB + b) * CD + t] = a;
  }
  red[t] = ql[t] * kb[t];
  __syncthreads();
  for (int s = 128; s > 0; s >>= 1) { if (t < s) red[t] += red[t + s]; __syncthreads(); }
  if (t == 0) qkb[up * CB + b] = red[0];
}

// raw sim[b][up][n]; grid (129, 16), 4 waves, one wave per n.
__global__ __launch_bounds__(256) void up_sim(
    const float* __restrict__ comb, const float* __restrict__ qt,
    const float* __restrict__ qkb, const float* __restrict__ pmask,
    float* __restrict__ sim)
{
  const int b = blockIdx.y, t = threadIdx.x;
  const int w = t >> 6, l = t & 63;
  __shared__ float qtl[4 * CD];
  __shared__ float qkbl[4];
  for (int i = t; i < 4 * CD; i += 256)
    qtl[i] = qt[((size_t)(i >> 8) * CB + b) * CD + (i & 255)];
  if (t < 4) qkbl[t] = qkb[t * CB + b];
  __syncthreads();
  const int n = blockIdx.x * 4 + w;
  if (n >= CNP1) return;
  float4 c4 = *(const float4*)(comb + ((size_t)b * CNP1 + n) * CD + l * 4);
  float p[4];
#pragma unroll
  for (int u = 0; u < 4; u++) {
    float4 q4 = *(const float4*)&qtl[u * CD + l * 4];
    p[u] = c4.x * q4.x + c4.y * q4.y + c4.z * q4.z + c4.w * q4.w;
  }
#pragma unroll
  for (int off = 32; off > 0; off >>= 1) {
#pragma unroll
    for (int u = 0; u < 4; u++) p[u] += __shfl_xor(p[u], off);
  }
  if (l == 0) {
    float m = (n < CN) ? pmask[b * CN + n] : 1.f;
#pragma unroll
    for (int u = 0; u < 4; u++) {
      float s = (p[u] + qkbl[u]) * 0.0625f;
      if (m == 0.f) s = 1e-8f;
      sim[((size_t)b * 4 + u) * CNP1 + n] = s;
    }
  }
}

// head += sum_n exp(sim)*comb ; den += sum_n exp(sim). grid (16,9).
// (exp without max-subtraction: scores are O(1), fp32 exp safe)
__global__ __launch_bounds__(256) void up_head(
    const float* __restrict__ comb, const float* __restrict__ sim,
    float* __restrict__ head, float* __restrict__ den)
{
  const int b = blockIdx.x, n0 = blockIdx.y * 64, t = threadIdx.x;
  const int up = t >> 6, dq = t & 63;
  __shared__ float attl[4][64];
  {
    int u = t >> 6, j = t & 63;
    attl[u][j] = (n0 + j < CNP1)
        ? __expf(sim[((size_t)b * 4 + u) * CNP1 + n0 + j]) : 0.f;
  }
  __syncthreads();
  float4 acc = make_float4(0.f, 0.f, 0.f, 0.f);
  const int nmax = min(64, CNP1 - n0);
  for (int j = 0; j < nmax; j++) {
    float a = attl[up][j];
    float4 c4 = *(const float4*)(comb + ((size_t)b * CNP1 + n0 + j) * CD + dq * 4);
    acc.x += a * c4.x; acc.y += a * c4.y; acc.z += a * c4.z; acc.w += a * c4.w;
  }
  float* hp = head + ((size_t)b * 4 + up) * CD + dq * 4;
  atomicAdd(hp + 0, acc.x); atomicAdd(hp + 1, acc.y);
  atomicAdd(hp + 2, acc.z); atomicAdd(hp + 3, acc.w);
  if (dq == 0) {
    float s = 0.f;
    for (int j = 0; j < 64; j++) s += attl[up][j];
    atomicAdd(den + b * 4 + up, s);
  }
}

// grid (16, 4): u[b][up][d]
__global__ __launch_bounds__(256) void up_out_all(
    const float* __restrict__ head, const float* __restrict__ den,
    const float* __restrict__ ow0, const float* __restrict__ ob0,
    const float* __restrict__ ow1, const float* __restrict__ ob1,
    const float* __restrict__ ow2, const float* __restrict__ ob2,
    const float* __restrict__ ow3, const float* __restrict__ ob3,
    float* __restrict__ uout)
{
  const int b = blockIdx.x, up = blockIdx.y, t = threadIdx.x;
  const float* ow = (up == 0) ? ow0 : (up == 1) ? ow1 : (up == 2) ? ow2 : ow3;
  const float* ob = (up == 0) ? ob0 : (up == 1) ? ob1 : (up == 2) ? ob2 : ob3;
  __shared__ float hl[CD];
  hl[t] = head[((size_t)b * 4 + up) * CD + t] * (1.f / den[b * 4 + up]);
  __syncthreads();
  const float* r0 = ow + (size_t)t * 4 * CD;
  float a = ob[t];
#pragma unroll 2
  for (int dd = 0; dd < CD; dd += 4) {
    float4 w0 = *(const float4*)(r0 + dd);
    float4 w1 = *(const float4*)(r0 + CD + dd);
    float4 w2 = *(const float4*)(r0 + 2 * CD + dd);
    float4 w3 = *(const float4*)(r0 + 3 * CD + dd);
    a += hl[dd]     * (w0.x + w1.x + w2.x + w3.x)
       + hl[dd + 1] * (w0.y + w1.y + w2.y + w3.y)
       + hl[dd + 2] * (w0.z + w1.z + w2.z + w3.z)
       + hl[dd + 3] * (w0.w + w1.w + w2.w + w3.w);
  }
  uout[((size_t)b * 4 + up) * CD + t] = a;
}

// ---------- fused U_GAT (gemm + attention + residual) + MLP + fcf heads.
// grid (16), 256 threads.
__global__ __launch_bounds__(256) void ugat_mlp(
    const float* __restrict__ u, const float* __restrict__ ugat_W,
    const float* __restrict__ attnw,
    const float* __restrict__ w1, const float* __restrict__ b1,
    const float* __restrict__ w2, const float* __restrict__ b2,
    const float* __restrict__ f1w, const float* __restrict__ f1b,
    const float* __restrict__ f2w, const float* __restrict__ f2b,
    const float* __restrict__ f3w, const float* __restrict__ f3b,
    const float* __restrict__ f4w, const float* __restrict__ f4b,
    float* __restrict__ out)
{
  const int b = blockIdx.x, t = threadIdx.x;
  __shared__ float ul[4][CD];
  __shared__ float uqk[4][CD];
  __shared__ float sql[4][4], skl[4][4];
  __shared__ float h1[4][CFH];
  __shared__ float h2[4][CFH];

  for (int i = t; i < 4 * CD; i += 256) ul[i >> 8][i & 255] = u[(size_t)b * 4 * CD + i];
  __syncthreads();
  // uqk[node][t] = sum_d ul[node][d] * W[t][d]
  {
    const float* wr = ugat_W + (size_t)t * CD;
    float a0 = 0.f, a1 = 0.f, a2 = 0.f, a3 = 0.f;
#pragma unroll 4
    for (int d = 0; d < CD; d += 4) {
      float4 w4 = *(const float4*)(wr + d);
      a0 += ul[0][d] * w4.x + ul[0][d + 1] * w4.y + ul[0][d + 2] * w4.z + ul[0][d + 3] * w4.w;
      a1 += ul[1][d] * w4.x + ul[1][d + 1] * w4.y + ul[1][d + 2] * w4.z + ul[1][d + 3] * w4.w;
      a2 += ul[2][d] * w4.x + ul[2][d + 1] * w4.y + ul[2][d + 2] * w4.z + ul[2][d + 3] * w4.w;
      a3 += ul[3][d] * w4.x + ul[3][d + 1] * w4.y + ul[3][d + 2] * w4.z + ul[3][d + 3] * w4.w;
    }
    uqk[0][t] = a0; uqk[1][t] = a1; uqk[2][t] = a2; uqk[3][t] = a3;
  }
  __syncthreads();
  if (t < 32) {
    int node = t >> 3, h = (t >> 1) & 3, which = t & 1;
    const float* w = attnw + h * 128 + which * 64;
    float a = 0.f;
    for (int j = 0; j < 64; j++) a += uqk[node][h * 64 + j] * w[j];
    if (which == 0) sql[node][h] = a; else skl[node][h] = a;
  }
  __syncthreads();
  {
    const int h = t >> 6;
#pragma unroll
    for (int q = 0; q < 4; q++) {
      float e[4]; float ssum = 0.f;
#pragma unroll
      for (int k = 0; k < 4; k++) { e[k] = __expf(tanh_fast(sql[q][h] + skl[k][h])); ssum += e[k]; }
      float hid = 0.f;
#pragma unroll
      for (int k = 0; k < 4; k++) hid += e[k] * uqk[k][t];
      ul[q][t] = ul[q][t] + tanh_fast(hid / ssum);
    }
  }
  __syncthreads();
  // MLP: h1 = relu(x@w1.T+b1), h2 = relu(h1@w2.T+b2); 2 traits per pass
  {
    const int j = t & 127;
#pragma unroll
    for (int pass = 0; pass < 2; pass++) {
      const int trait = pass * 2 + (t >> 7);
      const float* r = w1 + (size_t)j * CD;
      float a = b1[j];
#pragma unroll 4
      for (int k = 0; k < CD; k += 4) {
        float4 v = *(const float4*)(r + k);
        a += ul[trait][k] * v.x + ul[trait][k + 1] * v.y
           + ul[trait][k + 2] * v.z + ul[trait][k + 3] * v.w;
      }
      h1[trait][j] = fmaxf(a, 0.f);
    }
    __syncthreads();
#pragma unroll
    for (int pass = 0; pass < 2; pass++) {
      const int trait = pass * 2 + (t >> 7);
      const float* r = w2 + (size_t)j * CFH;
      float a = b2[j];
#pragma unroll 4
      for (int k = 0; k < CFH; k += 4) {
        float4 v = *(const float4*)(r + k);
        a += h1[trait][k] * v.x + h1[trait][k + 1] * v.y
           + h1[trait][k + 2] * v.z + h1[trait][k + 3] * v.w;
      }
      h2[trait][j] = fmaxf(a, 0.f);
    }
  }
  __syncthreads();
  if (t < 8) {
    const int trait = t >> 1, c = t & 1;
    const float* fw; const float* fb;
    switch (trait) {
      case 0:  fw = f1w; fb = f1b; break;
      case 1:  fw = f2w; fb = f2b; break;
      case 2:  fw = f3w; fb = f3b; break;
      default: fw = f4w; fb = f4b; break;
    }
    const float* r = fw + (size_t)c * CFH;
    float a = fb[c];
    for (int k = 0; k < CFH; k++) a += h2[trait][k] * r[k];
    out[(size_t)trait * (CB * CNC) + b * CNC + c] = a;
  }
}

extern "C" void kernel_launch(void* const* d_in, const int* in_sizes, int n_in,
                              void* d_out, int out_size, void* d_ws, size_t ws_size,
                              hipStream_t stream) {
  (void)in_sizes; (void)n_in; (void)out_size; (void)ws_size;
  const float* pmask    = (const float*)d_in[0];
  const float* feature  = (const float*)d_in[1];
  const float* cnode    = (const float*)d_in[2];
  const float* pgat_W   = (const float*)d_in[3];
  const float* pgat_att = (const float*)d_in[4];
  const float* upw[4][6];
  for (int i = 0; i < 4; i++)
    for (int j = 0; j < 6; j++) upw[i][j] = (const float*)d_in[5 + i * 6 + j];
  const float* ugat_W   = (const float*)d_in[29];
  const float* ugat_att = (const float*)d_in[30];
  const float* mlp_w1 = (const float*)d_in[31];
  const float* mlp_b1 = (const float*)d_in[32];
  const float* mlp_w2 = (const float*)d_in[33];
  const float* mlp_b2 = (const float*)d_in[34];
  const float* fcf[8];
  for (int j = 0; j < 8; j++) fcf[j] = (const float*)d_in[35 + j];

  float* ws = (float*)d_ws;
  size_t o = 0;
  float* ws_qk   = ws + o; o += (size_t)CB * CN * CD;
  float* ws_feat = ws + o; o += (size_t)CB * CN * CD;
  float* ws_comb = ws + o; o += (size_t)CB * CNP1 * CD;
  float* ws_sq   = ws + o; o += (size_t)CB * CPH * CN;
  float* ws_sk   = ws + o; o += (size_t)CB * CPH * CN;
  float* ws_qt   = ws + o; o += (size_t)4 * CB * CD;
  float* ws_qkb  = ws + o; o += 4 * CB;
  float* ws_sim  = ws + o; o += (size_t)CB * 4 * CNP1;
  float* ws_den  = ws + o; o += CB * 4;
  float* ws_head = ws + o; o += (size_t)CB * 4 * CD;
  float* ws_u    = ws + o; o += (size_t)CB * 4 * CD;

  const dim3 gemmGrid(CD / 64, (CB * CN) / 64);   // (4, 128)
  const dim3 attnGrid(CN / 64, CPH, CB);          // (8, 8, 16)

  // P_GAT layer 1
  gemm_bf16s<<<gemmGrid, 256, 0, stream>>>(feature, pgat_W, ws_qk);
  pgat_sqsk<<<dim3(CB * CN / 32), 256, 0, stream>>>(ws_qk, pgat_att, ws_sq, ws_sk);
  pgat_attn_mfma<<<attnGrid, 256, 0, stream>>>(ws_qk, ws_sq, ws_sk, pmask, feature, ws_feat, CN);
  // P_GAT layer 2 (writes into comb rows, stride 513)
  gemm_bf16s<<<gemmGrid, 256, 0, stream>>>(ws_feat, pgat_W, ws_qk);
  pgat_sqsk<<<dim3(CB * CN / 32), 256, 0, stream>>>(ws_qk, pgat_att, ws_sq, ws_sk);
  pgat_attn_mfma<<<attnGrid, 256, 0, stream>>>(ws_qk, ws_sq, ws_sk, pmask, ws_feat, ws_comb, CNP1);

  // UP_GAT x4 (also: cnode->comb row 512, zero head/den)
  up_q_all<<<dim3(4, CB), 256, 0, stream>>>(cnode,
      upw[0][0], upw[0][1], upw[0][2], upw[0][3],
      upw[1][0], upw[1][1], upw[1][2], upw[1][3],
      upw[2][0], upw[2][1], upw[2][2], upw[2][3],
      upw[3][0], upw[3][1], upw[3][2], upw[3][3],
      ws_qt, ws_qkb, ws_comb, ws_head, ws_den);
  up_sim<<<dim3((CNP1 + 3) / 4, CB), 256, 0, stream>>>(ws_comb, ws_qt, ws_qkb, pmask, ws_sim);
  up_head<<<dim3(CB, (CNP1 + 63) / 64), 256, 0, stream>>>(ws_comb, ws_sim, ws_head, ws_den);
  up_out_all<<<dim3(CB, 4), 256, 0, stream>>>(ws_head, ws_den,
      upw[0][4], upw[0][5], upw[1][4], upw[1][5],
      upw[2][4], upw[2][5], upw[3][4], upw[3][5], ws_u);

  // U_GAT + MLP + heads (fused)
  ugat_mlp<<<dim3(CB), 256, 0, stream>>>(ws_u, ugat_W, ugat_att,
                                         mlp_w1, mlp_b1, mlp_w2, mlp_b2,
                                         fcf[0], fcf[1], fcf[2], fcf[3],
                                         fcf[4], fcf[5], fcf[6], fcf[7],
                                         (float*)d_out);
}

// Round 6
// 323.846 us; speedup vs baseline: 2.3712x; 1.0309x over previous
//
#include <hip/hip_runtime.h>

constexpr int CB   = 16;    // batch
constexpr int CN   = 512;   // nodes
constexpr int CD   = 256;   // dim
constexpr int CPH  = 8;     // pgat heads
constexpr int CDH  = 32;    // CD / CPH
constexpr int CNP1 = 513;   // nodes + c_node
constexpr int CFH  = 128;
constexpr int CNC  = 2;

typedef __bf16 bf16x8 __attribute__((ext_vector_type(8)));
typedef float  f32x4  __attribute__((ext_vector_type(4)));

__device__ __forceinline__ float tanh_fast(float x) {
  x = fminf(fmaxf(x, -15.f), 15.f);
  float e = __expf(2.f * x);
  return (e - 1.f) / (e + 1.f);
}

// ---------- bf16-split MFMA GEMM: C[m,n] = sum_k A[m,k] * W[n,k]
__global__ __launch_bounds__(256) void gemm_bf16s(
    const float* __restrict__ A, const float* __restrict__ W,
    float* __restrict__ C)
{
  const int t  = threadIdx.x;
  const int nt = blockIdx.x * 64;
  const int mt = blockIdx.y * 64;
  const int wv = t >> 6, ln = t & 63;
  const int quad = ln >> 4, lc = ln & 15;

  __shared__ __align__(16) __bf16 aHi[64][56];
  __shared__ __align__(16) __bf16 aLo[64][56];
  __shared__ __align__(16) __bf16 bHi[64][56];
  __shared__ __align__(16) __bf16 bLo[64][56];

  f32x4 acc[4];
#pragma unroll
  for (int j = 0; j < 4; j++)
#pragma unroll
    for (int r = 0; r < 4; r++) acc[j][r] = 0.f;

  const int sr  = t >> 2;
  const int skq = (t & 3) * 8;

  for (int k0 = 0; k0 < 256; k0 += 32) {
    __syncthreads();
    {
      const float* ap = A + (size_t)(mt + sr) * 256 + k0 + skq;
      const float* wp = W + (size_t)(nt + sr) * 256 + k0 + skq;
      float4 a0 = *(const float4*)ap, a1 = *(const float4*)(ap + 4);
      float4 w0 = *(const float4*)wp, w1 = *(const float4*)(wp + 4);
      float av[8] = {a0.x, a0.y, a0.z, a0.w, a1.x, a1.y, a1.z, a1.w};
      float wvv[8] = {w0.x, w0.y, w0.z, w0.w, w1.x, w1.y, w1.z, w1.w};
      bf16x8 ah, al, bh, bl;
#pragma unroll
      for (int j = 0; j < 8; j++) {
        ah[j] = (__bf16)av[j];
        al[j] = (__bf16)(av[j] - (float)ah[j]);
        bh[j] = (__bf16)wvv[j];
        bl[j] = (__bf16)(wvv[j] - (float)bh[j]);
      }
      *(bf16x8*)&aHi[sr][skq] = ah;
      *(bf16x8*)&aLo[sr][skq] = al;
      *(bf16x8*)&bHi[sr][skq] = bh;
      *(bf16x8*)&bLo[sr][skq] = bl;
    }
    __syncthreads();
    bf16x8 fah = *(const bf16x8*)&aHi[wv * 16 + lc][quad * 8];
    bf16x8 fal = *(const bf16x8*)&aLo[wv * 16 + lc][quad * 8];
#pragma unroll
    for (int j = 0; j < 4; j++) {
      bf16x8 fbh = *(const bf16x8*)&bHi[j * 16 + lc][quad * 8];
      bf16x8 fbl = *(const bf16x8*)&bLo[j * 16 + lc][quad * 8];
      acc[j] = __builtin_amdgcn_mfma_f32_16x16x32_bf16(fah, fbh, acc[j], 0, 0, 0);
      acc[j] = __builtin_amdgcn_mfma_f32_16x16x32_bf16(fah, fbl, acc[j], 0, 0, 0);
      acc[j] = __builtin_amdgcn_mfma_f32_16x16x32_bf16(fal, fbh, acc[j], 0, 0, 0);
    }
  }
#pragma unroll
  for (int j = 0; j < 4; j++)
#pragma unroll
    for (int r = 0; r < 4; r++)
      C[(size_t)(mt + wv * 16 + quad * 4 + r) * 256 + nt + j * 16 + lc] = acc[j][r];
}

// ---------- P_GAT sq/sk
__global__ __launch_bounds__(256) void pgat_sqsk(
    const float* __restrict__ qk, const float* __restrict__ attnw,
    float* __restrict__ sqT, float* __restrict__ skT)
{
  __shared__ float aw[CPH * 64];
  const int t = threadIdx.x;
  for (int i = t; i < CPH * 64; i += 256) aw[i] = attnw[i];
  __syncthreads();
  const int r = blockIdx.x * 32 + (t >> 3);
  const int h = t & 7;
  const float* p  = qk + (size_t)r * CD + h * CDH;
  const float* w1 = &aw[h * 64];
  const float* w2 = &aw[h * 64 + 32];
  float s1 = 0.f, s2 = 0.f;
#pragma unroll
  for (int j = 0; j < CDH; j += 4) {
    float4 v = *(const float4*)(p + j);
    s1 += v.x * w1[j] + v.y * w1[j + 1] + v.z * w1[j + 2] + v.w * w1[j + 3];
    s2 += v.x * w2[j] + v.y * w2[j + 1] + v.z * w2[j + 2] + v.w * w2[j + 3];
  }
  const int b = r >> 9, n = r & 511;
  sqT[((size_t)b * CPH + h) * CN + n] = s1;
  skT[((size_t)b * CPH + h) * CN + n] = s2;
}

// ---------- P_GAT attention via bf16 MFMA
__global__ __launch_bounds__(256) void pgat_attn_mfma(
    const float* __restrict__ qk, const float* __restrict__ sqT,
    const float* __restrict__ skT, const float* __restrict__ pmask,
    const float* __restrict__ fin, float* __restrict__ fout, int outStride)
{
  const int qt = blockIdx.x;
  const int h  = blockIdx.y;
  const int b  = blockIdx.z;
  const int t  = threadIdx.x;
  const int wv = t >> 6;
  const int ln = t & 63;
  const int quad = ln >> 4;
  const int lc   = ln & 15;

  __shared__ __align__(16) __bf16 pbuf[64][72];
  __shared__ __align__(16) __bf16 vbuf[32][72];
  __shared__ float skl[CN];
  __shared__ float pml[CN];
  __shared__ float sql[64];
  __shared__ float pmq[64];

  for (int i = t; i < CN; i += 256) {
    skl[i] = skT[((size_t)b * CPH + h) * CN + i];
    pml[i] = pmask[b * CN + i];
  }
  if (t < 64) {
    sql[t] = sqT[((size_t)b * CPH + h) * CN + qt * 64 + t];
    pmq[t] = pmask[b * CN + qt * 64 + t];
  }

  f32x4 accV0 = {0.f, 0.f, 0.f, 0.f};
  f32x4 accV1 = {0.f, 0.f, 0.f, 0.f};
  f32x4 accD  = {0.f, 0.f, 0.f, 0.f};
  bf16x8 ones;
#pragma unroll
  for (int j = 0; j < 8; j++) ones[j] = (__bf16)1.0f;

  const int qg = t >> 2;
  const int kb = (t & 3) * 16;
  const int vkk = t >> 3;
  const int vdq = (t & 7) * 4;

  for (int k0 = 0; k0 < CN; k0 += 64) {
    __syncthreads();
    {
      float4 v0 = *(const float4*)(qk + ((size_t)(b * CN + k0 + vkk)) * CD + h * CDH + vdq);
      float4 v1 = *(const float4*)(qk + ((size_t)(b * CN + k0 + 32 + vkk)) * CD + h * CDH + vdq);
      vbuf[vdq + 0][vkk] = (__bf16)v0.x; vbuf[vdq + 1][vkk] = (__bf16)v0.y;
      vbuf[vdq + 2][vkk] = (__bf16)v0.z; vbuf[vdq + 3][vkk] = (__bf16)v0.w;
      vbuf[vdq + 0][32 + vkk] = (__bf16)v1.x; vbuf[vdq + 1][32 + vkk] = (__bf16)v1.y;
      vbuf[vdq + 2][32 + vkk] = (__bf16)v1.z; vbuf[vdq + 3][32 + vkk] = (__bf16)v1.w;
    }
    {
      float sq_ = sql[qg];
      float mq  = pmq[qg];
      bf16x8 w0, w1;
#pragma unroll
      for (int j = 0; j < 8; j++) {
        float s = tanh_fast(sq_ + skl[k0 + kb + j]);
        if (mq * pml[k0 + kb + j] == 0.f) s = -1e-8f;
        w0[j] = (__bf16)__expf(s);
      }
#pragma unroll
      for (int j = 0; j < 8; j++) {
        float s = tanh_fast(sq_ + skl[k0 + kb + 8 + j]);
        if (mq * pml[k0 + kb + 8 + j] == 0.f) s = -1e-8f;
        w1[j] = (__bf16)__expf(s);
      }
      *(bf16x8*)&pbuf[qg][kb]     = w0;
      *(bf16x8*)&pbuf[qg][kb + 8] = w1;
    }
    __syncthreads();
#pragma unroll
    for (int s = 0; s < 2; s++) {
      bf16x8 a  = *(const bf16x8*)&pbuf[wv * 16 + lc][s * 32 + quad * 8];
      bf16x8 b0 = *(const bf16x8*)&vbuf[lc][s * 32 + quad * 8];
      bf16x8 b1 = *(const bf16x8*)&vbuf[16 + lc][s * 32 + quad * 8];
      accV0 = __builtin_amdgcn_mfma_f32_16x16x32_bf16(a, b0, accV0, 0, 0, 0);
      accV1 = __builtin_amdgcn_mfma_f32_16x16x32_bf16(a, b1, accV1, 0, 0, 0);
      accD  = __builtin_amdgcn_mfma_f32_16x16x32_bf16(a, ones, accD, 0, 0, 0);
    }
  }
#pragma unroll
  for (int r = 0; r < 4; r++) {
    int q = qt * 64 + wv * 16 + quad * 4 + r;
    float inv = 1.f / accD[r];
    int d0 = h * CDH + lc;
    const float* ip = fin + ((size_t)b * CN + q) * CD;
    float*       op = fout + ((size_t)b * outStride + q) * CD;
    op[d0]      = ip[d0]      + tanh_fast(accV0[r] * inv);
    op[d0 + 16] = ip[d0 + 16] + tanh_fast(accV1[r] * inv);
  }
}

// ========== UP_GAT stage ==========

__global__ __launch_bounds__(256) void up_q_all(
    const float* __restrict__ cnode,
    const float* __restrict__ qw0, const float* __restrict__ qb0,
    const float* __restrict__ kw0, const float* __restrict__ kb0,
    const float* __restrict__ qw1, const float* __restrict__ qb1,
    const float* __restrict__ kw1, const float* __restrict__ kb1,
    const float* __restrict__ qw2, const float* __restrict__ qb2,
    const float* __restrict__ kw2, const float* __restrict__ kb2,
    const float* __restrict__ qw3, const float* __restrict__ qb3,
    const float* __restrict__ kw3, const float* __restrict__ kb3,
    float* __restrict__ qt_, float* __restrict__ qkb,
    float* __restrict__ comb, float* __restrict__ head, float* __restrict__ den)
{
  const int up = blockIdx.x, b = blockIdx.y, t = threadIdx.x;
  const float* qw = (up == 0) ? qw0 : (up == 1) ? qw1 : (up == 2) ? qw2 : qw3;
  const float* qb = (up == 0) ? qb0 : (up == 1) ? qb1 : (up == 2) ? qb2 : qb3;
  const float* kw = (up == 0) ? kw0 : (up == 1) ? kw1 : (up == 2) ? kw2 : kw3;
  const float* kb = (up == 0) ? kb0 : (up == 1) ? kb1 : (up == 2) ? kb2 : kb3;
  __shared__ float cl[CD];
  __shared__ float ql[CD];
  __shared__ float red[256];
  cl[t] = cnode[b * CD + t];
  head[((size_t)b * 4 + up) * CD + t] = 0.f;
  if (t == 0) den[b * 4 + up] = 0.f;
  __syncthreads();
  if (up == 0) comb[((size_t)b * CNP1 + CN) * CD + t] = cl[t];
  {
    const float* wr = qw + (size_t)t * CD;
    float a = qb[t];
#pragma unroll 4
    for (int k = 0; k < CD; k += 4) {
      float4 w4 = *(const float4*)(wr + k);
      a += cl[k] * w4.x + cl[k + 1] * w4.y + cl[k + 2] * w4.z + cl[k + 3] * w4.w;
    }
    ql[t] = a;
  }
  __syncthreads();
  {
    float a = 0.f;
    for (int d = 0; d < CD; d++) a += ql[d] * kw[d * CD + t];
    qt_[((size_t)up * CB + b) * CD + t] = a;
  }
  red[t] = ql[t] * kb[t];
  __syncthreads();
  for (int s = 128; s > 0; s >>= 1) { if (t < s) red[t] += red[t + s]; __syncthreads(); }
  if (t == 0) qkb[up * CB + b] = red[0];
}

__global__ __launch_bounds__(256) void up_sim(
    const float* __restrict__ comb, const float* __restrict__ qt,
    const float* __restrict__ qkb, const float* __restrict__ pmask,
    float* __restrict__ sim)
{
  const int b = blockIdx.y, t = threadIdx.x;
  const int w = t >> 6, l = t & 63;
  __shared__ float qtl[4 * CD];
  __shared__ float qkbl[4];
  for (int i = t; i < 4 * CD; i += 256)
    qtl[i] = qt[((size_t)(i >> 8) * CB + b) * CD + (i & 255)];
  if (t < 4) qkbl[t] = qkb[t * CB + b];
  __syncthreads();
  const int n = blockIdx.x * 4 + w;
  if (n >= CNP1) return;
  float4 c4 = *(const float4*)(comb + ((size_t)b * CNP1 + n) * CD + l * 4);
  float p[4];
#pragma unroll
  for (int u = 0; u < 4; u++) {
    float4 q4 = *(const float4*)&qtl[u * CD + l * 4];
    p[u] = c4.x * q4.x + c4.y * q4.y + c4.z * q4.z + c4.w * q4.w;
  }
#pragma unroll
  for (int off = 32; off > 0; off >>= 1) {
#pragma unroll
    for (int u = 0; u < 4; u++) p[u] += __shfl_xor(p[u], off);
  }
  if (l == 0) {
    float m = (n < CN) ? pmask[b * CN + n] : 1.f;
#pragma unroll
    for (int u = 0; u < 4; u++) {
      float s = (p[u] + qkbl[u]) * 0.0625f;
      if (m == 0.f) s = 1e-8f;
      sim[((size_t)b * 4 + u) * CNP1 + n] = s;
    }
  }
}

__global__ __launch_bounds__(256) void up_head(
    const float* __restrict__ comb, const float* __restrict__ sim,
    float* __restrict__ head, float* __restrict__ den)
{
  const int b = blockIdx.x, n0 = blockIdx.y * 64, t = threadIdx.x;
  const int up = t >> 6, dq = t & 63;
  __shared__ float attl[4][64];
  {
    int u = t >> 6, j = t & 63;
    attl[u][j] = (n0 + j < CNP1)
        ? __expf(sim[((size_t)b * 4 + u) * CNP1 + n0 + j]) : 0.f;
  }
  __syncthreads();
  float4 acc = make_float4(0.f, 0.f, 0.f, 0.f);
  const int nmax = min(64, CNP1 - n0);
  for (int j = 0; j < nmax; j++) {
    float a = attl[up][j];
    float4 c4 = *(const float4*)(comb + ((size_t)b * CNP1 + n0 + j) * CD + dq * 4);
    acc.x += a * c4.x; acc.y += a * c4.y; acc.z += a * c4.z; acc.w += a * c4.w;
  }
  float* hp = head + ((size_t)b * 4 + up) * CD + dq * 4;
  atomicAdd(hp + 0, acc.x); atomicAdd(hp + 1, acc.y);
  atomicAdd(hp + 2, acc.z); atomicAdd(hp + 3, acc.w);
  if (dq == 0) {
    float s = 0.f;
    for (int j = 0; j < 64; j++) s += attl[up][j];
    atomicAdd(den + b * 4 + up, s);
  }
}

__global__ __launch_bounds__(256) void up_out_all(
    const float* __restrict__ head, const float* __restrict__ den,
    const float* __restrict__ ow0, const float* __restrict__ ob0,
    const float* __restrict__ ow1, const float* __restrict__ ob1,
    const float* __restrict__ ow2, const float* __restrict__ ob2,
    const float* __restrict__ ow3, const float* __restrict__ ob3,
    float* __restrict__ uout)
{
  const int b = blockIdx.x, up = blockIdx.y, t = threadIdx.x;
  const float* ow = (up == 0) ? ow0 : (up == 1) ? ow1 : (up == 2) ? ow2 : ow3;
  const float* ob = (up == 0) ? ob0 : (up == 1) ? ob1 : (up == 2) ? ob2 : ob3;
  __shared__ float hl[CD];
  hl[t] = head[((size_t)b * 4 + up) * CD + t] * (1.f / den[b * 4 + up]);
  __syncthreads();
  const float* r0 = ow + (size_t)t * 4 * CD;
  float a = ob[t];
#pragma unroll 2
  for (int dd = 0; dd < CD; dd += 4) {
    float4 w0 = *(const float4*)(r0 + dd);
    float4 w1 = *(const float4*)(r0 + CD + dd);
    float4 w2 = *(const float4*)(r0 + 2 * CD + dd);
    float4 w3 = *(const float4*)(r0 + 3 * CD + dd);
    a += hl[dd]     * (w0.x + w1.x + w2.x + w3.x)
       + hl[dd + 1] * (w0.y + w1.y + w2.y + w3.y)
       + hl[dd + 2] * (w0.z + w1.z + w2.z + w3.z)
       + hl[dd + 3] * (w0.w + w1.w + w2.w + w3.w);
  }
  uout[((size_t)b * 4 + up) * CD + t] = a;
}

// ---------- U_GAT projection + per-node attn scores. grid (16, 4) = 64 blocks.
__global__ __launch_bounds__(256) void ugat_qk(
    const float* __restrict__ u, const float* __restrict__ W,
    const float* __restrict__ attnw,
    float* __restrict__ uqk, float* __restrict__ sqk)
{
  const int b = blockIdx.x, node = blockIdx.y, t = threadIdx.x;
  __shared__ float ul[CD];
  __shared__ float qkl[CD];
  ul[t] = u[((size_t)b * 4 + node) * CD + t];
  __syncthreads();
  const float* wr = W + (size_t)t * CD;
  float p0 = 0.f, p1 = 0.f, p2 = 0.f, p3 = 0.f;
#pragma unroll 4
  for (int d = 0; d < CD; d += 16) {
    float4 w0 = *(const float4*)(wr + d);
    float4 w1 = *(const float4*)(wr + d + 4);
    float4 w2 = *(const float4*)(wr + d + 8);
    float4 w3 = *(const float4*)(wr + d + 12);
    p0 += ul[d +  0] * w0.x + ul[d +  1] * w0.y + ul[d +  2] * w0.z + ul[d +  3] * w0.w;
    p1 += ul[d +  4] * w1.x + ul[d +  5] * w1.y + ul[d +  6] * w1.z + ul[d +  7] * w1.w;
    p2 += ul[d +  8] * w2.x + ul[d +  9] * w2.y + ul[d + 10] * w2.z + ul[d + 11] * w2.w;
    p3 += ul[d + 12] * w3.x + ul[d + 13] * w3.y + ul[d + 14] * w3.z + ul[d + 15] * w3.w;
  }
  float a = (p0 + p1) + (p2 + p3);
  qkl[t] = a;
  uqk[((size_t)b * 4 + node) * CD + t] = a;
  __syncthreads();
  if (t < 8) {
    const int h = t >> 1, which = t & 1;
    const float* w = attnw + h * 128 + which * 64;
    float s = 0.f;
    for (int j = 0; j < 64; j++) s += qkl[h * 64 + j] * w[j];
    sqk[(((size_t)b * 4 + node) * 4 + h) * 2 + which] = s;
  }
}

// ---------- U_GAT attention + residual (in-place on u). grid (16).
__global__ __launch_bounds__(256) void ugat_attn3(
    const float* __restrict__ uqk, const float* __restrict__ sqk,
    float* __restrict__ u)
{
  const int b = blockIdx.x, t = threadIdx.x;
  __shared__ float uq[4][CD];
  __shared__ float sl[4][4], kl[4][4];
  for (int i = t; i < 4 * CD; i += 256) uq[i >> 8][i & 255] = uqk[(size_t)b * 4 * CD + i];
  if (t < 16) {
    int node = t >> 2, h = t & 3;
    sl[node][h] = sqk[(((size_t)b * 4 + node) * 4 + h) * 2 + 0];
    kl[node][h] = sqk[(((size_t)b * 4 + node) * 4 + h) * 2 + 1];
  }
  __syncthreads();
  const int h = t >> 6;
#pragma unroll
  for (int q = 0; q < 4; q++) {
    float e[4]; float ssum = 0.f;
#pragma unroll
    for (int k = 0; k < 4; k++) { e[k] = __expf(tanh_fast(sl[q][h] + kl[k][h])); ssum += e[k]; }
    float hid = 0.f;
#pragma unroll
    for (int k = 0; k < 4; k++) hid += e[k] * uq[k][t];
    size_t idx = (size_t)b * 4 * CD + q * CD + t;
    u[idx] = u[idx] + tanh_fast(hid / ssum);
  }
}

// ---------- MLP + classifier heads. grid (16, 4), 128 threads.
__global__ __launch_bounds__(128) void mlp_kernel(
    const float* __restrict__ u,
    const float* __restrict__ w1, const float* __restrict__ b1,
    const float* __restrict__ w2, const float* __restrict__ b2,
    const float* __restrict__ f1w, const float* __restrict__ f1b,
    const float* __restrict__ f2w, const float* __restrict__ f2b,
    const float* __restrict__ f3w, const float* __restrict__ f3b,
    const float* __restrict__ f4w, const float* __restrict__ f4b,
    float* __restrict__ out)
{
  const int b = blockIdx.x, i = blockIdx.y, t = threadIdx.x;
  __shared__ float xl[CD];
  __shared__ float h1[CFH];
  __shared__ float h2[CFH];
  xl[t]       = u[((size_t)b * 4 + i) * CD + t];
  xl[t + 128] = u[((size_t)b * 4 + i) * CD + t + 128];
  __syncthreads();
  {
    const float* r = w1 + (size_t)t * CD;
    float a = b1[t];
#pragma unroll 4
    for (int k = 0; k < CD; k += 4) {
      float4 v = *(const float4*)(r + k);
      a += xl[k] * v.x + xl[k + 1] * v.y + xl[k + 2] * v.z + xl[k + 3] * v.w;
    }
    h1[t] = fmaxf(a, 0.f);
  }
  __syncthreads();
  {
    const float* r = w2 + (size_t)t * CFH;
    float a = b2[t];
#pragma unroll 4
    for (int k = 0; k < CFH; k += 4) {
      float4 v = *(const float4*)(r + k);
      a += h1[k] * v.x + h1[k + 1] * v.y + h1[k + 2] * v.z + h1[k + 3] * v.w;
    }
    h2[t] = fmaxf(a, 0.f);
  }
  __syncthreads();
  if (t < CNC) {
    const float* fw; const float* fb;
    switch (i) {
      case 0:  fw = f1w; fb = f1b; break;
      case 1:  fw = f2w; fb = f2b; break;
      case 2:  fw = f3w; fb = f3b; break;
      default: fw = f4w; fb = f4b; break;
    }
    const float* r = fw + (size_t)t * CFH;
    float a = fb[t];
    for (int k = 0; k < CFH; k++) a += h2[k] * r[k];
    out[(size_t)i * (CB * CNC) + b * CNC + t] = a;
  }
}

extern "C" void kernel_launch(void* const* d_in, const int* in_sizes, int n_in,
                              void* d_out, int out_size, void* d_ws, size_t ws_size,
                              hipStream_t stream) {
  (void)in_sizes; (void)n_in; (void)out_size; (void)ws_size;
  const float* pmask    = (const float*)d_in[0];
  const float* feature  = (const float*)d_in[1];
  const float* cnode    = (const float*)d_in[2];
  const float* pgat_W   = (const float*)d_in[3];
  const float* pgat_att = (const float*)d_in[4];
  const float* upw[4][6];
  for (int i = 0; i < 4; i++)
    for (int j = 0; j < 6; j++) upw[i][j] = (const float*)d_in[5 + i * 6 + j];
  const float* ugat_W   = (const float*)d_in[29];
  const float* ugat_att = (const float*)d_in[30];
  const float* mlp_w1 = (const float*)d_in[31];
  const float* mlp_b1 = (const float*)d_in[32];
  const float* mlp_w2 = (const float*)d_in[33];
  const float* mlp_b2 = (const float*)d_in[34];
  const float* fcf[8];
  for (int j = 0; j < 8; j++) fcf[j] = (const float*)d_in[35 + j];

  float* ws = (float*)d_ws;
  size_t o = 0;
  float* ws_qk   = ws + o; o += (size_t)CB * CN * CD;
  float* ws_feat = ws + o; o += (size_t)CB * CN * CD;
  float* ws_comb = ws + o; o += (size_t)CB * CNP1 * CD;
  float* ws_sq   = ws + o; o += (size_t)CB * CPH * CN;
  float* ws_sk   = ws + o; o += (size_t)CB * CPH * CN;
  float* ws_qt   = ws + o; o += (size_t)4 * CB * CD;
  float* ws_qkb  = ws + o; o += 4 * CB;
  float* ws_sim  = ws + o; o += (size_t)CB * 4 * CNP1;
  float* ws_den  = ws + o; o += CB * 4;
  float* ws_head = ws + o; o += (size_t)CB * 4 * CD;
  float* ws_u    = ws + o; o += (size_t)CB * 4 * CD;
  float* ws_uqk  = ws + o; o += (size_t)CB * 4 * CD;
  float* ws_sqk  = ws + o; o += (size_t)CB * 4 * 4 * 2;

  const dim3 gemmGrid(CD / 64, (CB * CN) / 64);   // (4, 128)
  const dim3 attnGrid(CN / 64, CPH, CB);          // (8, 8, 16)

  // P_GAT layer 1
  gemm_bf16s<<<gemmGrid, 256, 0, stream>>>(feature, pgat_W, ws_qk);
  pgat_sqsk<<<dim3(CB * CN / 32), 256, 0, stream>>>(ws_qk, pgat_att, ws_sq, ws_sk);
  pgat_attn_mfma<<<attnGrid, 256, 0, stream>>>(ws_qk, ws_sq, ws_sk, pmask, feature, ws_feat, CN);
  // P_GAT layer 2 (writes into comb rows, stride 513)
  gemm_bf16s<<<gemmGrid, 256, 0, stream>>>(ws_feat, pgat_W, ws_qk);
  pgat_sqsk<<<dim3(CB * CN / 32), 256, 0, stream>>>(ws_qk, pgat_att, ws_sq, ws_sk);
  pgat_attn_mfma<<<attnGrid, 256, 0, stream>>>(ws_qk, ws_sq, ws_sk, pmask, ws_feat, ws_comb, CNP1);

  // UP_GAT x4
  up_q_all<<<dim3(4, CB), 256, 0, stream>>>(cnode,
      upw[0][0], upw[0][1], upw[0][2], upw[0][3],
      upw[1][0], upw[1][1], upw[1][2], upw[1][3],
      upw[2][0], upw[2][1], upw[2][2], upw[2][3],
      upw[3][0], upw[3][1], upw[3][2], upw[3][3],
      ws_qt, ws_qkb, ws_comb, ws_head, ws_den);
  up_sim<<<dim3((CNP1 + 3) / 4, CB), 256, 0, stream>>>(ws_comb, ws_qt, ws_qkb, pmask, ws_sim);
  up_head<<<dim3(CB, (CNP1 + 63) / 64), 256, 0, stream>>>(ws_comb, ws_sim, ws_head, ws_den);
  up_out_all<<<dim3(CB, 4), 256, 0, stream>>>(ws_head, ws_den,
      upw[0][4], upw[0][5], upw[1][4], upw[1][5],
      upw[2][4], upw[2][5], upw[3][4], upw[3][5], ws_u);

  // U_GAT (wide) + MLP + heads
  ugat_qk<<<dim3(CB, 4), 256, 0, stream>>>(ws_u, ugat_W, ugat_att, ws_uqk, ws_sqk);
  ugat_attn3<<<dim3(CB), 256, 0, stream>>>(ws_uqk, ws_sqk, ws_u);
  mlp_kernel<<<dim3(CB, 4), 128, 0, stream>>>(ws_u, mlp_w1, mlp_b1, mlp_w2, mlp_b2,
                                              fcf[0], fcf[1], fcf[2], fcf[3],
                                              fcf[4], fcf[5], fcf[6], fcf[7],
                                              (float*)d_out);
}

// Round 7
// 319.954 us; speedup vs baseline: 2.4000x; 1.0122x over previous
//
#include <hip/hip_runtime.h>

constexpr int CB   = 16;    // batch
constexpr int CN   = 512;   // nodes
constexpr int CD   = 256;   // dim
constexpr int CPH  = 8;     // pgat heads
constexpr int CDH  = 32;    // CD / CPH
constexpr int CNP1 = 513;   // nodes + c_node
constexpr int CFH  = 128;
constexpr int CNC  = 2;

typedef __bf16 bf16x8 __attribute__((ext_vector_type(8)));
typedef __bf16 bf16x4 __attribute__((ext_vector_type(4)));
typedef float  f32x4  __attribute__((ext_vector_type(4)));

__device__ __forceinline__ float tanh_fast(float x) {
  x = fminf(fmaxf(x, -15.f), 15.f);
  float e = __expf(2.f * x);
  return (e - 1.f) / (e + 1.f);
}

// ---------- bf16-split MFMA GEMM + fused sq/sk epilogue.
// C[m,n] = sum_k A[m,k]*W[n,k] written as bf16; block cols = 2 whole heads,
// sq/sk computed from in-register acc via 16-lane butterfly.
__global__ __launch_bounds__(256) void gemm_fused(
    const float* __restrict__ A, const float* __restrict__ W,
    const float* __restrict__ attnw, __bf16* __restrict__ C,
    float* __restrict__ sqT, float* __restrict__ skT)
{
  const int t  = threadIdx.x;
  const int nt = blockIdx.x * 64;
  const int mt = blockIdx.y * 64;
  const int wv = t >> 6, ln = t & 63;
  const int quad = ln >> 4, lc = ln & 15;

  __shared__ __align__(16) __bf16 aHi[64][56];
  __shared__ __align__(16) __bf16 aLo[64][56];
  __shared__ __align__(16) __bf16 bHi[64][56];
  __shared__ __align__(16) __bf16 bLo[64][56];

  f32x4 acc[4];
#pragma unroll
  for (int j = 0; j < 4; j++)
#pragma unroll
    for (int r = 0; r < 4; r++) acc[j][r] = 0.f;

  const int sr  = t >> 2;
  const int skq = (t & 3) * 8;

  for (int k0 = 0; k0 < 256; k0 += 32) {
    __syncthreads();
    {
      const float* ap = A + (size_t)(mt + sr) * 256 + k0 + skq;
      const float* wp = W + (size_t)(nt + sr) * 256 + k0 + skq;
      float4 a0 = *(const float4*)ap, a1 = *(const float4*)(ap + 4);
      float4 w0 = *(const float4*)wp, w1 = *(const float4*)(wp + 4);
      float av[8] = {a0.x, a0.y, a0.z, a0.w, a1.x, a1.y, a1.z, a1.w};
      float wvv[8] = {w0.x, w0.y, w0.z, w0.w, w1.x, w1.y, w1.z, w1.w};
      bf16x8 ah, al, bh, bl;
#pragma unroll
      for (int j = 0; j < 8; j++) {
        ah[j] = (__bf16)av[j];
        al[j] = (__bf16)(av[j] - (float)ah[j]);
        bh[j] = (__bf16)wvv[j];
        bl[j] = (__bf16)(wvv[j] - (float)bh[j]);
      }
      *(bf16x8*)&aHi[sr][skq] = ah;
      *(bf16x8*)&aLo[sr][skq] = al;
      *(bf16x8*)&bHi[sr][skq] = bh;
      *(bf16x8*)&bLo[sr][skq] = bl;
    }
    __syncthreads();
    bf16x8 fah = *(const bf16x8*)&aHi[wv * 16 + lc][quad * 8];
    bf16x8 fal = *(const bf16x8*)&aLo[wv * 16 + lc][quad * 8];
#pragma unroll
    for (int j = 0; j < 4; j++) {
      bf16x8 fbh = *(const bf16x8*)&bHi[j * 16 + lc][quad * 8];
      bf16x8 fbl = *(const bf16x8*)&bLo[j * 16 + lc][quad * 8];
      acc[j] = __builtin_amdgcn_mfma_f32_16x16x32_bf16(fah, fbh, acc[j], 0, 0, 0);
      acc[j] = __builtin_amdgcn_mfma_f32_16x16x32_bf16(fah, fbl, acc[j], 0, 0, 0);
      acc[j] = __builtin_amdgcn_mfma_f32_16x16x32_bf16(fal, fbh, acc[j], 0, 0, 0);
    }
  }
  // C store (bf16), row m = mt + wv*16 + quad*4 + r, col = nt + j*16 + lc
#pragma unroll
  for (int j = 0; j < 4; j++)
#pragma unroll
    for (int r = 0; r < 4; r++)
      C[(size_t)(mt + wv * 16 + quad * 4 + r) * 256 + nt + j * 16 + lc] =
          (__bf16)acc[j][r];

  // fused sq/sk: heads hA=2*bx (cols 0..31 of tile), hB=hA+1 (cols 32..63)
  const int hA = blockIdx.x * 2, hB = hA + 1;
  const float wqa0 = attnw[hA * 64 + lc],      wqa1 = attnw[hA * 64 + 16 + lc];
  const float wka0 = attnw[hA * 64 + 32 + lc], wka1 = attnw[hA * 64 + 48 + lc];
  const float wqb0 = attnw[hB * 64 + lc],      wqb1 = attnw[hB * 64 + 16 + lc];
  const float wkb0 = attnw[hB * 64 + 32 + lc], wkb1 = attnw[hB * 64 + 48 + lc];
  float sqa[4], ska[4], sqb[4], skb[4];
#pragma unroll
  for (int r = 0; r < 4; r++) {
    sqa[r] = acc[0][r] * wqa0 + acc[1][r] * wqa1;
    ska[r] = acc[0][r] * wka0 + acc[1][r] * wka1;
    sqb[r] = acc[2][r] * wqb0 + acc[3][r] * wqb1;
    skb[r] = acc[2][r] * wkb0 + acc[3][r] * wkb1;
  }
#pragma unroll
  for (int m = 1; m <= 8; m <<= 1) {
#pragma unroll
    for (int r = 0; r < 4; r++) {
      sqa[r] += __shfl_xor(sqa[r], m);
      ska[r] += __shfl_xor(ska[r], m);
      sqb[r] += __shfl_xor(sqb[r], m);
      skb[r] += __shfl_xor(skb[r], m);
    }
  }
  if (lc == 0) {
#pragma unroll
    for (int r = 0; r < 4; r++) {
      int gm = mt + wv * 16 + quad * 4 + r;
      int bb = gm >> 9, nn = gm & 511;
      sqT[((size_t)bb * CPH + hA) * CN + nn] = sqa[r];
      skT[((size_t)bb * CPH + hA) * CN + nn] = ska[r];
      sqT[((size_t)bb * CPH + hB) * CN + nn] = sqb[r];
      skT[((size_t)bb * CPH + hB) * CN + nn] = skb[r];
    }
  }
}

// ---------- P_GAT attention via bf16 MFMA (V input now bf16)
__global__ __launch_bounds__(256) void pgat_attn_mfma(
    const __bf16* __restrict__ qk, const float* __restrict__ sqT,
    const float* __restrict__ skT, const float* __restrict__ pmask,
    const float* __restrict__ fin, float* __restrict__ fout, int outStride)
{
  const int qt = blockIdx.x;
  const int h  = blockIdx.y;
  const int b  = blockIdx.z;
  const int t  = threadIdx.x;
  const int wv = t >> 6;
  const int ln = t & 63;
  const int quad = ln >> 4;
  const int lc   = ln & 15;

  __shared__ __align__(16) __bf16 pbuf[64][72];
  __shared__ __align__(16) __bf16 vbuf[32][72];
  __shared__ float skl[CN];
  __shared__ float pml[CN];
  __shared__ float sql[64];
  __shared__ float pmq[64];

  for (int i = t; i < CN; i += 256) {
    skl[i] = skT[((size_t)b * CPH + h) * CN + i];
    pml[i] = pmask[b * CN + i];
  }
  if (t < 64) {
    sql[t] = sqT[((size_t)b * CPH + h) * CN + qt * 64 + t];
    pmq[t] = pmask[b * CN + qt * 64 + t];
  }

  f32x4 accV0 = {0.f, 0.f, 0.f, 0.f};
  f32x4 accV1 = {0.f, 0.f, 0.f, 0.f};
  f32x4 accD  = {0.f, 0.f, 0.f, 0.f};
  bf16x8 ones;
#pragma unroll
  for (int j = 0; j < 8; j++) ones[j] = (__bf16)1.0f;

  const int qg = t >> 2;
  const int kb = (t & 3) * 16;
  const int vkk = t >> 3;
  const int vdq = (t & 7) * 4;

  for (int k0 = 0; k0 < CN; k0 += 64) {
    __syncthreads();
    {
      bf16x4 v0 = *(const bf16x4*)(qk + ((size_t)(b * CN + k0 + vkk)) * CD + h * CDH + vdq);
      bf16x4 v1 = *(const bf16x4*)(qk + ((size_t)(b * CN + k0 + 32 + vkk)) * CD + h * CDH + vdq);
      vbuf[vdq + 0][vkk] = v0[0]; vbuf[vdq + 1][vkk] = v0[1];
      vbuf[vdq + 2][vkk] = v0[2]; vbuf[vdq + 3][vkk] = v0[3];
      vbuf[vdq + 0][32 + vkk] = v1[0]; vbuf[vdq + 1][32 + vkk] = v1[1];
      vbuf[vdq + 2][32 + vkk] = v1[2]; vbuf[vdq + 3][32 + vkk] = v1[3];
    }
    {
      float sq_ = sql[qg];
      float mq  = pmq[qg];
      bf16x8 w0, w1;
#pragma unroll
      for (int j = 0; j < 8; j++) {
        float s = tanh_fast(sq_ + skl[k0 + kb + j]);
        if (mq * pml[k0 + kb + j] == 0.f) s = -1e-8f;
        w0[j] = (__bf16)__expf(s);
      }
#pragma unroll
      for (int j = 0; j < 8; j++) {
        float s = tanh_fast(sq_ + skl[k0 + kb + 8 + j]);
        if (mq * pml[k0 + kb + 8 + j] == 0.f) s = -1e-8f;
        w1[j] = (__bf16)__expf(s);
      }
      *(bf16x8*)&pbuf[qg][kb]     = w0;
      *(bf16x8*)&pbuf[qg][kb + 8] = w1;
    }
    __syncthreads();
#pragma unroll
    for (int s = 0; s < 2; s++) {
      bf16x8 a  = *(const bf16x8*)&pbuf[wv * 16 + lc][s * 32 + quad * 8];
      bf16x8 b0 = *(const bf16x8*)&vbuf[lc][s * 32 + quad * 8];
      bf16x8 b1 = *(const bf16x8*)&vbuf[16 + lc][s * 32 + quad * 8];
      accV0 = __builtin_amdgcn_mfma_f32_16x16x32_bf16(a, b0, accV0, 0, 0, 0);
      accV1 = __builtin_amdgcn_mfma_f32_16x16x32_bf16(a, b1, accV1, 0, 0, 0);
      accD  = __builtin_amdgcn_mfma_f32_16x16x32_bf16(a, ones, accD, 0, 0, 0);
    }
  }
#pragma unroll
  for (int r = 0; r < 4; r++) {
    int q = qt * 64 + wv * 16 + quad * 4 + r;
    float inv = 1.f / accD[r];
    int d0 = h * CDH + lc;
    const float* ip = fin + ((size_t)b * CN + q) * CD;
    float*       op = fout + ((size_t)b * outStride + q) * CD;
    op[d0]      = ip[d0]      + tanh_fast(accV0[r] * inv);
    op[d0 + 16] = ip[d0 + 16] + tanh_fast(accV1[r] * inv);
  }
}

// ========== UP_GAT stage ==========

__global__ __launch_bounds__(256) void up_q_all(
    const float* __restrict__ cnode,
    const float* __restrict__ qw0, const float* __restrict__ qb0,
    const float* __restrict__ kw0, const float* __restrict__ kb0,
    const float* __restrict__ qw1, const float* __restrict__ qb1,
    const float* __restrict__ kw1, const float* __restrict__ kb1,
    const float* __restrict__ qw2, const float* __restrict__ qb2,
    const float* __restrict__ kw2, const float* __restrict__ kb2,
    const float* __restrict__ qw3, const float* __restrict__ qb3,
    const float* __restrict__ kw3, const float* __restrict__ kb3,
    float* __restrict__ qt_, float* __restrict__ qkb,
    float* __restrict__ comb, float* __restrict__ head, float* __restrict__ den)
{
  const int up = blockIdx.x, b = blockIdx.y, t = threadIdx.x;
  const float* qw = (up == 0) ? qw0 : (up == 1) ? qw1 : (up == 2) ? qw2 : qw3;
  const float* qb = (up == 0) ? qb0 : (up == 1) ? qb1 : (up == 2) ? qb2 : qb3;
  const float* kw = (up == 0) ? kw0 : (up == 1) ? kw1 : (up == 2) ? kw2 : kw3;
  const float* kb = (up == 0) ? kb0 : (up == 1) ? kb1 : (up == 2) ? kb2 : kb3;
  __shared__ float cl[CD];
  __shared__ float ql[CD];
  __shared__ float red[256];
  cl[t] = cnode[b * CD + t];
  head[((size_t)b * 4 + up) * CD + t] = 0.f;
  if (t == 0) den[b * 4 + up] = 0.f;
  __syncthreads();
  if (up == 0) comb[((size_t)b * CNP1 + CN) * CD + t] = cl[t];
  {
    const float* wr = qw + (size_t)t * CD;
    float a = qb[t];
#pragma unroll 4
    for (int k = 0; k < CD; k += 4) {
      float4 w4 = *(const float4*)(wr + k);
      a += cl[k] * w4.x + cl[k + 1] * w4.y + cl[k + 2] * w4.z + cl[k + 3] * w4.w;
    }
    ql[t] = a;
  }
  __syncthreads();
  {
    float a = 0.f;
    for (int d = 0; d < CD; d++) a += ql[d] * kw[d * CD + t];
    qt_[((size_t)up * CB + b) * CD + t] = a;
  }
  red[t] = ql[t] * kb[t];
  __syncthreads();
  for (int s = 128; s > 0; s >>= 1) { if (t < s) red[t] += red[t + s]; __syncthreads(); }
  if (t == 0) qkb[up * CB + b] = red[0];
}

// sim+exp+weighted-sum fused. grid (16, 9), 256 thr: t -> (up = t>>6, j = t&63)
__global__ __launch_bounds__(256) void up_headsim(
    const float* __restrict__ comb, const float* __restrict__ qt,
    const float* __restrict__ qkb, const float* __restrict__ pmask,
    float* __restrict__ head, float* __restrict__ den)
{
  const int b = blockIdx.x, n0 = blockIdx.y * 64, t = threadIdx.x;
  const int up = t >> 6, j = t & 63;
  __shared__ float qtl[4][CD];
  __shared__ float qkbl[4];
  __shared__ float attl[4][64];
  for (int i = t; i < 4 * CD; i += 256)
    qtl[i >> 8][i & 255] = qt[((size_t)(i >> 8) * CB + b) * CD + (i & 255)];
  if (t < 4) qkbl[t] = qkb[t * CB + b];
  __syncthreads();
  // phase 1: sim + exp for my (up, n)
  {
    const int n = n0 + j;
    float e = 0.f;
    if (n < CNP1) {
      const float* cr = comb + ((size_t)b * CNP1 + n) * CD;
      float p = 0.f;
#pragma unroll 4
      for (int d = 0; d < CD; d += 4) {
        float4 c4 = *(const float4*)(cr + d);
        p += qtl[up][d] * c4.x + qtl[up][d + 1] * c4.y
           + qtl[up][d + 2] * c4.z + qtl[up][d + 3] * c4.w;
      }
      float s = (p + qkbl[up]) * 0.0625f;
      float m = (n < CN) ? pmask[b * CN + n] : 1.f;
      if (m == 0.f) s = 1e-8f;
      e = __expf(s);
    }
    attl[up][j] = e;
  }
  __syncthreads();
  // phase 2: weighted sum (up = t>>6, dq = j)
  float4 acc = make_float4(0.f, 0.f, 0.f, 0.f);
  const int nmax = min(64, CNP1 - n0);
  for (int jj = 0; jj < nmax; jj++) {
    float a = attl[up][jj];
    float4 c4 = *(const float4*)(comb + ((size_t)b * CNP1 + n0 + jj) * CD + j * 4);
    acc.x += a * c4.x; acc.y += a * c4.y; acc.z += a * c4.z; acc.w += a * c4.w;
  }
  float* hp = head + ((size_t)b * 4 + up) * CD + j * 4;
  atomicAdd(hp + 0, acc.x); atomicAdd(hp + 1, acc.y);
  atomicAdd(hp + 2, acc.z); atomicAdd(hp + 3, acc.w);
  if (j == 0) {
    float s = 0.f;
    for (int jj = 0; jj < 64; jj++) s += attl[up][jj];
    atomicAdd(den + b * 4 + up, s);
  }
}

__global__ __launch_bounds__(256) void up_out_all(
    const float* __restrict__ head, const float* __restrict__ den,
    const float* __restrict__ ow0, const float* __restrict__ ob0,
    const float* __restrict__ ow1, const float* __restrict__ ob1,
    const float* __restrict__ ow2, const float* __restrict__ ob2,
    const float* __restrict__ ow3, const float* __restrict__ ob3,
    float* __restrict__ uout)
{
  const int b = blockIdx.x, up = blockIdx.y, t = threadIdx.x;
  const float* ow = (up == 0) ? ow0 : (up == 1) ? ow1 : (up == 2) ? ow2 : ow3;
  const float* ob = (up == 0) ? ob0 : (up == 1) ? ob1 : (up == 2) ? ob2 : ob3;
  __shared__ float hl[CD];
  hl[t] = head[((size_t)b * 4 + up) * CD + t] * (1.f / den[b * 4 + up]);
  __syncthreads();
  const float* r0 = ow + (size_t)t * 4 * CD;
  float a = ob[t];
#pragma unroll 2
  for (int dd = 0; dd < CD; dd += 4) {
    float4 w0 = *(const float4*)(r0 + dd);
    float4 w1 = *(const float4*)(r0 + CD + dd);
    float4 w2 = *(const float4*)(r0 + 2 * CD + dd);
    float4 w3 = *(const float4*)(r0 + 3 * CD + dd);
    a += hl[dd]     * (w0.x + w1.x + w2.x + w3.x)
       + hl[dd + 1] * (w0.y + w1.y + w2.y + w3.y)
       + hl[dd + 2] * (w0.z + w1.z + w2.z + w3.z)
       + hl[dd + 3] * (w0.w + w1.w + w2.w + w3.w);
  }
  uout[((size_t)b * 4 + up) * CD + t] = a;
}

// ---------- U_GAT projection + per-node attn scores. grid (16, 4).
__global__ __launch_bounds__(256) void ugat_qk(
    const float* __restrict__ u, const float* __restrict__ W,
    const float* __restrict__ attnw,
    float* __restrict__ uqk, float* __restrict__ sqk)
{
  const int b = blockIdx.x, node = blockIdx.y, t = threadIdx.x;
  __shared__ float ul[CD];
  __shared__ float qkl[CD];
  ul[t] = u[((size_t)b * 4 + node) * CD + t];
  __syncthreads();
  const float* wr = W + (size_t)t * CD;
  float p0 = 0.f, p1 = 0.f, p2 = 0.f, p3 = 0.f;
#pragma unroll 4
  for (int d = 0; d < CD; d += 16) {
    float4 w0 = *(const float4*)(wr + d);
    float4 w1 = *(const float4*)(wr + d + 4);
    float4 w2 = *(const float4*)(wr + d + 8);
    float4 w3 = *(const float4*)(wr + d + 12);
    p0 += ul[d +  0] * w0.x + ul[d +  1] * w0.y + ul[d +  2] * w0.z + ul[d +  3] * w0.w;
    p1 += ul[d +  4] * w1.x + ul[d +  5] * w1.y + ul[d +  6] * w1.z + ul[d +  7] * w1.w;
    p2 += ul[d +  8] * w2.x + ul[d +  9] * w2.y + ul[d + 10] * w2.z + ul[d + 11] * w2.w;
    p3 += ul[d + 12] * w3.x + ul[d + 13] * w3.y + ul[d + 14] * w3.z + ul[d + 15] * w3.w;
  }
  float a = (p0 + p1) + (p2 + p3);
  qkl[t] = a;
  uqk[((size_t)b * 4 + node) * CD + t] = a;
  __syncthreads();
  if (t < 8) {
    const int h = t >> 1, which = t & 1;
    const float* w = attnw + h * 128 + which * 64;
    float s = 0.f;
    for (int j = 0; j < 64; j++) s += qkl[h * 64 + j] * w[j];
    sqk[(((size_t)b * 4 + node) * 4 + h) * 2 + which] = s;
  }
}

// ---------- fused U_GAT attention (per-trait) + MLP + classifier. grid (16,4).
__global__ __launch_bounds__(256) void ugat_mlp2(
    const float* __restrict__ u, const float* __restrict__ uqk,
    const float* __restrict__ sqk,
    const float* __restrict__ w1, const float* __restrict__ b1,
    const float* __restrict__ w2, const float* __restrict__ b2,
    const float* __restrict__ f1w, const float* __restrict__ f1b,
    const float* __restrict__ f2w, const float* __restrict__ f2b,
    const float* __restrict__ f3w, const float* __restrict__ f3b,
    const float* __restrict__ f4w, const float* __restrict__ f4b,
    float* __restrict__ out)
{
  const int b = blockIdx.x, trait = blockIdx.y, t = threadIdx.x;
  __shared__ float uq[4][CD];
  __shared__ float sl[4][4], kl[4][4];
  __shared__ float xl[CD];
  __shared__ float h1[CFH];
  __shared__ float h2[CFH];
  for (int i = t; i < 4 * CD; i += 256) uq[i >> 8][i & 255] = uqk[(size_t)b * 4 * CD + i];
  if (t < 16) {
    int node = t >> 2, h = t & 3;
    sl[node][h] = sqk[(((size_t)b * 4 + node) * 4 + h) * 2 + 0];
    kl[node][h] = sqk[(((size_t)b * 4 + node) * 4 + h) * 2 + 1];
  }
  float ur = u[((size_t)b * 4 + trait) * CD + t];
  __syncthreads();
  {
    const int h = t >> 6;
    float e[4]; float ssum = 0.f;
#pragma unroll
    for (int k = 0; k < 4; k++) { e[k] = __expf(tanh_fast(sl[trait][h] + kl[k][h])); ssum += e[k]; }
    float hid = 0.f;
#pragma unroll
    for (int k = 0; k < 4; k++) hid += e[k] * uq[k][t];
    xl[t] = ur + tanh_fast(hid / ssum);
  }
  __syncthreads();
  if (t < CFH) {
    const float* r = w1 + (size_t)t * CD;
    float a = b1[t];
#pragma unroll 4
    for (int k = 0; k < CD; k += 4) {
      float4 v = *(const float4*)(r + k);
      a += xl[k] * v.x + xl[k + 1] * v.y + xl[k + 2] * v.z + xl[k + 3] * v.w;
    }
    h1[t] = fmaxf(a, 0.f);
  }
  __syncthreads();
  if (t < CFH) {
    const float* r = w2 + (size_t)t * CFH;
    float a = b2[t];
#pragma unroll 4
    for (int k = 0; k < CFH; k += 4) {
      float4 v = *(const float4*)(r + k);
      a += h1[k] * v.x + h1[k + 1] * v.y + h1[k + 2] * v.z + h1[k + 3] * v.w;
    }
    h2[t] = fmaxf(a, 0.f);
  }
  __syncthreads();
  if (t < CNC) {
    const float* fw; const float* fb;
    switch (trait) {
      case 0:  fw = f1w; fb = f1b; break;
      case 1:  fw = f2w; fb = f2b; break;
      case 2:  fw = f3w; fb = f3b; break;
      default: fw = f4w; fb = f4b; break;
    }
    const float* r = fw + (size_t)t * CFH;
    float a = fb[t];
    for (int k = 0; k < CFH; k++) a += h2[k] * r[k];
    out[(size_t)trait * (CB * CNC) + b * CNC + t] = a;
  }
}

extern "C" void kernel_launch(void* const* d_in, const int* in_sizes, int n_in,
                              void* d_out, int out_size, void* d_ws, size_t ws_size,
                              hipStream_t stream) {
  (void)in_sizes; (void)n_in; (void)out_size; (void)ws_size;
  const float* pmask    = (const float*)d_in[0];
  const float* feature  = (const float*)d_in[1];
  const float* cnode    = (const float*)d_in[2];
  const float* pgat_W   = (const float*)d_in[3];
  const float* pgat_att = (const float*)d_in[4];
  const float* upw[4][6];
  for (int i = 0; i < 4; i++)
    for (int j = 0; j < 6; j++) upw[i][j] = (const float*)d_in[5 + i * 6 + j];
  const float* ugat_W   = (const float*)d_in[29];
  const float* ugat_att = (const float*)d_in[30];
  const float* mlp_w1 = (const float*)d_in[31];
  const float* mlp_b1 = (const float*)d_in[32];
  const float* mlp_w2 = (const float*)d_in[33];
  const float* mlp_b2 = (const float*)d_in[34];
  const float* fcf[8];
  for (int j = 0; j < 8; j++) fcf[j] = (const float*)d_in[35 + j];

  float* ws = (float*)d_ws;
  size_t o = 0;
  float* ws_qk   = ws + o; o += (size_t)CB * CN * CD;    // used as bf16 (half)
  float* ws_feat = ws + o; o += (size_t)CB * CN * CD;
  float* ws_comb = ws + o; o += (size_t)CB * CNP1 * CD;
  float* ws_sq   = ws + o; o += (size_t)CB * CPH * CN;
  float* ws_sk   = ws + o; o += (size_t)CB * CPH * CN;
  float* ws_qt   = ws + o; o += (size_t)4 * CB * CD;
  float* ws_qkb  = ws + o; o += 4 * CB;
  float* ws_den  = ws + o; o += CB * 4;
  float* ws_head = ws + o; o += (size_t)CB * 4 * CD;
  float* ws_u    = ws + o; o += (size_t)CB * 4 * CD;
  float* ws_uqk  = ws + o; o += (size_t)CB * 4 * CD;
  float* ws_sqk  = ws + o; o += (size_t)CB * 4 * 4 * 2;
  __bf16* qk16 = (__bf16*)ws_qk;

  const dim3 gemmGrid(CD / 64, (CB * CN) / 64);   // (4, 128)
  const dim3 attnGrid(CN / 64, CPH, CB);          // (8, 8, 16)

  // P_GAT layer 1 (gemm + fused sq/sk)
  gemm_fused<<<gemmGrid, 256, 0, stream>>>(feature, pgat_W, pgat_att, qk16, ws_sq, ws_sk);
  pgat_attn_mfma<<<attnGrid, 256, 0, stream>>>(qk16, ws_sq, ws_sk, pmask, feature, ws_feat, CN);
  // P_GAT layer 2 (writes into comb rows, stride 513)
  gemm_fused<<<gemmGrid, 256, 0, stream>>>(ws_feat, pgat_W, pgat_att, qk16, ws_sq, ws_sk);
  pgat_attn_mfma<<<attnGrid, 256, 0, stream>>>(qk16, ws_sq, ws_sk, pmask, ws_feat, ws_comb, CNP1);

  // UP_GAT x4
  up_q_all<<<dim3(4, CB), 256, 0, stream>>>(cnode,
      upw[0][0], upw[0][1], upw[0][2], upw[0][3],
      upw[1][0], upw[1][1], upw[1][2], upw[1][3],
      upw[2][0], upw[2][1], upw[2][2], upw[2][3],
      upw[3][0], upw[3][1], upw[3][2], upw[3][3],
      ws_qt, ws_qkb, ws_comb, ws_head, ws_den);
  up_headsim<<<dim3(CB, (CNP1 + 63) / 64), 256, 0, stream>>>(ws_comb, ws_qt, ws_qkb, pmask,
                                                             ws_head, ws_den);
  up_out_all<<<dim3(CB, 4), 256, 0, stream>>>(ws_head, ws_den,
      upw[0][4], upw[0][5], upw[1][4], upw[1][5],
      upw[2][4], upw[2][5], upw[3][4], upw[3][5], ws_u);

  // U_GAT + MLP + heads
  ugat_qk<<<dim3(CB, 4), 256, 0, stream>>>(ws_u, ugat_W, ugat_att, ws_uqk, ws_sqk);
  ugat_mlp2<<<dim3(CB, 4), 256, 0, stream>>>(ws_u, ws_uqk, ws_sqk,
                                             mlp_w1, mlp_b1, mlp_w2, mlp_b2,
                                             fcf[0], fcf[1], fcf[2], fcf[3],
                                             fcf[4], fcf[5], fcf[6], fcf[7],
                                             (float*)d_out);
}

// Round 8
// 301.992 us; speedup vs baseline: 2.5428x; 1.0595x over previous
//
#include <hip/hip_runtime.h>

constexpr int CB   = 16;    // batch
constexpr int CN   = 512;   // nodes
constexpr int CD   = 256;   // dim
constexpr int CPH  = 8;     // pgat heads
constexpr int CDH  = 32;    // CD / CPH
constexpr int CNP1 = 513;   // nodes + c_node
constexpr int CFH  = 128;
constexpr int CNC  = 2;

typedef __bf16 bf16x8 __attribute__((ext_vector_type(8)));
typedef __bf16 bf16x4 __attribute__((ext_vector_type(4)));
typedef float  f32x4  __attribute__((ext_vector_type(4)));

__device__ __forceinline__ float tanh_fast(float x) {
  x = fminf(fmaxf(x, -15.f), 15.f);
  float e = __expf(2.f * x);
  return (e - 1.f) / (e + 1.f);
}

// clamped e^{2x}: range keeps u=tq*tk finite and matches tanh saturation
__device__ __forceinline__ float exp2x_clamped(float x) {
  x = fminf(fmaxf(x, -18.f), 18.f);
  return __expf(2.f * x);
}

// ---------- bf16-split MFMA GEMM + fused sq/sk epilogue (unchanged from R6)
__global__ __launch_bounds__(256) void gemm_fused(
    const float* __restrict__ A, const float* __restrict__ W,
    const float* __restrict__ attnw, __bf16* __restrict__ C,
    float* __restrict__ sqT, float* __restrict__ skT)
{
  const int t  = threadIdx.x;
  const int nt = blockIdx.x * 64;
  const int mt = blockIdx.y * 64;
  const int wv = t >> 6, ln = t & 63;
  const int quad = ln >> 4, lc = ln & 15;

  __shared__ __align__(16) __bf16 aHi[64][56];
  __shared__ __align__(16) __bf16 aLo[64][56];
  __shared__ __align__(16) __bf16 bHi[64][56];
  __shared__ __align__(16) __bf16 bLo[64][56];

  f32x4 acc[4];
#pragma unroll
  for (int j = 0; j < 4; j++)
#pragma unroll
    for (int r = 0; r < 4; r++) acc[j][r] = 0.f;

  const int sr  = t >> 2;
  const int skq = (t & 3) * 8;

  for (int k0 = 0; k0 < 256; k0 += 32) {
    __syncthreads();
    {
      const float* ap = A + (size_t)(mt + sr) * 256 + k0 + skq;
      const float* wp = W + (size_t)(nt + sr) * 256 + k0 + skq;
      float4 a0 = *(const float4*)ap, a1 = *(const float4*)(ap + 4);
      float4 w0 = *(const float4*)wp, w1 = *(const float4*)(wp + 4);
      float av[8] = {a0.x, a0.y, a0.z, a0.w, a1.x, a1.y, a1.z, a1.w};
      float wvv[8] = {w0.x, w0.y, w0.z, w0.w, w1.x, w1.y, w1.z, w1.w};
      bf16x8 ah, al, bh, bl;
#pragma unroll
      for (int j = 0; j < 8; j++) {
        ah[j] = (__bf16)av[j];
        al[j] = (__bf16)(av[j] - (float)ah[j]);
        bh[j] = (__bf16)wvv[j];
        bl[j] = (__bf16)(wvv[j] - (float)bh[j]);
      }
      *(bf16x8*)&aHi[sr][skq] = ah;
      *(bf16x8*)&aLo[sr][skq] = al;
      *(bf16x8*)&bHi[sr][skq] = bh;
      *(bf16x8*)&bLo[sr][skq] = bl;
    }
    __syncthreads();
    bf16x8 fah = *(const bf16x8*)&aHi[wv * 16 + lc][quad * 8];
    bf16x8 fal = *(const bf16x8*)&aLo[wv * 16 + lc][quad * 8];
#pragma unroll
    for (int j = 0; j < 4; j++) {
      bf16x8 fbh = *(const bf16x8*)&bHi[j * 16 + lc][quad * 8];
      bf16x8 fbl = *(const bf16x8*)&bLo[j * 16 + lc][quad * 8];
      acc[j] = __builtin_amdgcn_mfma_f32_16x16x32_bf16(fah, fbh, acc[j], 0, 0, 0);
      acc[j] = __builtin_amdgcn_mfma_f32_16x16x32_bf16(fah, fbl, acc[j], 0, 0, 0);
      acc[j] = __builtin_amdgcn_mfma_f32_16x16x32_bf16(fal, fbh, acc[j], 0, 0, 0);
    }
  }
#pragma unroll
  for (int j = 0; j < 4; j++)
#pragma unroll
    for (int r = 0; r < 4; r++)
      C[(size_t)(mt + wv * 16 + quad * 4 + r) * 256 + nt + j * 16 + lc] =
          (__bf16)acc[j][r];

  const int hA = blockIdx.x * 2, hB = hA + 1;
  const float wqa0 = attnw[hA * 64 + lc],      wqa1 = attnw[hA * 64 + 16 + lc];
  const float wka0 = attnw[hA * 64 + 32 + lc], wka1 = attnw[hA * 64 + 48 + lc];
  const float wqb0 = attnw[hB * 64 + lc],      wqb1 = attnw[hB * 64 + 16 + lc];
  const float wkb0 = attnw[hB * 64 + 32 + lc], wkb1 = attnw[hB * 64 + 48 + lc];
  float sqa[4], ska[4], sqb[4], skb[4];
#pragma unroll
  for (int r = 0; r < 4; r++) {
    sqa[r] = acc[0][r] * wqa0 + acc[1][r] * wqa1;
    ska[r] = acc[0][r] * wka0 + acc[1][r] * wka1;
    sqb[r] = acc[2][r] * wqb0 + acc[3][r] * wqb1;
    skb[r] = acc[2][r] * wkb0 + acc[3][r] * wkb1;
  }
#pragma unroll
  for (int m = 1; m <= 8; m <<= 1) {
#pragma unroll
    for (int r = 0; r < 4; r++) {
      sqa[r] += __shfl_xor(sqa[r], m);
      ska[r] += __shfl_xor(ska[r], m);
      sqb[r] += __shfl_xor(sqb[r], m);
      skb[r] += __shfl_xor(skb[r], m);
    }
  }
  if (lc == 0) {
#pragma unroll
    for (int r = 0; r < 4; r++) {
      int gm = mt + wv * 16 + quad * 4 + r;
      int bb = gm >> 9, nn = gm & 511;
      sqT[((size_t)bb * CPH + hA) * CN + nn] = sqa[r];
      skT[((size_t)bb * CPH + hA) * CN + nn] = ska[r];
      sqT[((size_t)bb * CPH + hB) * CN + nn] = sqb[r];
      skT[((size_t)bb * CPH + hB) * CN + nn] = skb[r];
    }
  }
}

// ---------- P_GAT attention, 2 q-tiles/block + factored exp.
// grid (qt=4, h=8, b=16) = 512 blocks, 4 waves. Block: 128 q x 32 d, K=512.
// P = exp(tanh(sq+sk)); e^{2sq},e^{2sk} precomputed -> per element:
// u = tq*tk (1 mul), tanh=(u-1)*rcp(u+1), one exp.
__global__ __launch_bounds__(256) void pgat_attn_mfma2(
    const __bf16* __restrict__ qk, const float* __restrict__ sqT,
    const float* __restrict__ skT, const float* __restrict__ pmask,
    const float* __restrict__ fin, float* __restrict__ fout, int outStride)
{
  const int qt = blockIdx.x;      // 128-q tile
  const int h  = blockIdx.y;
  const int b  = blockIdx.z;
  const int t  = threadIdx.x;
  const int wv = t >> 6;
  const int ln = t & 63;
  const int quad = ln >> 4;
  const int lc   = ln & 15;

  __shared__ __align__(16) __bf16 pbuf[128][72];   // 18.4 KB
  __shared__ __align__(16) __bf16 vbuf[32][72];    // 4.6 KB
  __shared__ float skl[CN];    // e^{2sk}
  __shared__ float pml[CN];
  __shared__ float sql[128];   // e^{2sq}
  __shared__ float pmq[128];

  for (int i = t; i < CN; i += 256) {
    skl[i] = exp2x_clamped(skT[((size_t)b * CPH + h) * CN + i]);
    pml[i] = pmask[b * CN + i];
  }
  if (t < 128) {
    sql[t] = exp2x_clamped(sqT[((size_t)b * CPH + h) * CN + qt * 128 + t]);
    pmq[t] = pmask[b * CN + qt * 128 + t];
  }

  f32x4 aV0 = {0.f,0.f,0.f,0.f}, aV1 = {0.f,0.f,0.f,0.f}, aD = {0.f,0.f,0.f,0.f};
  f32x4 bV0 = {0.f,0.f,0.f,0.f}, bV1 = {0.f,0.f,0.f,0.f}, bD = {0.f,0.f,0.f,0.f};
  bf16x8 ones;
#pragma unroll
  for (int j = 0; j < 8; j++) ones[j] = (__bf16)1.0f;

  const int qg  = t >> 1;         // P-gen: q row 0..127
  const int kb  = (t & 1) * 32;   // P-gen: 32-k half
  const int vkk = t >> 3;         // V-stage: k row 0..31
  const int vdq = (t & 7) * 4;    // V-stage: d quad

  for (int k0 = 0; k0 < CN; k0 += 64) {
    __syncthreads();
    // ---- stage V chunk (64k x 32d) transposed
    {
      bf16x4 v0 = *(const bf16x4*)(qk + ((size_t)(b * CN + k0 + vkk)) * CD + h * CDH + vdq);
      bf16x4 v1 = *(const bf16x4*)(qk + ((size_t)(b * CN + k0 + 32 + vkk)) * CD + h * CDH + vdq);
      vbuf[vdq + 0][vkk] = v0[0]; vbuf[vdq + 1][vkk] = v0[1];
      vbuf[vdq + 2][vkk] = v0[2]; vbuf[vdq + 3][vkk] = v0[3];
      vbuf[vdq + 0][32 + vkk] = v1[0]; vbuf[vdq + 1][32 + vkk] = v1[1];
      vbuf[vdq + 2][32 + vkk] = v1[2]; vbuf[vdq + 3][32 + vkk] = v1[3];
    }
    // ---- generate P: 128q x 64k, 32 elements/thread
    {
      const float tq = sql[qg];
      const float mq = pmq[qg];
#pragma unroll
      for (int g = 0; g < 4; g++) {
        bf16x8 w;
#pragma unroll
        for (int j = 0; j < 8; j++) {
          const int kk = k0 + kb + g * 8 + j;
          float u  = fminf(tq * skl[kk], 1e30f);
          float th = (u - 1.f) * __builtin_amdgcn_rcpf(u + 1.f);
          float e  = __expf(th);
          if (mq * pml[kk] == 0.f) e = 1.f;
          w[j] = (__bf16)e;
        }
        *(bf16x8*)&pbuf[qg][kb + g * 8] = w;
      }
    }
    __syncthreads();
    // ---- MFMA: wave wv owns q rows wv*16.. and 64+wv*16..
#pragma unroll
    for (int s = 0; s < 2; s++) {
      bf16x8 b0 = *(const bf16x8*)&vbuf[lc][s * 32 + quad * 8];
      bf16x8 b1 = *(const bf16x8*)&vbuf[16 + lc][s * 32 + quad * 8];
      bf16x8 fa = *(const bf16x8*)&pbuf[wv * 16 + lc][s * 32 + quad * 8];
      bf16x8 fb = *(const bf16x8*)&pbuf[64 + wv * 16 + lc][s * 32 + quad * 8];
      aV0 = __builtin_amdgcn_mfma_f32_16x16x32_bf16(fa, b0, aV0, 0, 0, 0);
      aV1 = __builtin_amdgcn_mfma_f32_16x16x32_bf16(fa, b1, aV1, 0, 0, 0);
      aD  = __builtin_amdgcn_mfma_f32_16x16x32_bf16(fa, ones, aD, 0, 0, 0);
      bV0 = __builtin_amdgcn_mfma_f32_16x16x32_bf16(fb, b0, bV0, 0, 0, 0);
      bV1 = __builtin_amdgcn_mfma_f32_16x16x32_bf16(fb, b1, bV1, 0, 0, 0);
      bD  = __builtin_amdgcn_mfma_f32_16x16x32_bf16(fb, ones, bD, 0, 0, 0);
    }
  }
#pragma unroll
  for (int r = 0; r < 4; r++) {
    const int d0 = h * CDH + lc;
    {
      int q = qt * 128 + wv * 16 + quad * 4 + r;
      float inv = 1.f / aD[r];
      const float* ip = fin + ((size_t)b * CN + q) * CD;
      float*       op = fout + ((size_t)b * outStride + q) * CD;
      op[d0]      = ip[d0]      + tanh_fast(aV0[r] * inv);
      op[d0 + 16] = ip[d0 + 16] + tanh_fast(aV1[r] * inv);
    }
    {
      int q = qt * 128 + 64 + wv * 16 + quad * 4 + r;
      float inv = 1.f / bD[r];
      const float* ip = fin + ((size_t)b * CN + q) * CD;
      float*       op = fout + ((size_t)b * outStride + q) * CD;
      op[d0]      = ip[d0]      + tanh_fast(bV0[r] * inv);
      op[d0 + 16] = ip[d0 + 16] + tanh_fast(bV1[r] * inv);
    }
  }
}

// ========== UP_GAT stage ==========

__global__ __launch_bounds__(256) void up_q_all(
    const float* __restrict__ cnode,
    const float* __restrict__ qw0, const float* __restrict__ qb0,
    const float* __restrict__ kw0, const float* __restrict__ kb0,
    const float* __restrict__ qw1, const float* __restrict__ qb1,
    const float* __restrict__ kw1, const float* __restrict__ kb1,
    const float* __restrict__ qw2, const float* __restrict__ qb2,
    const float* __restrict__ kw2, const float* __restrict__ kb2,
    const float* __restrict__ qw3, const float* __restrict__ qb3,
    const float* __restrict__ kw3, const float* __restrict__ kb3,
    float* __restrict__ qt_, float* __restrict__ qkb,
    float* __restrict__ comb, float* __restrict__ head, float* __restrict__ den)
{
  const int up = blockIdx.x, b = blockIdx.y, t = threadIdx.x;
  const float* qw = (up == 0) ? qw0 : (up == 1) ? qw1 : (up == 2) ? qw2 : qw3;
  const float* qb = (up == 0) ? qb0 : (up == 1) ? qb1 : (up == 2) ? qb2 : qb3;
  const float* kw = (up == 0) ? kw0 : (up == 1) ? kw1 : (up == 2) ? kw2 : kw3;
  const float* kb = (up == 0) ? kb0 : (up == 1) ? kb1 : (up == 2) ? kb2 : kb3;
  __shared__ float cl[CD];
  __shared__ float ql[CD];
  __shared__ float red[256];
  cl[t] = cnode[b * CD + t];
  head[((size_t)b * 4 + up) * CD + t] = 0.f;
  if (t == 0) den[b * 4 + up] = 0.f;
  __syncthreads();
  if (up == 0) comb[((size_t)b * CNP1 + CN) * CD + t] = cl[t];
  {
    const float* wr = qw + (size_t)t * CD;
    float a = qb[t];
#pragma unroll 4
    for (int k = 0; k < CD; k += 4) {
      float4 w4 = *(const float4*)(wr + k);
      a += cl[k] * w4.x + cl[k + 1] * w4.y + cl[k + 2] * w4.z + cl[k + 3] * w4.w;
    }
    ql[t] = a;
  }
  __syncthreads();
  {
    float a = 0.f;
#pragma unroll 8
    for (int d = 0; d < CD; d++) a += ql[d] * kw[d * CD + t];
    qt_[((size_t)up * CB + b) * CD + t] = a;
  }
  red[t] = ql[t] * kb[t];
  __syncthreads();
  for (int s = 128; s > 0; s >>= 1) { if (t < s) red[t] += red[t + s]; __syncthreads(); }
  if (t == 0) qkb[up * CB + b] = red[0];
}

// sim+exp+weighted-sum fused. grid (16, 9)
__global__ __launch_bounds__(256) void up_headsim(
    const float* __restrict__ comb, const float* __restrict__ qt,
    const float* __restrict__ qkb, const float* __restrict__ pmask,
    float* __restrict__ head, float* __restrict__ den)
{
  const int b = blockIdx.x, n0 = blockIdx.y * 64, t = threadIdx.x;
  const int up = t >> 6, j = t & 63;
  __shared__ float qtl[4][CD];
  __shared__ float qkbl[4];
  __shared__ float attl[4][64];
  for (int i = t; i < 4 * CD; i += 256)
    qtl[i >> 8][i & 255] = qt[((size_t)(i >> 8) * CB + b) * CD + (i & 255)];
  if (t < 4) qkbl[t] = qkb[t * CB + b];
  __syncthreads();
  {
    const int n = n0 + j;
    float e = 0.f;
    if (n < CNP1) {
      const float* cr = comb + ((size_t)b * CNP1 + n) * CD;
      float p = 0.f;
#pragma unroll 4
      for (int d = 0; d < CD; d += 4) {
        float4 c4 = *(const float4*)(cr + d);
        p += qtl[up][d] * c4.x + qtl[up][d + 1] * c4.y
           + qtl[up][d + 2] * c4.z + qtl[up][d + 3] * c4.w;
      }
      float s = (p + qkbl[up]) * 0.0625f;
      float m = (n < CN) ? pmask[b * CN + n] : 1.f;
      if (m == 0.f) s = 1e-8f;
      e = __expf(s);
    }
    attl[up][j] = e;
  }
  __syncthreads();
  float4 acc = make_float4(0.f, 0.f, 0.f, 0.f);
  const int nmax = min(64, CNP1 - n0);
  for (int jj = 0; jj < nmax; jj++) {
    float a = attl[up][jj];
    float4 c4 = *(const float4*)(comb + ((size_t)b * CNP1 + n0 + jj) * CD + j * 4);
    acc.x += a * c4.x; acc.y += a * c4.y; acc.z += a * c4.z; acc.w += a * c4.w;
  }
  float* hp = head + ((size_t)b * 4 + up) * CD + j * 4;
  atomicAdd(hp + 0, acc.x); atomicAdd(hp + 1, acc.y);
  atomicAdd(hp + 2, acc.z); atomicAdd(hp + 3, acc.w);
  if (j == 0) {
    float s = 0.f;
    for (int jj = 0; jj < 64; jj++) s += attl[up][jj];
    atomicAdd(den + b * 4 + up, s);
  }
}

// fused up_out + ugat projection. grid (16, 4): node==up.
__global__ __launch_bounds__(256) void up_out_ugat(
    const float* __restrict__ head, const float* __restrict__ den,
    const float* __restrict__ ow0, const float* __restrict__ ob0,
    const float* __restrict__ ow1, const float* __restrict__ ob1,
    const float* __restrict__ ow2, const float* __restrict__ ob2,
    const float* __restrict__ ow3, const float* __restrict__ ob3,
    const float* __restrict__ ugat_W, const float* __restrict__ attnw,
    float* __restrict__ uout, float* __restrict__ uqk, float* __restrict__ sqk)
{
  const int b = blockIdx.x, up = blockIdx.y, t = threadIdx.x;
  const float* ow = (up == 0) ? ow0 : (up == 1) ? ow1 : (up == 2) ? ow2 : ow3;
  const float* ob = (up == 0) ? ob0 : (up == 1) ? ob1 : (up == 2) ? ob2 : ob3;
  __shared__ float hl[CD];
  __shared__ float xl[CD];
  __shared__ float qkl[CD];
  hl[t] = head[((size_t)b * 4 + up) * CD + t] * (1.f / den[b * 4 + up]);
  __syncthreads();
  {
    const float* r0 = ow + (size_t)t * 4 * CD;
    float a = ob[t];
#pragma unroll 2
    for (int dd = 0; dd < CD; dd += 4) {
      float4 w0 = *(const float4*)(r0 + dd);
      float4 w1 = *(const float4*)(r0 + CD + dd);
      float4 w2 = *(const float4*)(r0 + 2 * CD + dd);
      float4 w3 = *(const float4*)(r0 + 3 * CD + dd);
      a += hl[dd]     * (w0.x + w1.x + w2.x + w3.x)
         + hl[dd + 1] * (w0.y + w1.y + w2.y + w3.y)
         + hl[dd + 2] * (w0.z + w1.z + w2.z + w3.z)
         + hl[dd + 3] * (w0.w + w1.w + w2.w + w3.w);
    }
    xl[t] = a;
    uout[((size_t)b * 4 + up) * CD + t] = a;
  }
  __syncthreads();
  // ugat projection: uqk[t] = sum_d xl[d] * W[t][d]
  {
    const float* wr = ugat_W + (size_t)t * CD;
    float p0 = 0.f, p1 = 0.f, p2 = 0.f, p3 = 0.f;
#pragma unroll 4
    for (int d = 0; d < CD; d += 16) {
      float4 w0 = *(const float4*)(wr + d);
      float4 w1 = *(const float4*)(wr + d + 4);
      float4 w2 = *(const float4*)(wr + d + 8);
      float4 w3 = *(const float4*)(wr + d + 12);
      p0 += xl[d +  0] * w0.x + xl[d +  1] * w0.y + xl[d +  2] * w0.z + xl[d +  3] * w0.w;
      p1 += xl[d +  4] * w1.x + xl[d +  5] * w1.y + xl[d +  6] * w1.z + xl[d +  7] * w1.w;
      p2 += xl[d +  8] * w2.x + xl[d +  9] * w2.y + xl[d + 10] * w2.z + xl[d + 11] * w2.w;
      p3 += xl[d + 12] * w3.x + xl[d + 13] * w3.y + xl[d + 14] * w3.z + xl[d + 15] * w3.w;
    }
    float a = (p0 + p1) + (p2 + p3);
    qkl[t] = a;
    uqk[((size_t)b * 4 + up) * CD + t] = a;
  }
  __syncthreads();
  if (t < 8) {
    const int h = t >> 1, which = t & 1;
    const float* w = attnw + h * 128 + which * 64;
    float s = 0.f;
    for (int j = 0; j < 64; j++) s += qkl[h * 64 + j] * w[j];
    sqk[(((size_t)b * 4 + up) * 4 + h) * 2 + which] = s;
  }
}

// fused U_GAT attention (per-trait) + MLP + classifier. grid (16,4).
__global__ __launch_bounds__(256) void ugat_mlp2(
    const float* __restrict__ u, const float* __restrict__ uqk,
    const float* __restrict__ sqk,
    const float* __restrict__ w1, const float* __restrict__ b1,
    const float* __restrict__ w2, const float* __restrict__ b2,
    const float* __restrict__ f1w, const float* __restrict__ f1b,
    const float* __restrict__ f2w, const float* __restrict__ f2b,
    const float* __restrict__ f3w, const float* __restrict__ f3b,
    const float* __restrict__ f4w, const float* __restrict__ f4b,
    float* __restrict__ out)
{
  const int b = blockIdx.x, trait = blockIdx.y, t = threadIdx.x;
  __shared__ float uq[4][CD];
  __shared__ float sl[4][4], kl[4][4];
  __shared__ float xl[CD];
  __shared__ float h1[CFH];
  __shared__ float h2[CFH];
  for (int i = t; i < 4 * CD; i += 256) uq[i >> 8][i & 255] = uqk[(size_t)b * 4 * CD + i];
  if (t < 16) {
    int node = t >> 2, h = t & 3;
    sl[node][h] = sqk[(((size_t)b * 4 + node) * 4 + h) * 2 + 0];
    kl[node][h] = sqk[(((size_t)b * 4 + node) * 4 + h) * 2 + 1];
  }
  float ur = u[((size_t)b * 4 + trait) * CD + t];
  __syncthreads();
  {
    const int h = t >> 6;
    float e[4]; float ssum = 0.f;
#pragma unroll
    for (int k = 0; k < 4; k++) { e[k] = __expf(tanh_fast(sl[trait][h] + kl[k][h])); ssum += e[k]; }
    float hid = 0.f;
#pragma unroll
    for (int k = 0; k < 4; k++) hid += e[k] * uq[k][t];
    xl[t] = ur + tanh_fast(hid / ssum);
  }
  __syncthreads();
  if (t < CFH) {
    const float* r = w1 + (size_t)t * CD;
    float a = b1[t];
#pragma unroll 4
    for (int k = 0; k < CD; k += 4) {
      float4 v = *(const float4*)(r + k);
      a += xl[k] * v.x + xl[k + 1] * v.y + xl[k + 2] * v.z + xl[k + 3] * v.w;
    }
    h1[t] = fmaxf(a, 0.f);
  }
  __syncthreads();
  if (t < CFH) {
    const float* r = w2 + (size_t)t * CFH;
    float a = b2[t];
#pragma unroll 4
    for (int k = 0; k < CFH; k += 4) {
      float4 v = *(const float4*)(r + k);
      a += h1[k] * v.x + h1[k + 1] * v.y + h1[k + 2] * v.z + h1[k + 3] * v.w;
    }
    h2[t] = fmaxf(a, 0.f);
  }
  __syncthreads();
  if (t < CNC) {
    const float* fw; const float* fb;
    switch (trait) {
      case 0:  fw = f1w; fb = f1b; break;
      case 1:  fw = f2w; fb = f2b; break;
      case 2:  fw = f3w; fb = f3b; break;
      default: fw = f4w; fb = f4b; break;
    }
    const float* r = fw + (size_t)t * CFH;
    float a = fb[t];
    for (int k = 0; k < CFH; k++) a += h2[k] * r[k];
    out[(size_t)trait * (CB * CNC) + b * CNC + t] = a;
  }
}

extern "C" void kernel_launch(void* const* d_in, const int* in_sizes, int n_in,
                              void* d_out, int out_size, void* d_ws, size_t ws_size,
                              hipStream_t stream) {
  (void)in_sizes; (void)n_in; (void)out_size; (void)ws_size;
  const float* pmask    = (const float*)d_in[0];
  const float* feature  = (const float*)d_in[1];
  const float* cnode    = (const float*)d_in[2];
  const float* pgat_W   = (const float*)d_in[3];
  const float* pgat_att = (const float*)d_in[4];
  const float* upw[4][6];
  for (int i = 0; i < 4; i++)
    for (int j = 0; j < 6; j++) upw[i][j] = (const float*)d_in[5 + i * 6 + j];
  const float* ugat_W   = (const float*)d_in[29];
  const float* ugat_att = (const float*)d_in[30];
  const float* mlp_w1 = (const float*)d_in[31];
  const float* mlp_b1 = (const float*)d_in[32];
  const float* mlp_w2 = (const float*)d_in[33];
  const float* mlp_b2 = (const float*)d_in[34];
  const float* fcf[8];
  for (int j = 0; j < 8; j++) fcf[j] = (const float*)d_in[35 + j];

  float* ws = (float*)d_ws;
  size_t o = 0;
  float* ws_qk   = ws + o; o += (size_t)CB * CN * CD;    // bf16 qk lives here
  float* ws_feat = ws + o; o += (size_t)CB * CN * CD;
  float* ws_comb = ws + o; o += (size_t)CB * CNP1 * CD;
  float* ws_sq   = ws + o; o += (size_t)CB * CPH * CN;
  float* ws_sk   = ws + o; o += (size_t)CB * CPH * CN;
  float* ws_qt   = ws + o; o += (size_t)4 * CB * CD;
  float* ws_qkb  = ws + o; o += 4 * CB;
  float* ws_den  = ws + o; o += CB * 4;
  float* ws_head = ws + o; o += (size_t)CB * 4 * CD;
  float* ws_u    = ws + o; o += (size_t)CB * 4 * CD;
  float* ws_uqk  = ws + o; o += (size_t)CB * 4 * CD;
  float* ws_sqk  = ws + o; o += (size_t)CB * 4 * 4 * 2;
  __bf16* qk16 = (__bf16*)ws_qk;

  const dim3 gemmGrid(CD / 64, (CB * CN) / 64);   // (4, 128)
  const dim3 attnGrid(CN / 128, CPH, CB);         // (4, 8, 16)

  // P_GAT layer 1
  gemm_fused<<<gemmGrid, 256, 0, stream>>>(feature, pgat_W, pgat_att, qk16, ws_sq, ws_sk);
  pgat_attn_mfma2<<<attnGrid, 256, 0, stream>>>(qk16, ws_sq, ws_sk, pmask, feature, ws_feat, CN);
  // P_GAT layer 2 (writes into comb rows, stride 513)
  gemm_fused<<<gemmGrid, 256, 0, stream>>>(ws_feat, pgat_W, pgat_att, qk16, ws_sq, ws_sk);
  pgat_attn_mfma2<<<attnGrid, 256, 0, stream>>>(qk16, ws_sq, ws_sk, pmask, ws_feat, ws_comb, CNP1);

  // UP_GAT x4
  up_q_all<<<dim3(4, CB), 256, 0, stream>>>(cnode,
      upw[0][0], upw[0][1], upw[0][2], upw[0][3],
      upw[1][0], upw[1][1], upw[1][2], upw[1][3],
      upw[2][0], upw[2][1], upw[2][2], upw[2][3],
      upw[3][0], upw[3][1], upw[3][2], upw[3][3],
      ws_qt, ws_qkb, ws_comb, ws_head, ws_den);
  up_headsim<<<dim3(CB, (CNP1 + 63) / 64), 256, 0, stream>>>(ws_comb, ws_qt, ws_qkb, pmask,
                                                             ws_head, ws_den);
  up_out_ugat<<<dim3(CB, 4), 256, 0, stream>>>(ws_head, ws_den,
      upw[0][4], upw[0][5], upw[1][4], upw[1][5],
      upw[2][4], upw[2][5], upw[3][4], upw[3][5],
      ugat_W, ugat_att, ws_u, ws_uqk, ws_sqk);

  // U_GAT attention + MLP + heads
  ugat_mlp2<<<dim3(CB, 4), 256, 0, stream>>>(ws_u, ws_uqk, ws_sqk,
                                             mlp_w1, mlp_b1, mlp_w2, mlp_b2,
                                             fcf[0], fcf[1], fcf[2], fcf[3],
                                             fcf[4], fcf[5], fcf[6], fcf[7],
                                             (float*)d_out);
}

// Round 10
// 276.677 us; speedup vs baseline: 2.7754x; 1.0915x over previous
//
#include <hip/hip_runtime.h>

constexpr int CB   = 16;    // batch
constexpr int CN   = 512;   // nodes
constexpr int CD   = 256;   // dim
constexpr int CPH  = 8;     // pgat heads
constexpr int CDH  = 32;    // CD / CPH
constexpr int CNP1 = 513;   // nodes + c_node
constexpr int CFH  = 128;
constexpr int CNC  = 2;

typedef __bf16 bf16x8 __attribute__((ext_vector_type(8)));
typedef __bf16 bf16x4 __attribute__((ext_vector_type(4)));
typedef float  f32x4  __attribute__((ext_vector_type(4)));

__device__ __forceinline__ float tanh_fast(float x) {
  x = fminf(fmaxf(x, -15.f), 15.f);
  float e = __expf(2.f * x);
  return (e - 1.f) / (e + 1.f);
}

__device__ __forceinline__ float exp2x_clamped(float x) {
  x = fminf(fmaxf(x, -18.f), 18.f);
  return __expf(2.f * x);
}

// ---------- bf16-split MFMA GEMM + fused sq/sk epilogue (R7, passing)
__global__ __launch_bounds__(256) void gemm_fused(
    const float* __restrict__ A, const float* __restrict__ W,
    const float* __restrict__ attnw, __bf16* __restrict__ C,
    float* __restrict__ sqT, float* __restrict__ skT)
{
  const int t  = threadIdx.x;
  const int nt = blockIdx.x * 64;
  const int mt = blockIdx.y * 64;
  const int wv = t >> 6, ln = t & 63;
  const int quad = ln >> 4, lc = ln & 15;

  __shared__ __align__(16) __bf16 aHi[64][56];
  __shared__ __align__(16) __bf16 aLo[64][56];
  __shared__ __align__(16) __bf16 bHi[64][56];
  __shared__ __align__(16) __bf16 bLo[64][56];

  f32x4 acc[4];
#pragma unroll
  for (int j = 0; j < 4; j++)
#pragma unroll
    for (int r = 0; r < 4; r++) acc[j][r] = 0.f;

  const int sr  = t >> 2;
  const int skq = (t & 3) * 8;

  for (int k0 = 0; k0 < 256; k0 += 32) {
    __syncthreads();
    {
      const float* ap = A + (size_t)(mt + sr) * 256 + k0 + skq;
      const float* wp = W + (size_t)(nt + sr) * 256 + k0 + skq;
      float4 a0 = *(const float4*)ap, a1 = *(const float4*)(ap + 4);
      float4 w0 = *(const float4*)wp, w1 = *(const float4*)(wp + 4);
      float av[8] = {a0.x, a0.y, a0.z, a0.w, a1.x, a1.y, a1.z, a1.w};
      float wvv[8] = {w0.x, w0.y, w0.z, w0.w, w1.x, w1.y, w1.z, w1.w};
      bf16x8 ah, al, bh, bl;
#pragma unroll
      for (int j = 0; j < 8; j++) {
        ah[j] = (__bf16)av[j];
        al[j] = (__bf16)(av[j] - (float)ah[j]);
        bh[j] = (__bf16)wvv[j];
        bl[j] = (__bf16)(wvv[j] - (float)bh[j]);
      }
      *(bf16x8*)&aHi[sr][skq] = ah;
      *(bf16x8*)&aLo[sr][skq] = al;
      *(bf16x8*)&bHi[sr][skq] = bh;
      *(bf16x8*)&bLo[sr][skq] = bl;
    }
    __syncthreads();
    bf16x8 fah = *(const bf16x8*)&aHi[wv * 16 + lc][quad * 8];
    bf16x8 fal = *(const bf16x8*)&aLo[wv * 16 + lc][quad * 8];
#pragma unroll
    for (int j = 0; j < 4; j++) {
      bf16x8 fbh = *(const bf16x8*)&bHi[j * 16 + lc][quad * 8];
      bf16x8 fbl = *(const bf16x8*)&bLo[j * 16 + lc][quad * 8];
      acc[j] = __builtin_amdgcn_mfma_f32_16x16x32_bf16(fah, fbh, acc[j], 0, 0, 0);
      acc[j] = __builtin_amdgcn_mfma_f32_16x16x32_bf16(fah, fbl, acc[j], 0, 0, 0);
      acc[j] = __builtin_amdgcn_mfma_f32_16x16x32_bf16(fal, fbh, acc[j], 0, 0, 0);
    }
  }
#pragma unroll
  for (int j = 0; j < 4; j++)
#pragma unroll
    for (int r = 0; r < 4; r++)
      C[(size_t)(mt + wv * 16 + quad * 4 + r) * 256 + nt + j * 16 + lc] =
          (__bf16)acc[j][r];

  const int hA = blockIdx.x * 2, hB = hA + 1;
  const float wqa0 = attnw[hA * 64 + lc],      wqa1 = attnw[hA * 64 + 16 + lc];
  const float wka0 = attnw[hA * 64 + 32 + lc], wka1 = attnw[hA * 64 + 48 + lc];
  const float wqb0 = attnw[hB * 64 + lc],      wqb1 = attnw[hB * 64 + 16 + lc];
  const float wkb0 = attnw[hB * 64 + 32 + lc], wkb1 = attnw[hB * 64 + 48 + lc];
  float sqa[4], ska[4], sqb[4], skb[4];
#pragma unroll
  for (int r = 0; r < 4; r++) {
    sqa[r] = acc[0][r] * wqa0 + acc[1][r] * wqa1;
    ska[r] = acc[0][r] * wka0 + acc[1][r] * wka1;
    sqb[r] = acc[2][r] * wqb0 + acc[3][r] * wqb1;
    skb[r] = acc[2][r] * wkb0 + acc[3][r] * wkb1;
  }
#pragma unroll
  for (int m = 1; m <= 8; m <<= 1) {
#pragma unroll
    for (int r = 0; r < 4; r++) {
      sqa[r] += __shfl_xor(sqa[r], m);
      ska[r] += __shfl_xor(ska[r], m);
      sqb[r] += __shfl_xor(sqb[r], m);
      skb[r] += __shfl_xor(skb[r], m);
    }
  }
  if (lc == 0) {
#pragma unroll
    for (int r = 0; r < 4; r++) {
      int gm = mt + wv * 16 + quad * 4 + r;
      int bb = gm >> 9, nn = gm & 511;
      sqT[((size_t)bb * CPH + hA) * CN + nn] = sqa[r];
      skT[((size_t)bb * CPH + hA) * CN + nn] = ska[r];
      sqT[((size_t)bb * CPH + hB) * CN + nn] = sqb[r];
      skT[((size_t)bb * CPH + hB) * CN + nn] = skb[r];
    }
  }
}

// ---------- P_GAT attention, 2 q-tiles/block + factored exp (R7, passing)
__global__ __launch_bounds__(256) void pgat_attn_mfma2(
    const __bf16* __restrict__ qk, const float* __restrict__ sqT,
    const float* __restrict__ skT, const float* __restrict__ pmask,
    const float* __restrict__ fin, float* __restrict__ fout, int outStride)
{
  const int qt = blockIdx.x;
  const int h  = blockIdx.y;
  const int b  = blockIdx.z;
  const int t  = threadIdx.x;
  const int wv = t >> 6;
  const int ln = t & 63;
  const int quad = ln >> 4;
  const int lc   = ln & 15;

  __shared__ __align__(16) __bf16 pbuf[128][72];
  __shared__ __align__(16) __bf16 vbuf[32][72];
  __shared__ float skl[CN];
  __shared__ float pml[CN];
  __shared__ float sql[128];
  __shared__ float pmq[128];

  for (int i = t; i < CN; i += 256) {
    skl[i] = exp2x_clamped(skT[((size_t)b * CPH + h) * CN + i]);
    pml[i] = pmask[b * CN + i];
  }
  if (t < 128) {
    sql[t] = exp2x_clamped(sqT[((size_t)b * CPH + h) * CN + qt * 128 + t]);
    pmq[t] = pmask[b * CN + qt * 128 + t];
  }

  f32x4 aV0 = {0.f,0.f,0.f,0.f}, aV1 = {0.f,0.f,0.f,0.f}, aD = {0.f,0.f,0.f,0.f};
  f32x4 bV0 = {0.f,0.f,0.f,0.f}, bV1 = {0.f,0.f,0.f,0.f}, bD = {0.f,0.f,0.f,0.f};
  bf16x8 ones;
#pragma unroll
  for (int j = 0; j < 8; j++) ones[j] = (__bf16)1.0f;

  const int qg  = t >> 1;
  const int kb  = (t & 1) * 32;
  const int vkk = t >> 3;
  const int vdq = (t & 7) * 4;

  for (int k0 = 0; k0 < CN; k0 += 64) {
    __syncthreads();
    {
      bf16x4 v0 = *(const bf16x4*)(qk + ((size_t)(b * CN + k0 + vkk)) * CD + h * CDH + vdq);
      bf16x4 v1 = *(const bf16x4*)(qk + ((size_t)(b * CN + k0 + 32 + vkk)) * CD + h * CDH + vdq);
      vbuf[vdq + 0][vkk] = v0[0]; vbuf[vdq + 1][vkk] = v0[1];
      vbuf[vdq + 2][vkk] = v0[2]; vbuf[vdq + 3][vkk] = v0[3];
      vbuf[vdq + 0][32 + vkk] = v1[0]; vbuf[vdq + 1][32 + vkk] = v1[1];
      vbuf[vdq + 2][32 + vkk] = v1[2]; vbuf[vdq + 3][32 + vkk] = v1[3];
    }
    {
      const float tq = sql[qg];
      const float mq = pmq[qg];
#pragma unroll
      for (int g = 0; g < 4; g++) {
        bf16x8 w;
#pragma unroll
        for (int j = 0; j < 8; j++) {
          const int kk = k0 + kb + g * 8 + j;
          float u  = fminf(tq * skl[kk], 1e30f);
          float th = (u - 1.f) * __builtin_amdgcn_rcpf(u + 1.f);
          float e  = __expf(th);
          if (mq * pml[kk] == 0.f) e = 1.f;
          w[j] = (__bf16)e;
        }
        *(bf16x8*)&pbuf[qg][kb + g * 8] = w;
      }
    }
    __syncthreads();
#pragma unroll
    for (int s = 0; s < 2; s++) {
      bf16x8 b0 = *(const bf16x8*)&vbuf[lc][s * 32 + quad * 8];
      bf16x8 b1 = *(const bf16x8*)&vbuf[16 + lc][s * 32 + quad * 8];
      bf16x8 fa = *(const bf16x8*)&pbuf[wv * 16 + lc][s * 32 + quad * 8];
      bf16x8 fb = *(const bf16x8*)&pbuf[64 + wv * 16 + lc][s * 32 + quad * 8];
      aV0 = __builtin_amdgcn_mfma_f32_16x16x32_bf16(fa, b0, aV0, 0, 0, 0);
      aV1 = __builtin_amdgcn_mfma_f32_16x16x32_bf16(fa, b1, aV1, 0, 0, 0);
      aD  = __builtin_amdgcn_mfma_f32_16x16x32_bf16(fa, ones, aD, 0, 0, 0);
      bV0 = __builtin_amdgcn_mfma_f32_16x16x32_bf16(fb, b0, bV0, 0, 0, 0);
      bV1 = __builtin_amdgcn_mfma_f32_16x16x32_bf16(fb, b1, bV1, 0, 0, 0);
      bD  = __builtin_amdgcn_mfma_f32_16x16x32_bf16(fb, ones, bD, 0, 0, 0);
    }
  }
#pragma unroll
  for (int r = 0; r < 4; r++) {
    const int d0 = h * CDH + lc;
    {
      int q = qt * 128 + wv * 16 + quad * 4 + r;
      float inv = 1.f / aD[r];
      const float* ip = fin + ((size_t)b * CN + q) * CD;
      float*       op = fout + ((size_t)b * outStride + q) * CD;
      op[d0]      = ip[d0]      + tanh_fast(aV0[r] * inv);
      op[d0 + 16] = ip[d0 + 16] + tanh_fast(aV1[r] * inv);
    }
    {
      int q = qt * 128 + 64 + wv * 16 + quad * 4 + r;
      float inv = 1.f / bD[r];
      const float* ip = fin + ((size_t)b * CN + q) * CD;
      float*       op = fout + ((size_t)b * outStride + q) * CD;
      op[d0]      = ip[d0]      + tanh_fast(bV0[r] * inv);
      op[d0 + 16] = ip[d0 + 16] + tanh_fast(bV1[r] * inv);
    }
  }
}

// ========== UP_GAT stage (R7, passing) ==========

__global__ __launch_bounds__(256) void up_q_all(
    const float* __restrict__ cnode,
    const float* __restrict__ qw0, const float* __restrict__ qb0,
    const float* __restrict__ kw0, const float* __restrict__ kb0,
    const float* __restrict__ qw1, const float* __restrict__ qb1,
    const float* __restrict__ kw1, const float* __restrict__ kb1,
    const float* __restrict__ qw2, const float* __restrict__ qb2,
    const float* __restrict__ kw2, const float* __restrict__ kb2,
    const float* __restrict__ qw3, const float* __restrict__ qb3,
    const float* __restrict__ kw3, const float* __restrict__ kb3,
    float* __restrict__ qt_, float* __restrict__ qkb,
    float* __restrict__ comb, float* __restrict__ head, float* __restrict__ den)
{
  const int up = blockIdx.x, b = blockIdx.y, t = threadIdx.x;
  const float* qw = (up == 0) ? qw0 : (up == 1) ? qw1 : (up == 2) ? qw2 : qw3;
  const float* qb = (up == 0) ? qb0 : (up == 1) ? qb1 : (up == 2) ? qb2 : qb3;
  const float* kw = (up == 0) ? kw0 : (up == 1) ? kw1 : (up == 2) ? kw2 : kw3;
  const float* kb = (up == 0) ? kb0 : (up == 1) ? kb1 : (up == 2) ? kb2 : kb3;
  __shared__ float cl[CD];
  __shared__ float ql[CD];
  __shared__ float red[256];
  cl[t] = cnode[b * CD + t];
  head[((size_t)b * 4 + up) * CD + t] = 0.f;
  if (t == 0) den[b * 4 + up] = 0.f;
  __syncthreads();
  if (up == 0) comb[((size_t)b * CNP1 + CN) * CD + t] = cl[t];
  {
    const float* wr = qw + (size_t)t * CD;
    float a = qb[t];
#pragma unroll 4
    for (int k = 0; k < CD; k += 4) {
      float4 w4 = *(const float4*)(wr + k);
      a += cl[k] * w4.x + cl[k + 1] * w4.y + cl[k + 2] * w4.z + cl[k + 3] * w4.w;
    }
    ql[t] = a;
  }
  __syncthreads();
  {
    float a = 0.f;
#pragma unroll 8
    for (int d = 0; d < CD; d++) a += ql[d] * kw[d * CD + t];
    qt_[((size_t)up * CB + b) * CD + t] = a;
  }
  red[t] = ql[t] * kb[t];
  __syncthreads();
  for (int s = 128; s > 0; s >>= 1) { if (t < s) red[t] += red[t + s]; __syncthreads(); }
  if (t == 0) qkb[up * CB + b] = red[0];
}

// sim+exp+weighted-sum fused. grid (16, 9)  (R7, passing)
__global__ __launch_bounds__(256) void up_headsim(
    const float* __restrict__ comb, const float* __restrict__ qt,
    const float* __restrict__ qkb, const float* __restrict__ pmask,
    float* __restrict__ head, float* __restrict__ den)
{
  const int b = blockIdx.x, n0 = blockIdx.y * 64, t = threadIdx.x;
  const int up = t >> 6, j = t & 63;
  __shared__ float qtl[4][CD];
  __shared__ float qkbl[4];
  __shared__ float attl[4][64];
  for (int i = t; i < 4 * CD; i += 256)
    qtl[i >> 8][i & 255] = qt[((size_t)(i >> 8) * CB + b) * CD + (i & 255)];
  if (t < 4) qkbl[t] = qkb[t * CB + b];
  __syncthreads();
  {
    const int n = n0 + j;
    float e = 0.f;
    if (n < CNP1) {
      const float* cr = comb + ((size_t)b * CNP1 + n) * CD;
      float p = 0.f;
#pragma unroll 4
      for (int d = 0; d < CD; d += 4) {
        float4 c4 = *(const float4*)(cr + d);
        p += qtl[up][d] * c4.x + qtl[up][d + 1] * c4.y
           + qtl[up][d + 2] * c4.z + qtl[up][d + 3] * c4.w;
      }
      float s = (p + qkbl[up]) * 0.0625f;
      float m = (n < CN) ? pmask[b * CN + n] : 1.f;
      if (m == 0.f) s = 1e-8f;
      e = __expf(s);
    }
    attl[up][j] = e;
  }
  __syncthreads();
  float4 acc = make_float4(0.f, 0.f, 0.f, 0.f);
  const int nmax = min(64, CNP1 - n0);
  for (int jj = 0; jj < nmax; jj++) {
    float a = attl[up][jj];
    float4 c4 = *(const float4*)(comb + ((size_t)b * CNP1 + n0 + jj) * CD + j * 4);
    acc.x += a * c4.x; acc.y += a * c4.y; acc.z += a * c4.z; acc.w += a * c4.w;
  }
  float* hp = head + ((size_t)b * 4 + up) * CD + j * 4;
  atomicAdd(hp + 0, acc.x); atomicAdd(hp + 1, acc.y);
  atomicAdd(hp + 2, acc.z); atomicAdd(hp + 3, acc.w);
  if (j == 0) {
    float s = 0.f;
    for (int jj = 0; jj < 64; jj++) s += attl[up][jj];
    atomicAdd(den + b * 4 + up, s);
  }
}

// ---------- NEW: fold ow -> weff once (fp32). weff[up][n][e] = sum_r ow[n][r*256+e]
// grid (4, 64), 256 thr, 1 float4 per thread. Fold order (w0+w1)+(w2+w3)... keep
// left-to-right to match R7 exactly: ((x+y)+z)+w per component.
__global__ __launch_bounds__(256) void fold_ow(
    const float* __restrict__ ow0, const float* __restrict__ ow1,
    const float* __restrict__ ow2, const float* __restrict__ ow3,
    float* __restrict__ weff)
{
  const int up = blockIdx.x;
  const float* ow = (up == 0) ? ow0 : (up == 1) ? ow1 : (up == 2) ? ow2 : ow3;
  const int idx = blockIdx.y * 256 + threadIdx.x;   // 0..16383 float4s
  const int n = idx >> 6, e4 = (idx & 63) * 4;
  const float* base = ow + (size_t)n * (4 * CD) + e4;
  float4 w0 = *(const float4*)(base);
  float4 w1 = *(const float4*)(base + CD);
  float4 w2 = *(const float4*)(base + 2 * CD);
  float4 w3 = *(const float4*)(base + 3 * CD);
  float4 o;
  o.x = w0.x + w1.x + w2.x + w3.x;
  o.y = w0.y + w1.y + w2.y + w3.y;
  o.z = w0.z + w1.z + w2.z + w3.z;
  o.w = w0.w + w1.w + w2.w + w3.w;
  *(float4*)(weff + (size_t)up * CD * CD + (size_t)n * CD + e4) = o;
}

// fused up_out + ugat projection, reading L2-resident weff. grid (16, 4).
__global__ __launch_bounds__(256) void up_out_ugat(
    const float* __restrict__ head, const float* __restrict__ den,
    const float* __restrict__ weff,
    const float* __restrict__ ob0, const float* __restrict__ ob1,
    const float* __restrict__ ob2, const float* __restrict__ ob3,
    const float* __restrict__ ugat_W, const float* __restrict__ attnw,
    float* __restrict__ uout, float* __restrict__ uqk, float* __restrict__ sqk)
{
  const int b = blockIdx.x, up = blockIdx.y, t = threadIdx.x;
  const float* ob = (up == 0) ? ob0 : (up == 1) ? ob1 : (up == 2) ? ob2 : ob3;
  __shared__ float hl[CD];
  __shared__ float xl[CD];
  __shared__ float qkl[CD];
  hl[t] = head[((size_t)b * 4 + up) * CD + t] * (1.f / den[b * 4 + up]);
  __syncthreads();
  // u[n=t] = ob[n] + sum_e weff[up][n][e] * hl[e], 4-way ILP partials
  {
    const float* r0 = weff + (size_t)up * CD * CD + (size_t)t * CD;
    float p0 = 0.f, p1 = 0.f, p2 = 0.f, p3 = 0.f;
#pragma unroll 4
    for (int d = 0; d < CD; d += 16) {
      float4 w0 = *(const float4*)(r0 + d);
      float4 w1 = *(const float4*)(r0 + d + 4);
      float4 w2 = *(const float4*)(r0 + d + 8);
      float4 w3 = *(const float4*)(r0 + d + 12);
      p0 += hl[d +  0] * w0.x + hl[d +  1] * w0.y + hl[d +  2] * w0.z + hl[d +  3] * w0.w;
      p1 += hl[d +  4] * w1.x + hl[d +  5] * w1.y + hl[d +  6] * w1.z + hl[d +  7] * w1.w;
      p2 += hl[d +  8] * w2.x + hl[d +  9] * w2.y + hl[d + 10] * w2.z + hl[d + 11] * w2.w;
      p3 += hl[d + 12] * w3.x + hl[d + 13] * w3.y + hl[d + 14] * w3.z + hl[d + 15] * w3.w;
    }
    float a = ob[t] + ((p0 + p1) + (p2 + p3));
    xl[t] = a;
    uout[((size_t)b * 4 + up) * CD + t] = a;
  }
  __syncthreads();
  // ugat projection: uqk[t] = sum_d xl[d] * W[t][d]
  {
    const float* wr = ugat_W + (size_t)t * CD;
    float p0 = 0.f, p1 = 0.f, p2 = 0.f, p3 = 0.f;
#pragma unroll 4
    for (int d = 0; d < CD; d += 16) {
      float4 w0 = *(const float4*)(wr + d);
      float4 w1 = *(const float4*)(wr + d + 4);
      float4 w2 = *(const float4*)(wr + d + 8);
      float4 w3 = *(const float4*)(wr + d + 12);
      p0 += xl[d +  0] * w0.x + xl[d +  1] * w0.y + xl[d +  2] * w0.z + xl[d +  3] * w0.w;
      p1 += xl[d +  4] * w1.x + xl[d +  5] * w1.y + xl[d +  6] * w1.z + xl[d +  7] * w1.w;
      p2 += xl[d +  8] * w2.x + xl[d +  9] * w2.y + xl[d + 10] * w2.z + xl[d + 11] * w2.w;
      p3 += xl[d + 12] * w3.x + xl[d + 13] * w3.y + xl[d + 14] * w3.z + xl[d + 15] * w3.w;
    }
    float a = (p0 + p1) + (p2 + p3);
    qkl[t] = a;
    uqk[((size_t)b * 4 + up) * CD + t] = a;
  }
  __syncthreads();
  if (t < 8) {
    const int h = t >> 1, which = t & 1;
    const float* w = attnw + h * 128 + which * 64;
    float s = 0.f;
    for (int j = 0; j < 64; j++) s += qkl[h * 64 + j] * w[j];
    sqk[(((size_t)b * 4 + up) * 4 + h) * 2 + which] = s;
  }
}

// fused U_GAT attention (per-trait) + MLP + classifier. grid (16,4). (R7)
__global__ __launch_bounds__(256) void ugat_mlp2(
    const float* __restrict__ u, const float* __restrict__ uqk,
    const float* __restrict__ sqk,
    const float* __restrict__ w1, const float* __restrict__ b1,
    const float* __restrict__ w2, const float* __restrict__ b2,
    const float* __restrict__ f1w, const float* __restrict__ f1b,
    const float* __restrict__ f2w, const float* __restrict__ f2b,
    const float* __restrict__ f3w, const float* __restrict__ f3b,
    const float* __restrict__ f4w, const float* __restrict__ f4b,
    float* __restrict__ out)
{
  const int b = blockIdx.x, trait = blockIdx.y, t = threadIdx.x;
  __shared__ float uq[4][CD];
  __shared__ float sl[4][4], kl[4][4];
  __shared__ float xl[CD];
  __shared__ float h1[CFH];
  __shared__ float h2[CFH];
  for (int i = t; i < 4 * CD; i += 256) uq[i >> 8][i & 255] = uqk[(size_t)b * 4 * CD + i];
  if (t < 16) {
    int node = t >> 2, h = t & 3;
    sl[node][h] = sqk[(((size_t)b * 4 + node) * 4 + h) * 2 + 0];
    kl[node][h] = sqk[(((size_t)b * 4 + node) * 4 + h) * 2 + 1];
  }
  float ur = u[((size_t)b * 4 + trait) * CD + t];
  __syncthreads();
  {
    const int h = t >> 6;
    float e[4]; float ssum = 0.f;
#pragma unroll
    for (int k = 0; k < 4; k++) { e[k] = __expf(tanh_fast(sl[trait][h] + kl[k][h])); ssum += e[k]; }
    float hid = 0.f;
#pragma unroll
    for (int k = 0; k < 4; k++) hid += e[k] * uq[k][t];
    xl[t] = ur + tanh_fast(hid / ssum);
  }
  __syncthreads();
  if (t < CFH) {
    const float* r = w1 + (size_t)t * CD;
    float a = b1[t];
#pragma unroll 4
    for (int k = 0; k < CD; k += 4) {
      float4 v = *(const float4*)(r + k);
      a += xl[k] * v.x + xl[k + 1] * v.y + xl[k + 2] * v.z + xl[k + 3] * v.w;
    }
    h1[t] = fmaxf(a, 0.f);
  }
  __syncthreads();
  if (t < CFH) {
    const float* r = w2 + (size_t)t * CFH;
    float a = b2[t];
#pragma unroll 4
    for (int k = 0; k < CFH; k += 4) {
      float4 v = *(const float4*)(r + k);
      a += h1[k] * v.x + h1[k + 1] * v.y + h1[k + 2] * v.z + h1[k + 3] * v.w;
    }
    h2[t] = fmaxf(a, 0.f);
  }
  __syncthreads();
  if (t < CNC) {
    const float* fw; const float* fb;
    switch (trait) {
      case 0:  fw = f1w; fb = f1b; break;
      case 1:  fw = f2w; fb = f2b; break;
      case 2:  fw = f3w; fb = f3b; break;
      default: fw = f4w; fb = f4b; break;
    }
    const float* r = fw + (size_t)t * CFH;
    float a = fb[t];
    for (int k = 0; k < CFH; k++) a += h2[k] * r[k];
    out[(size_t)trait * (CB * CNC) + b * CNC + t] = a;
  }
}

extern "C" void kernel_launch(void* const* d_in, const int* in_sizes, int n_in,
                              void* d_out, int out_size, void* d_ws, size_t ws_size,
                              hipStream_t stream) {
  (void)in_sizes; (void)n_in; (void)out_size; (void)ws_size;
  const float* pmask    = (const float*)d_in[0];
  const float* feature  = (const float*)d_in[1];
  const float* cnode    = (const float*)d_in[2];
  const float* pgat_W   = (const float*)d_in[3];
  const float* pgat_att = (const float*)d_in[4];
  const float* upw[4][6];
  for (int i = 0; i < 4; i++)
    for (int j = 0; j < 6; j++) upw[i][j] = (const float*)d_in[5 + i * 6 + j];
  const float* ugat_W   = (const float*)d_in[29];
  const float* ugat_att = (const float*)d_in[30];
  const float* mlp_w1 = (const float*)d_in[31];
  const float* mlp_b1 = (const float*)d_in[32];
  const float* mlp_w2 = (const float*)d_in[33];
  const float* mlp_b2 = (const float*)d_in[34];
  const float* fcf[8];
  for (int j = 0; j < 8; j++) fcf[j] = (const float*)d_in[35 + j];

  float* ws = (float*)d_ws;
  size_t o = 0;
  float* ws_qk   = ws + o; o += (size_t)CB * CN * CD;    // bf16 qk lives here
  float* ws_feat = ws + o; o += (size_t)CB * CN * CD;
  float* ws_comb = ws + o; o += (size_t)CB * CNP1 * CD;
  float* ws_sq   = ws + o; o += (size_t)CB * CPH * CN;
  float* ws_sk   = ws + o; o += (size_t)CB * CPH * CN;
  float* ws_qt   = ws + o; o += (size_t)4 * CB * CD;
  float* ws_qkb  = ws + o; o += 4 * CB;
  float* ws_den  = ws + o; o += CB * 4;
  float* ws_head = ws + o; o += (size_t)CB * 4 * CD;
  float* ws_u    = ws + o; o += (size_t)CB * 4 * CD;
  float* ws_uqk  = ws + o; o += (size_t)CB * 4 * CD;
  float* ws_sqk  = ws + o; o += (size_t)CB * 4 * 4 * 2;
  float* ws_weff = ws + o; o += (size_t)4 * CD * CD;
  __bf16* qk16 = (__bf16*)ws_qk;

  const dim3 gemmGrid(CD / 64, (CB * CN) / 64);   // (4, 128)
  const dim3 attnGrid(CN / 128, CPH, CB);         // (4, 8, 16)

  // P_GAT layer 1
  gemm_fused<<<gemmGrid, 256, 0, stream>>>(feature, pgat_W, pgat_att, qk16, ws_sq, ws_sk);
  pgat_attn_mfma2<<<attnGrid, 256, 0, stream>>>(qk16, ws_sq, ws_sk, pmask, feature, ws_feat, CN);
  // P_GAT layer 2 (writes into comb rows, stride 513)
  gemm_fused<<<gemmGrid, 256, 0, stream>>>(ws_feat, pgat_W, pgat_att, qk16, ws_sq, ws_sk);
  pgat_attn_mfma2<<<attnGrid, 256, 0, stream>>>(qk16, ws_sq, ws_sk, pmask, ws_feat, ws_comb, CNP1);

  // fold ow once (overlaps with P_GAT dependency-wise? independent inputs, but
  // same stream: cheap ~3 µs)
  fold_ow<<<dim3(4, 64), 256, 0, stream>>>(upw[0][4], upw[1][4], upw[2][4], upw[3][4], ws_weff);

  // UP_GAT x4
  up_q_all<<<dim3(4, CB), 256, 0, stream>>>(cnode,
      upw[0][0], upw[0][1], upw[0][2], upw[0][3],
      upw[1][0], upw[1][1], upw[1][2], upw[1][3],
      upw[2][0], upw[2][1], upw[2][2], upw[2][3],
      upw[3][0], upw[3][1], upw[3][2], upw[3][3],
      ws_qt, ws_qkb, ws_comb, ws_head, ws_den);
  up_headsim<<<dim3(CB, (CNP1 + 63) / 64), 256, 0, stream>>>(ws_comb, ws_qt, ws_qkb, pmask,
                                                             ws_head, ws_den);
  up_out_ugat<<<dim3(CB, 4), 256, 0, stream>>>(ws_head, ws_den, ws_weff,
      upw[0][5], upw[1][5], upw[2][5], upw[3][5],
      ugat_W, ugat_att, ws_u, ws_uqk, ws_sqk);

  // U_GAT attention + MLP + heads
  ugat_mlp2<<<dim3(CB, 4), 256, 0, stream>>>(ws_u, ws_uqk, ws_sqk,
                                             mlp_w1, mlp_b1, mlp_w2, mlp_b2,
                                             fcf[0], fcf[1], fcf[2], fcf[3],
                                             fcf[4], fcf[5], fcf[6], fcf[7],
                                             (float*)d_out);
}

// Round 11
// 270.721 us; speedup vs baseline: 2.8365x; 1.0220x over previous
//
#include <hip/hip_runtime.h>

constexpr int CB   = 16;    // batch
constexpr int CN   = 512;   // nodes
constexpr int CD   = 256;   // dim
constexpr int CPH  = 8;     // pgat heads
constexpr int CDH  = 32;    // CD / CPH
constexpr int CNP1 = 513;   // nodes + c_node
constexpr int CFH  = 128;
constexpr int CNC  = 2;

typedef __bf16 bf16x8 __attribute__((ext_vector_type(8)));
typedef __bf16 bf16x4 __attribute__((ext_vector_type(4)));
typedef float  f32x4  __attribute__((ext_vector_type(4)));

__device__ __forceinline__ float tanh_fast(float x) {
  x = fminf(fmaxf(x, -15.f), 15.f);
  float e = __expf(2.f * x);
  return (e - 1.f) / (e + 1.f);
}

__device__ __forceinline__ float exp2x_clamped(float x) {
  x = fminf(fmaxf(x, -18.f), 18.f);
  return __expf(2.f * x);
}

// ---------- bf16-split MFMA GEMM + fused sq/sk epilogue (passing since R6)
__global__ __launch_bounds__(256) void gemm_fused(
    const float* __restrict__ A, const float* __restrict__ W,
    const float* __restrict__ attnw, __bf16* __restrict__ C,
    float* __restrict__ sqT, float* __restrict__ skT)
{
  const int t  = threadIdx.x;
  const int nt = blockIdx.x * 64;
  const int mt = blockIdx.y * 64;
  const int wv = t >> 6, ln = t & 63;
  const int quad = ln >> 4, lc = ln & 15;

  __shared__ __align__(16) __bf16 aHi[64][56];
  __shared__ __align__(16) __bf16 aLo[64][56];
  __shared__ __align__(16) __bf16 bHi[64][56];
  __shared__ __align__(16) __bf16 bLo[64][56];

  f32x4 acc[4];
#pragma unroll
  for (int j = 0; j < 4; j++)
#pragma unroll
    for (int r = 0; r < 4; r++) acc[j][r] = 0.f;

  const int sr  = t >> 2;
  const int skq = (t & 3) * 8;

  for (int k0 = 0; k0 < 256; k0 += 32) {
    __syncthreads();
    {
      const float* ap = A + (size_t)(mt + sr) * 256 + k0 + skq;
      const float* wp = W + (size_t)(nt + sr) * 256 + k0 + skq;
      float4 a0 = *(const float4*)ap, a1 = *(const float4*)(ap + 4);
      float4 w0 = *(const float4*)wp, w1 = *(const float4*)(wp + 4);
      float av[8] = {a0.x, a0.y, a0.z, a0.w, a1.x, a1.y, a1.z, a1.w};
      float wvv[8] = {w0.x, w0.y, w0.z, w0.w, w1.x, w1.y, w1.z, w1.w};
      bf16x8 ah, al, bh, bl;
#pragma unroll
      for (int j = 0; j < 8; j++) {
        ah[j] = (__bf16)av[j];
        al[j] = (__bf16)(av[j] - (float)ah[j]);
        bh[j] = (__bf16)wvv[j];
        bl[j] = (__bf16)(wvv[j] - (float)bh[j]);
      }
      *(bf16x8*)&aHi[sr][skq] = ah;
      *(bf16x8*)&aLo[sr][skq] = al;
      *(bf16x8*)&bHi[sr][skq] = bh;
      *(bf16x8*)&bLo[sr][skq] = bl;
    }
    __syncthreads();
    bf16x8 fah = *(const bf16x8*)&aHi[wv * 16 + lc][quad * 8];
    bf16x8 fal = *(const bf16x8*)&aLo[wv * 16 + lc][quad * 8];
#pragma unroll
    for (int j = 0; j < 4; j++) {
      bf16x8 fbh = *(const bf16x8*)&bHi[j * 16 + lc][quad * 8];
      bf16x8 fbl = *(const bf16x8*)&bLo[j * 16 + lc][quad * 8];
      acc[j] = __builtin_amdgcn_mfma_f32_16x16x32_bf16(fah, fbh, acc[j], 0, 0, 0);
      acc[j] = __builtin_amdgcn_mfma_f32_16x16x32_bf16(fah, fbl, acc[j], 0, 0, 0);
      acc[j] = __builtin_amdgcn_mfma_f32_16x16x32_bf16(fal, fbh, acc[j], 0, 0, 0);
    }
  }
#pragma unroll
  for (int j = 0; j < 4; j++)
#pragma unroll
    for (int r = 0; r < 4; r++)
      C[(size_t)(mt + wv * 16 + quad * 4 + r) * 256 + nt + j * 16 + lc] =
          (__bf16)acc[j][r];

  const int hA = blockIdx.x * 2, hB = hA + 1;
  const float wqa0 = attnw[hA * 64 + lc],      wqa1 = attnw[hA * 64 + 16 + lc];
  const float wka0 = attnw[hA * 64 + 32 + lc], wka1 = attnw[hA * 64 + 48 + lc];
  const float wqb0 = attnw[hB * 64 + lc],      wqb1 = attnw[hB * 64 + 16 + lc];
  const float wkb0 = attnw[hB * 64 + 32 + lc], wkb1 = attnw[hB * 64 + 48 + lc];
  float sqa[4], ska[4], sqb[4], skb[4];
#pragma unroll
  for (int r = 0; r < 4; r++) {
    sqa[r] = acc[0][r] * wqa0 + acc[1][r] * wqa1;
    ska[r] = acc[0][r] * wka0 + acc[1][r] * wka1;
    sqb[r] = acc[2][r] * wqb0 + acc[3][r] * wqb1;
    skb[r] = acc[2][r] * wkb0 + acc[3][r] * wkb1;
  }
#pragma unroll
  for (int m = 1; m <= 8; m <<= 1) {
#pragma unroll
    for (int r = 0; r < 4; r++) {
      sqa[r] += __shfl_xor(sqa[r], m);
      ska[r] += __shfl_xor(ska[r], m);
      sqb[r] += __shfl_xor(sqb[r], m);
      skb[r] += __shfl_xor(skb[r], m);
    }
  }
  if (lc == 0) {
#pragma unroll
    for (int r = 0; r < 4; r++) {
      int gm = mt + wv * 16 + quad * 4 + r;
      int bb = gm >> 9, nn = gm & 511;
      sqT[((size_t)bb * CPH + hA) * CN + nn] = sqa[r];
      skT[((size_t)bb * CPH + hA) * CN + nn] = ska[r];
      sqT[((size_t)bb * CPH + hB) * CN + nn] = sqb[r];
      skT[((size_t)bb * CPH + hB) * CN + nn] = skb[r];
    }
  }
}

// ---------- P_GAT attention, trimmed P-gen.
// masks staged as 0/1; masked -> th=0 -> exp(0)=1 (bf16-identical to old path).
__global__ __launch_bounds__(256) void pgat_attn_mfma2(
    const __bf16* __restrict__ qk, const float* __restrict__ sqT,
    const float* __restrict__ skT, const float* __restrict__ pmask,
    const float* __restrict__ fin, float* __restrict__ fout, int outStride)
{
  const int qt = blockIdx.x;
  const int h  = blockIdx.y;
  const int b  = blockIdx.z;
  const int t  = threadIdx.x;
  const int wv = t >> 6;
  const int ln = t & 63;
  const int quad = ln >> 4;
  const int lc   = ln & 15;

  __shared__ __align__(16) __bf16 pbuf[128][72];
  __shared__ __align__(16) __bf16 vbuf[32][72];
  __shared__ float skl[CN];    // e^{2sk}
  __shared__ float ckm[CN];    // k mask as 0/1
  __shared__ float sql[128];   // e^{2sq}
  __shared__ float qfm[128];   // q mask as 0/1

  for (int i = t; i < CN; i += 256) {
    skl[i] = exp2x_clamped(skT[((size_t)b * CPH + h) * CN + i]);
    ckm[i] = (pmask[b * CN + i] == 0.f) ? 0.f : 1.f;
  }
  if (t < 128) {
    sql[t] = exp2x_clamped(sqT[((size_t)b * CPH + h) * CN + qt * 128 + t]);
    qfm[t] = (pmask[b * CN + qt * 128 + t] == 0.f) ? 0.f : 1.f;
  }

  f32x4 aV0 = {0.f,0.f,0.f,0.f}, aV1 = {0.f,0.f,0.f,0.f}, aD = {0.f,0.f,0.f,0.f};
  f32x4 bV0 = {0.f,0.f,0.f,0.f}, bV1 = {0.f,0.f,0.f,0.f}, bD = {0.f,0.f,0.f,0.f};
  bf16x8 ones;
#pragma unroll
  for (int j = 0; j < 8; j++) ones[j] = (__bf16)1.0f;

  const int qg  = t >> 1;
  const int kb  = (t & 1) * 32;
  const int vkk = t >> 3;
  const int vdq = (t & 7) * 4;

  for (int k0 = 0; k0 < CN; k0 += 64) {
    __syncthreads();
    {
      bf16x4 v0 = *(const bf16x4*)(qk + ((size_t)(b * CN + k0 + vkk)) * CD + h * CDH + vdq);
      bf16x4 v1 = *(const bf16x4*)(qk + ((size_t)(b * CN + k0 + 32 + vkk)) * CD + h * CDH + vdq);
      vbuf[vdq + 0][vkk] = v0[0]; vbuf[vdq + 1][vkk] = v0[1];
      vbuf[vdq + 2][vkk] = v0[2]; vbuf[vdq + 3][vkk] = v0[3];
      vbuf[vdq + 0][32 + vkk] = v1[0]; vbuf[vdq + 1][32 + vkk] = v1[1];
      vbuf[vdq + 2][32 + vkk] = v1[2]; vbuf[vdq + 3][32 + vkk] = v1[3];
    }
    {
      const float tq = sql[qg];
      const float qf = qfm[qg];
#pragma unroll
      for (int g = 0; g < 4; g++) {
        bf16x8 w;
#pragma unroll
        for (int j = 0; j < 8; j++) {
          const int kk = k0 + kb + g * 8 + j;
          float u  = tq * skl[kk];
          float th = (u - 1.f) * __builtin_amdgcn_rcpf(u + 1.f);
          th *= qf * ckm[kk];
          w[j] = (__bf16)__expf(th);
        }
        *(bf16x8*)&pbuf[qg][kb + g * 8] = w;
      }
    }
    __syncthreads();
#pragma unroll
    for (int s = 0; s < 2; s++) {
      bf16x8 b0 = *(const bf16x8*)&vbuf[lc][s * 32 + quad * 8];
      bf16x8 b1 = *(const bf16x8*)&vbuf[16 + lc][s * 32 + quad * 8];
      bf16x8 fa = *(const bf16x8*)&pbuf[wv * 16 + lc][s * 32 + quad * 8];
      bf16x8 fb = *(const bf16x8*)&pbuf[64 + wv * 16 + lc][s * 32 + quad * 8];
      aV0 = __builtin_amdgcn_mfma_f32_16x16x32_bf16(fa, b0, aV0, 0, 0, 0);
      aV1 = __builtin_amdgcn_mfma_f32_16x16x32_bf16(fa, b1, aV1, 0, 0, 0);
      aD  = __builtin_amdgcn_mfma_f32_16x16x32_bf16(fa, ones, aD, 0, 0, 0);
      bV0 = __builtin_amdgcn_mfma_f32_16x16x32_bf16(fb, b0, bV0, 0, 0, 0);
      bV1 = __builtin_amdgcn_mfma_f32_16x16x32_bf16(fb, b1, bV1, 0, 0, 0);
      bD  = __builtin_amdgcn_mfma_f32_16x16x32_bf16(fb, ones, bD, 0, 0, 0);
    }
  }
#pragma unroll
  for (int r = 0; r < 4; r++) {
    const int d0 = h * CDH + lc;
    {
      int q = qt * 128 + wv * 16 + quad * 4 + r;
      float inv = 1.f / aD[r];
      const float* ip = fin + ((size_t)b * CN + q) * CD;
      float*       op = fout + ((size_t)b * outStride + q) * CD;
      op[d0]      = ip[d0]      + tanh_fast(aV0[r] * inv);
      op[d0 + 16] = ip[d0 + 16] + tanh_fast(aV1[r] * inv);
    }
    {
      int q = qt * 128 + 64 + wv * 16 + quad * 4 + r;
      float inv = 1.f / bD[r];
      const float* ip = fin + ((size_t)b * CN + q) * CD;
      float*       op = fout + ((size_t)b * outStride + q) * CD;
      op[d0]      = ip[d0]      + tanh_fast(bV0[r] * inv);
      op[d0 + 16] = ip[d0 + 16] + tanh_fast(bV1[r] * inv);
    }
  }
}

// ========== UP_GAT stage ==========

// grid (up=4, b=16). Also: c_node->comb row 512, zero head/den, and fold a
// 16-row slice of weff[up] (weff[up][n][e] = sum_r ow[up][n][r*256+e]).
__global__ __launch_bounds__(256) void up_q_all(
    const float* __restrict__ cnode,
    const float* __restrict__ qw0, const float* __restrict__ qb0,
    const float* __restrict__ kw0, const float* __restrict__ kb0,
    const float* __restrict__ ow0,
    const float* __restrict__ qw1, const float* __restrict__ qb1,
    const float* __restrict__ kw1, const float* __restrict__ kb1,
    const float* __restrict__ ow1,
    const float* __restrict__ qw2, const float* __restrict__ qb2,
    const float* __restrict__ kw2, const float* __restrict__ kb2,
    const float* __restrict__ ow2,
    const float* __restrict__ qw3, const float* __restrict__ qb3,
    const float* __restrict__ kw3, const float* __restrict__ kb3,
    const float* __restrict__ ow3,
    float* __restrict__ qt_, float* __restrict__ qkb,
    float* __restrict__ comb, float* __restrict__ head, float* __restrict__ den,
    float* __restrict__ weff)
{
  const int up = blockIdx.x, b = blockIdx.y, t = threadIdx.x;
  const float* qw = (up == 0) ? qw0 : (up == 1) ? qw1 : (up == 2) ? qw2 : qw3;
  const float* qb = (up == 0) ? qb0 : (up == 1) ? qb1 : (up == 2) ? qb2 : qb3;
  const float* kw = (up == 0) ? kw0 : (up == 1) ? kw1 : (up == 2) ? kw2 : kw3;
  const float* kb = (up == 0) ? kb0 : (up == 1) ? kb1 : (up == 2) ? kb2 : kb3;
  const float* ow = (up == 0) ? ow0 : (up == 1) ? ow1 : (up == 2) ? ow2 : ow3;
  __shared__ float cl[CD];
  __shared__ float ql[CD];
  __shared__ float red[256];
  cl[t] = cnode[b * CD + t];
  head[((size_t)b * 4 + up) * CD + t] = 0.f;
  if (t == 0) den[b * 4 + up] = 0.f;

  // fold weff slice: rows n in [b*16, b*16+16), 1024 float4 / 256 thr
  {
#pragma unroll
    for (int i = 0; i < 4; i++) {
      int idx = t + 256 * i;               // 0..1023
      int n = b * 16 + (idx >> 6), e4 = (idx & 63) * 4;
      const float* base = ow + (size_t)n * (4 * CD) + e4;
      float4 w0 = *(const float4*)(base);
      float4 w1 = *(const float4*)(base + CD);
      float4 w2 = *(const float4*)(base + 2 * CD);
      float4 w3 = *(const float4*)(base + 3 * CD);
      float4 o;
      o.x = w0.x + w1.x + w2.x + w3.x;
      o.y = w0.y + w1.y + w2.y + w3.y;
      o.z = w0.z + w1.z + w2.z + w3.z;
      o.w = w0.w + w1.w + w2.w + w3.w;
      *(float4*)(weff + (size_t)up * CD * CD + (size_t)n * CD + e4) = o;
    }
  }
  __syncthreads();
  if (up == 0) comb[((size_t)b * CNP1 + CN) * CD + t] = cl[t];
  {
    const float* wr = qw + (size_t)t * CD;
    float a = qb[t];
#pragma unroll 4
    for (int k = 0; k < CD; k += 4) {
      float4 w4 = *(const float4*)(wr + k);
      a += cl[k] * w4.x + cl[k + 1] * w4.y + cl[k + 2] * w4.z + cl[k + 3] * w4.w;
    }
    ql[t] = a;
  }
  __syncthreads();
  {
    float a0 = 0.f, a1 = 0.f, a2 = 0.f, a3 = 0.f;
#pragma unroll 4
    for (int d = 0; d < CD; d += 4) {
      a0 += ql[d]     * kw[(d)     * CD + t];
      a1 += ql[d + 1] * kw[(d + 1) * CD + t];
      a2 += ql[d + 2] * kw[(d + 2) * CD + t];
      a3 += ql[d + 3] * kw[(d + 3) * CD + t];
    }
    qt_[((size_t)up * CB + b) * CD + t] = (a0 + a1) + (a2 + a3);
  }
  red[t] = ql[t] * kb[t];
  __syncthreads();
  for (int s = 128; s > 0; s >>= 1) { if (t < s) red[t] += red[t + s]; __syncthreads(); }
  if (t == 0) qkb[up * CB + b] = red[0];
}

// sim+exp+weighted-sum fused. grid (16, 9)
__global__ __launch_bounds__(256) void up_headsim(
    const float* __restrict__ comb, const float* __restrict__ qt,
    const float* __restrict__ qkb, const float* __restrict__ pmask,
    float* __restrict__ head, float* __restrict__ den)
{
  const int b = blockIdx.x, n0 = blockIdx.y * 64, t = threadIdx.x;
  const int up = t >> 6, j = t & 63;
  __shared__ float qtl[4][CD];
  __shared__ float qkbl[4];
  __shared__ float attl[4][64];
  for (int i = t; i < 4 * CD; i += 256)
    qtl[i >> 8][i & 255] = qt[((size_t)(i >> 8) * CB + b) * CD + (i & 255)];
  if (t < 4) qkbl[t] = qkb[t * CB + b];
  __syncthreads();
  {
    const int n = n0 + j;
    float e = 0.f;
    if (n < CNP1) {
      const float* cr = comb + ((size_t)b * CNP1 + n) * CD;
      float p = 0.f;
#pragma unroll 4
      for (int d = 0; d < CD; d += 4) {
        float4 c4 = *(const float4*)(cr + d);
        p += qtl[up][d] * c4.x + qtl[up][d + 1] * c4.y
           + qtl[up][d + 2] * c4.z + qtl[up][d + 3] * c4.w;
      }
      float s = (p + qkbl[up]) * 0.0625f;
      float m = (n < CN) ? pmask[b * CN + n] : 1.f;
      if (m == 0.f) s = 1e-8f;
      e = __expf(s);
    }
    attl[up][j] = e;
  }
  __syncthreads();
  float4 acc = make_float4(0.f, 0.f, 0.f, 0.f);
  const int nmax = min(64, CNP1 - n0);
  for (int jj = 0; jj < nmax; jj++) {
    float a = attl[up][jj];
    float4 c4 = *(const float4*)(comb + ((size_t)b * CNP1 + n0 + jj) * CD + j * 4);
    acc.x += a * c4.x; acc.y += a * c4.y; acc.z += a * c4.z; acc.w += a * c4.w;
  }
  float* hp = head + ((size_t)b * 4 + up) * CD + j * 4;
  atomicAdd(hp + 0, acc.x); atomicAdd(hp + 1, acc.y);
  atomicAdd(hp + 2, acc.z); atomicAdd(hp + 3, acc.w);
  if (j == 0) {
    float s = 0.f;
    for (int jj = 0; jj < 64; jj++) s += attl[up][jj];
    atomicAdd(den + b * 4 + up, s);
  }
}

// fused up_out + ugat projection, reading L2-resident weff. grid (16, 4).
__global__ __launch_bounds__(256) void up_out_ugat(
    const float* __restrict__ head, const float* __restrict__ den,
    const float* __restrict__ weff,
    const float* __restrict__ ob0, const float* __restrict__ ob1,
    const float* __restrict__ ob2, const float* __restrict__ ob3,
    const float* __restrict__ ugat_W, const float* __restrict__ attnw,
    float* __restrict__ uout, float* __restrict__ uqk, float* __restrict__ sqk)
{
  const int b = blockIdx.x, up = blockIdx.y, t = threadIdx.x;
  const float* ob = (up == 0) ? ob0 : (up == 1) ? ob1 : (up == 2) ? ob2 : ob3;
  __shared__ float hl[CD];
  __shared__ float xl[CD];
  __shared__ float qkl[CD];
  hl[t] = head[((size_t)b * 4 + up) * CD + t] * (1.f / den[b * 4 + up]);
  __syncthreads();
  {
    const float* r0 = weff + (size_t)up * CD * CD + (size_t)t * CD;
    float p0 = 0.f, p1 = 0.f, p2 = 0.f, p3 = 0.f;
#pragma unroll 4
    for (int d = 0; d < CD; d += 16) {
      float4 w0 = *(const float4*)(r0 + d);
      float4 w1 = *(const float4*)(r0 + d + 4);
      float4 w2 = *(const float4*)(r0 + d + 8);
      float4 w3 = *(const float4*)(r0 + d + 12);
      p0 += hl[d +  0] * w0.x + hl[d +  1] * w0.y + hl[d +  2] * w0.z + hl[d +  3] * w0.w;
      p1 += hl[d +  4] * w1.x + hl[d +  5] * w1.y + hl[d +  6] * w1.z + hl[d +  7] * w1.w;
      p2 += hl[d +  8] * w2.x + hl[d +  9] * w2.y + hl[d + 10] * w2.z + hl[d + 11] * w2.w;
      p3 += hl[d + 12] * w3.x + hl[d + 13] * w3.y + hl[d + 14] * w3.z + hl[d + 15] * w3.w;
    }
    float a = ob[t] + ((p0 + p1) + (p2 + p3));
    xl[t] = a;
    uout[((size_t)b * 4 + up) * CD + t] = a;
  }
  __syncthreads();
  {
    const float* wr = ugat_W + (size_t)t * CD;
    float p0 = 0.f, p1 = 0.f, p2 = 0.f, p3 = 0.f;
#pragma unroll 4
    for (int d = 0; d < CD; d += 16) {
      float4 w0 = *(const float4*)(wr + d);
      float4 w1 = *(const float4*)(wr + d + 4);
      float4 w2 = *(const float4*)(wr + d + 8);
      float4 w3 = *(const float4*)(wr + d + 12);
      p0 += xl[d +  0] * w0.x + xl[d +  1] * w0.y + xl[d +  2] * w0.z + xl[d +  3] * w0.w;
      p1 += xl[d +  4] * w1.x + xl[d +  5] * w1.y + xl[d +  6] * w1.z + xl[d +  7] * w1.w;
      p2 += xl[d +  8] * w2.x + xl[d +  9] * w2.y + xl[d + 10] * w2.z + xl[d + 11] * w2.w;
      p3 += xl[d + 12] * w3.x + xl[d + 13] * w3.y + xl[d + 14] * w3.z + xl[d + 15] * w3.w;
    }
    float a = (p0 + p1) + (p2 + p3);
    qkl[t] = a;
    uqk[((size_t)b * 4 + up) * CD + t] = a;
  }
  __syncthreads();
  if (t < 8) {
    const int h = t >> 1, which = t & 1;
    const float* w = attnw + h * 128 + which * 64;
    float s = 0.f;
    for (int j = 0; j < 64; j++) s += qkl[h * 64 + j] * w[j];
    sqk[(((size_t)b * 4 + up) * 4 + h) * 2 + which] = s;
  }
}

// fused U_GAT attention (per-trait) + MLP + classifier. grid (16,4).
__global__ __launch_bounds__(256) void ugat_mlp2(
    const float* __restrict__ u, const float* __restrict__ uqk,
    const float* __restrict__ sqk,
    const float* __restrict__ w1, const float* __restrict__ b1,
    const float* __restrict__ w2, const float* __restrict__ b2,
    const float* __restrict__ f1w, const float* __restrict__ f1b,
    const float* __restrict__ f2w, const float* __restrict__ f2b,
    const float* __restrict__ f3w, const float* __restrict__ f3b,
    const float* __restrict__ f4w, const float* __restrict__ f4b,
    float* __restrict__ out)
{
  const int b = blockIdx.x, trait = blockIdx.y, t = threadIdx.x;
  __shared__ float uq[4][CD];
  __shared__ float sl[4][4], kl[4][4];
  __shared__ float xl[CD];
  __shared__ float h1[CFH];
  __shared__ float h2[CFH];
  for (int i = t; i < 4 * CD; i += 256) uq[i >> 8][i & 255] = uqk[(size_t)b * 4 * CD + i];
  if (t < 16) {
    int node = t >> 2, h = t & 3;
    sl[node][h] = sqk[(((size_t)b * 4 + node) * 4 + h) * 2 + 0];
    kl[node][h] = sqk[(((size_t)b * 4 + node) * 4 + h) * 2 + 1];
  }
  float ur = u[((size_t)b * 4 + trait) * CD + t];
  __syncthreads();
  {
    const int h = t >> 6;
    float e[4]; float ssum = 0.f;
#pragma unroll
    for (int k = 0; k < 4; k++) { e[k] = __expf(tanh_fast(sl[trait][h] + kl[k][h])); ssum += e[k]; }
    float hid = 0.f;
#pragma unroll
    for (int k = 0; k < 4; k++) hid += e[k] * uq[k][t];
    xl[t] = ur + tanh_fast(hid / ssum);
  }
  __syncthreads();
  if (t < CFH) {
    const float* r = w1 + (size_t)t * CD;
    float a = b1[t];
#pragma unroll 4
    for (int k = 0; k < CD; k += 4) {
      float4 v = *(const float4*)(r + k);
      a += xl[k] * v.x + xl[k + 1] * v.y + xl[k + 2] * v.z + xl[k + 3] * v.w;
    }
    h1[t] = fmaxf(a, 0.f);
  }
  __syncthreads();
  if (t < CFH) {
    const float* r = w2 + (size_t)t * CFH;
    float a = b2[t];
#pragma unroll 4
    for (int k = 0; k < CFH; k += 4) {
      float4 v = *(const float4*)(r + k);
      a += h1[k] * v.x + h1[k + 1] * v.y + h1[k + 2] * v.z + h1[k + 3] * v.w;
    }
    h2[t] = fmaxf(a, 0.f);
  }
  __syncthreads();
  if (t < CNC) {
    const float* fw; const float* fb;
    switch (trait) {
      case 0:  fw = f1w; fb = f1b; break;
      case 1:  fw = f2w; fb = f2b; break;
      case 2:  fw = f3w; fb = f3b; break;
      default: fw = f4w; fb = f4b; break;
    }
    const float* r = fw + (size_t)t * CFH;
    float a = fb[t];
    for (int k = 0; k < CFH; k++) a += h2[k] * r[k];
    out[(size_t)trait * (CB * CNC) + b * CNC + t] = a;
  }
}

extern "C" void kernel_launch(void* const* d_in, const int* in_sizes, int n_in,
                              void* d_out, int out_size, void* d_ws, size_t ws_size,
                              hipStream_t stream) {
  (void)in_sizes; (void)n_in; (void)out_size; (void)ws_size;
  const float* pmask    = (const float*)d_in[0];
  const float* feature  = (const float*)d_in[1];
  const float* cnode    = (const float*)d_in[2];
  const float* pgat_W   = (const float*)d_in[3];
  const float* pgat_att = (const float*)d_in[4];
  const float* upw[4][6];
  for (int i = 0; i < 4; i++)
    for (int j = 0; j < 6; j++) upw[i][j] = (const float*)d_in[5 + i * 6 + j];
  const float* ugat_W   = (const float*)d_in[29];
  const float* ugat_att = (const float*)d_in[30];
  const float* mlp_w1 = (const float*)d_in[31];
  const float* mlp_b1 = (const float*)d_in[32];
  const float* mlp_w2 = (const float*)d_in[33];
  const float* mlp_b2 = (const float*)d_in[34];
  const float* fcf[8];
  for (int j = 0; j < 8; j++) fcf[j] = (const float*)d_in[35 + j];

  float* ws = (float*)d_ws;
  size_t o = 0;
  float* ws_qk   = ws + o; o += (size_t)CB * CN * CD;    // bf16 qk lives here
  float* ws_feat = ws + o; o += (size_t)CB * CN * CD;
  float* ws_comb = ws + o; o += (size_t)CB * CNP1 * CD;
  float* ws_sq   = ws + o; o += (size_t)CB * CPH * CN;
  float* ws_sk   = ws + o; o += (size_t)CB * CPH * CN;
  float* ws_qt   = ws + o; o += (size_t)4 * CB * CD;
  float* ws_qkb  = ws + o; o += 4 * CB;
  float* ws_den  = ws + o; o += CB * 4;
  float* ws_head = ws + o; o += (size_t)CB * 4 * CD;
  float* ws_u    = ws + o; o += (size_t)CB * 4 * CD;
  float* ws_uqk  = ws + o; o += (size_t)CB * 4 * CD;
  float* ws_sqk  = ws + o; o += (size_t)CB * 4 * 4 * 2;
  float* ws_weff = ws + o; o += (size_t)4 * CD * CD;
  __bf16* qk16 = (__bf16*)ws_qk;

  const dim3 gemmGrid(CD / 64, (CB * CN) / 64);   // (4, 128)
  const dim3 attnGrid(CN / 128, CPH, CB);         // (4, 8, 16)

  // P_GAT layer 1
  gemm_fused<<<gemmGrid, 256, 0, stream>>>(feature, pgat_W, pgat_att, qk16, ws_sq, ws_sk);
  pgat_attn_mfma2<<<attnGrid, 256, 0, stream>>>(qk16, ws_sq, ws_sk, pmask, feature, ws_feat, CN);
  // P_GAT layer 2 (writes into comb rows, stride 513)
  gemm_fused<<<gemmGrid, 256, 0, stream>>>(ws_feat, pgat_W, pgat_att, qk16, ws_sq, ws_sk);
  pgat_attn_mfma2<<<attnGrid, 256, 0, stream>>>(qk16, ws_sq, ws_sk, pmask, ws_feat, ws_comb, CNP1);

  // UP_GAT x4 (also folds weff, zeroes head/den, copies c_node row)
  up_q_all<<<dim3(4, CB), 256, 0, stream>>>(cnode,
      upw[0][0], upw[0][1], upw[0][2], upw[0][3], upw[0][4],
      upw[1][0], upw[1][1], upw[1][2], upw[1][3], upw[1][4],
      upw[2][0], upw[2][1], upw[2][2], upw[2][3], upw[2][4],
      upw[3][0], upw[3][1], upw[3][2], upw[3][3], upw[3][4],
      ws_qt, ws_qkb, ws_comb, ws_head, ws_den, ws_weff);
  up_headsim<<<dim3(CB, (CNP1 + 63) / 64), 256, 0, stream>>>(ws_comb, ws_qt, ws_qkb, pmask,
                                                             ws_head, ws_den);
  up_out_ugat<<<dim3(CB, 4), 256, 0, stream>>>(ws_head, ws_den, ws_weff,
      upw[0][5], upw[1][5], upw[2][5], upw[3][5],
      ugat_W, ugat_att, ws_u, ws_uqk, ws_sqk);

  // U_GAT attention + MLP + heads
  ugat_mlp2<<<dim3(CB, 4), 256, 0, stream>>>(ws_u, ws_uqk, ws_sqk,
                                             mlp_w1, mlp_b1, mlp_w2, mlp_b2,
                                             fcf[0], fcf[1], fcf[2], fcf[3],
                                             fcf[4], fcf[5], fcf[6], fcf[7],
                                             (float*)d_out);
}